// Round 15
// baseline (226.583 us; speedup 1.0000x reference)
//
#include <hip/hip_runtime.h>
#include <hip/hip_bf16.h>
#include <math.h>

#define NB 32
#define NS 512
#define NH 1024
#define NT 37
#define NLP 39
#define NM (NB*NS)   // 16384

typedef __attribute__((ext_vector_type(8))) short bf16x8;
typedef __attribute__((ext_vector_type(4))) float f32x4;

__device__ __forceinline__ float bf2f(unsigned int u) {
    unsigned int x = u << 16;
    float f;
    __builtin_memcpy(&f, &x, 4);
    return f;
}
__device__ __forceinline__ unsigned short f2bf(float f) {
    __hip_bfloat16 hb = __float2bfloat16(f);
    unsigned short u;
    __builtin_memcpy(&u, &hb, 2);
    return u;
}
__device__ __forceinline__ unsigned int pk2(float lo, float hi) {
    return ((unsigned int)f2bf(hi) << 16) | (unsigned int)f2bf(lo);
}
// bijective XOR swizzle for [row][64B] bf16 LDS tiles
__device__ __forceinline__ int SW64(int b)  { return b ^ ((b >> 2) & 0x70); }
// tile swizzle for [128/256 row][64 k] bf16 tiles (row stride 128B)
__device__ __forceinline__ int TSW(int row, int kcolByte) {
    return (row * 128 + kcolByte) ^ ((row & 7) << 4);
}
__device__ __forceinline__ float rl(float x, int l) {
    return __int_as_float(__builtin_amdgcn_readlane(__float_as_int(x), l));
}
__device__ __forceinline__ void gld16(const void* g, void* l) {
    __builtin_amdgcn_global_load_lds((const __attribute__((address_space(1))) void*)g,
                                     (__attribute__((address_space(3))) void*)l, 16, 0, 0);
}
#define VMW(N) asm volatile("s_waitcnt vmcnt(" #N ")" ::: "memory")
#define BARR() do { __builtin_amdgcn_s_barrier(); __builtin_amdgcn_sched_barrier(0); } while (0)

// ---------------------------------------------------------------------------
// Kernel Pre (fast): fused kA1 + kW + kW2, 548 blocks x 512 thr.
//  bid <128  : kA1 work (scores->softmax->attn) AND writes Asw region 0
//              (h as bf16, tile-major TSW) from the fragments it already holds.
//  bid <512  : kW (Wcat -> Wsw swizzled tiles), tile = bid-128.
//  else      : kW2 (Wcrf^T prepack), idx = (bid-512)*512+tid.
// ---------------------------------------------------------------------------
__global__ __launch_bounds__(512) void kPre(const float* __restrict__ h,
                                            const float* __restrict__ bio,
                                            const float* __restrict__ Wcat,
                                            const float* __restrict__ Wcrf,
                                            unsigned short* __restrict__ attn,
                                            char* __restrict__ Asw,
                                            char* __restrict__ Wsw,
                                            unsigned short* __restrict__ WT) {
    __shared__ __align__(16) char shmem[48 * 2048];   // 96KB, aliased per branch
    const int bid = blockIdx.x;
    const int tid = threadIdx.x;

    if (bid < 128) {
        // ---------------- kA1 + region-0 writes ----------------
        char* Bl = shmem;
        const int lane = tid & 63;
        const int wid  = tid >> 6;
        const int lr   = lane & 15;
        const int lk   = lane >> 4;
        const int m0   = bid * 128;

        for (int idx = tid; idx < 37 * 256; idx += 512) {
            int t = idx >> 8, k4 = idx & 255;
            float4 v = *(const float4*)&bio[(size_t)t * NH + k4 * 4];
            int byte = (t * 2048 + k4 * 8) ^ ((t & 7) << 4);
            *(uint2*)(Bl + byte) = make_uint2(pk2(v.x, v.y), pk2(v.z, v.w));
        }
        for (int idx = tid; idx < 11 * 256; idx += 512) {
            int t = 37 + (idx >> 8), k4 = idx & 255;
            int byte = (t * 2048 + k4 * 8) ^ ((t & 7) << 4);
            *(uint2*)(Bl + byte) = make_uint2(0, 0);
        }
        __syncthreads();

        const int arow = m0 + wid * 16 + lr;
        const float* hp = h + (size_t)arow * NH + lk * 8;
        const int trow = wid * 16 + lr;          // within-tile row

        f32x4 sacc[3];
#pragma unroll
        for (int j = 0; j < 3; ++j) sacc[j] = (f32x4){0.f, 0.f, 0.f, 0.f};

        float4 p0 = *(const float4*)(hp);
        float4 p1 = *(const float4*)(hp + 4);
        for (int kt = 0; kt < NH; kt += 32) {
            float4 c0 = p0, c1 = p1;
            if (kt + 32 < NH) {
                p0 = *(const float4*)(hp + kt + 32);
                p1 = *(const float4*)(hp + kt + 36);
            }
            union { unsigned int u[4]; bf16x8 v; uint4 q; } af;
            af.u[0] = pk2(c0.x, c0.y); af.u[1] = pk2(c0.z, c0.w);
            af.u[2] = pk2(c1.x, c1.y); af.u[3] = pk2(c1.z, c1.w);
            // region-0 write: h as bf16, tile-major swizzled
            {
                int kg = kt + lk * 8;
                size_t tb = ((size_t)bid * 48 + (kg >> 6)) * 16384;
                *(uint4*)(Asw + tb + TSW(trow, (kg & 63) * 2)) = af.q;
            }
#pragma unroll
            for (int nf = 0; nf < 3; ++nf) {
                int t = nf * 16 + lr;
                int byte = (t * 2048 + (kt + lk * 8) * 2) ^ ((t & 7) << 4);
                bf16x8 bf = *(const bf16x8*)(Bl + byte);
                sacc[nf] = __builtin_amdgcn_mfma_f32_16x16x32_bf16(af.v, bf, sacc[nf], 0, 0, 0);
            }
        }

#pragma unroll
        for (int r = 0; r < 4; ++r) {
            const int orow = wid * 16 + lk * 4 + r;
            float s0 = sacc[0][r] * 0.03125f;
            float s1 = sacc[1][r] * 0.03125f;
            float s2 = sacc[2][r] * 0.03125f;
            const bool v2 = (lr < 5);
            float mx = fmaxf(fmaxf(s0, s1), v2 ? s2 : -1e30f);
#pragma unroll
            for (int d = 1; d < 16; d <<= 1) mx = fmaxf(mx, __shfl_xor(mx, d, 64));
            float e0 = __expf(s0 - mx), e1 = __expf(s1 - mx);
            float e2 = v2 ? __expf(s2 - mx) : 0.f;
            float sm = e0 + e1 + e2;
#pragma unroll
            for (int d = 1; d < 16; d <<= 1) sm += __shfl_xor(sm, d, 64);
            float inv = 1.f / sm;
            size_t g = (size_t)(m0 + orow) * 64;
            attn[g + lr]      = f2bf(e0 * inv);
            attn[g + 16 + lr] = f2bf(e1 * inv);
            attn[g + 32 + lr] = f2bf(e2 * inv);
            attn[g + 48 + lr] = 0;
        }
    } else if (bid < 512) {
        // ---------------- kW: Wcat -> Wsw swizzled tiles ----------------
        unsigned short* wt = (unsigned short*)shmem;   // 16KB
        const int tile = bid - 128;
        const int tn   = tile / 48;
        const int tk   = tile - tn * 48;
        const int n00  = tn * 128;
        const int k0   = tk * 64;

        for (int lin = tid; lin < 2048; lin += 512) {
            int kk = lin >> 5, ng = lin & 31;
            float4 v = *(const float4*)&Wcat[(size_t)(k0 + kk) * NH + n00 + ng * 4];
            *(uint2*)&wt[kk * 128 + ng * 4] = make_uint2(pk2(v.x, v.y), pk2(v.z, v.w));
        }
        __syncthreads();
        for (int lin = tid; lin < 1024; lin += 512) {
            int rn = lin >> 3, kg = lin & 7;
            unsigned short t8[8];
#pragma unroll
            for (int j = 0; j < 8; ++j) t8[j] = wt[(kg * 8 + j) * 128 + rn];
            uint4 v;
            __builtin_memcpy(&v, t8, 16);
            *(uint4*)(Wsw + (size_t)tile * 16384 + TSW(rn, kg * 16)) = v;
        }
    } else {
        // ---------------- kW2: Wcrf^T prepack ----------------
        const int idx = (bid - 512) * 512 + tid;
        if (idx < 48 * 384) {
            const int t = idx / 384, kg = idx - t * 384;
            unsigned short v[8];
#pragma unroll
            for (int e = 0; e < 8; ++e) {
                int k = kg * 8 + e;
                v[e] = (t < NT) ? f2bf(Wcrf[(size_t)k * NT + t]) : (unsigned short)0;
            }
            uint4 w;
            __builtin_memcpy(&w, v, 16);
            *(uint4*)(WT + (size_t)t * 3072 + kg * 8) = w;
        }
    }
}

// ---------------------------------------------------------------------------
// Kernel A1 (fallback): scores -> softmax -> attn only.
// ---------------------------------------------------------------------------
__global__ __launch_bounds__(512) void kA1(const float* __restrict__ h,
                                           const float* __restrict__ bio,
                                           unsigned short* __restrict__ attn) {
    __shared__ __align__(16) char Bl[48 * 2048];

    const int tid  = threadIdx.x;
    const int lane = tid & 63;
    const int wid  = tid >> 6;
    const int lr   = lane & 15;
    const int lk   = lane >> 4;
    const int m0   = blockIdx.x * 128;

    for (int idx = tid; idx < 37 * 256; idx += 512) {
        int t = idx >> 8, k4 = idx & 255;
        float4 v = *(const float4*)&bio[(size_t)t * NH + k4 * 4];
        int byte = (t * 2048 + k4 * 8) ^ ((t & 7) << 4);
        *(uint2*)(Bl + byte) = make_uint2(pk2(v.x, v.y), pk2(v.z, v.w));
    }
    for (int idx = tid; idx < 11 * 256; idx += 512) {
        int t = 37 + (idx >> 8), k4 = idx & 255;
        int byte = (t * 2048 + k4 * 8) ^ ((t & 7) << 4);
        *(uint2*)(Bl + byte) = make_uint2(0, 0);
    }
    __syncthreads();

    const int arow = m0 + wid * 16 + lr;
    const float* hp = h + (size_t)arow * NH + lk * 8;

    f32x4 sacc[3];
#pragma unroll
    for (int j = 0; j < 3; ++j) sacc[j] = (f32x4){0.f, 0.f, 0.f, 0.f};

    float4 p0 = *(const float4*)(hp);
    float4 p1 = *(const float4*)(hp + 4);
    for (int kt = 0; kt < NH; kt += 32) {
        float4 c0 = p0, c1 = p1;
        if (kt + 32 < NH) {
            p0 = *(const float4*)(hp + kt + 32);
            p1 = *(const float4*)(hp + kt + 36);
        }
        union { unsigned int u[4]; bf16x8 v; } af;
        af.u[0] = pk2(c0.x, c0.y); af.u[1] = pk2(c0.z, c0.w);
        af.u[2] = pk2(c1.x, c1.y); af.u[3] = pk2(c1.z, c1.w);
#pragma unroll
        for (int nf = 0; nf < 3; ++nf) {
            int t = nf * 16 + lr;
            int byte = (t * 2048 + (kt + lk * 8) * 2) ^ ((t & 7) << 4);
            bf16x8 bf = *(const bf16x8*)(Bl + byte);
            sacc[nf] = __builtin_amdgcn_mfma_f32_16x16x32_bf16(af.v, bf, sacc[nf], 0, 0, 0);
        }
    }

#pragma unroll
    for (int r = 0; r < 4; ++r) {
        const int orow = wid * 16 + lk * 4 + r;
        float s0 = sacc[0][r] * 0.03125f;
        float s1 = sacc[1][r] * 0.03125f;
        float s2 = sacc[2][r] * 0.03125f;
        const bool v2 = (lr < 5);
        float mx = fmaxf(fmaxf(s0, s1), v2 ? s2 : -1e30f);
#pragma unroll
        for (int d = 1; d < 16; d <<= 1) mx = fmaxf(mx, __shfl_xor(mx, d, 64));
        float e0 = __expf(s0 - mx), e1 = __expf(s1 - mx);
        float e2 = v2 ? __expf(s2 - mx) : 0.f;
        float sm = e0 + e1 + e2;
#pragma unroll
        for (int d = 1; d < 16; d <<= 1) sm += __shfl_xor(sm, d, 64);
        float inv = 1.f / sm;
        size_t g = (size_t)(m0 + orow) * 64;
        attn[g + lr]      = f2bf(e0 * inv);
        attn[g + 16 + lr] = f2bf(e1 * inv);
        attn[g + 32 + lr] = f2bf(e2 * inv);
        attn[g + 48 + lr] = 0;
    }
}

// ---------------------------------------------------------------------------
// Kernel A2 (fallback): aware = attn @ bio, plain bf16 row-major out.
// ---------------------------------------------------------------------------
__global__ __launch_bounds__(256) void kA2(const unsigned short* __restrict__ attn,
                                           const float* __restrict__ bio,
                                           unsigned short* __restrict__ aware) {
    __shared__ __align__(16) char Bsl[128 * 64];

    const int tid  = threadIdx.x;
    const int lane = tid & 63;
    const int wid  = tid >> 6;
    const int wm   = (wid >> 1) * 64;
    const int wn   = (wid & 1) * 64;
    const int lr   = lane & 15;
    const int lk   = lane >> 4;
    const int n0   = blockIdx.x * 128;
    const int m0   = blockIdx.y * 128;

    const int bn = tid & 127;
    const int bq = (tid >> 7) * 16;

    f32x4 acc[4][4];
#pragma unroll
    for (int i = 0; i < 4; ++i)
#pragma unroll
        for (int j = 0; j < 4; ++j) acc[i][j] = (f32x4){0.f, 0.f, 0.f, 0.f};

#pragma unroll
    for (int ks = 0; ks < 2; ++ks) {
        unsigned int p[8];
#pragma unroll
        for (int i = 0; i < 8; ++i) {
            int t0 = ks*32 + bq + 2*i;
            float lo = (t0     < NT) ? bio[(size_t)t0 * NH + n0 + bn]       : 0.f;
            float hi = (t0 + 1 < NT) ? bio[(size_t)(t0+1) * NH + n0 + bn]   : 0.f;
            p[i] = pk2(lo, hi);
        }
        __syncthreads();
        *(int4*)(Bsl + SW64(bn*64 + bq*2))      = make_int4(p[0], p[1], p[2], p[3]);
        *(int4*)(Bsl + SW64(bn*64 + bq*2 + 16)) = make_int4(p[4], p[5], p[6], p[7]);
        __syncthreads();

        bf16x8 af[4];
#pragma unroll
        for (int mf = 0; mf < 4; ++mf)
            af[mf] = *(const bf16x8*)(attn + (size_t)(m0 + wm + mf*16 + lr) * 64 + ks*32 + lk*8);
#pragma unroll
        for (int nf = 0; nf < 4; ++nf) {
            bf16x8 bb = *(const bf16x8*)(Bsl + SW64((wn + nf*16 + lr)*64 + lk*16));
#pragma unroll
            for (int mf = 0; mf < 4; ++mf)
                acc[mf][nf] = __builtin_amdgcn_mfma_f32_16x16x32_bf16(af[mf], bb, acc[mf][nf], 0, 0, 0);
        }
    }

#pragma unroll
    for (int mf = 0; mf < 4; ++mf)
#pragma unroll
        for (int nf = 0; nf < 4; ++nf)
#pragma unroll
            for (int r = 0; r < 4; ++r) {
                size_t row = (size_t)(m0 + wm + mf*16 + lk*4 + r);
                aware[row * NH + n0 + wn + nf*16 + lr] = f2bf(acc[mf][nf][r]);
            }
}

// ---------------------------------------------------------------------------
// Kernel A2f (fast, v2): computes aware chunk; reads h as bf16 from Asw
// region 0 (written by kPre); writes only regions 1 (aware) and 2 (h*aware).
// ---------------------------------------------------------------------------
__global__ __launch_bounds__(256) void kA2f(const unsigned short* __restrict__ attn,
                                            const float* __restrict__ bio,
                                            char* __restrict__ Asw) {
    __shared__ __align__(16) char Bsl[128 * 64];
    __shared__ __align__(16) unsigned short awL[128 * 128];  // 32KB aware chunk

    const int tid  = threadIdx.x;
    const int lane = tid & 63;
    const int wid  = tid >> 6;
    const int wm   = (wid >> 1) * 64;
    const int wn   = (wid & 1) * 64;
    const int lr   = lane & 15;
    const int lk   = lane >> 4;
    const int n0   = blockIdx.x * 128;
    const int m0   = blockIdx.y * 128;
    const int tm   = blockIdx.y;

    const int bn = tid & 127;
    const int bq = (tid >> 7) * 16;

    f32x4 acc[4][4];
#pragma unroll
    for (int i = 0; i < 4; ++i)
#pragma unroll
        for (int j = 0; j < 4; ++j) acc[i][j] = (f32x4){0.f, 0.f, 0.f, 0.f};

#pragma unroll
    for (int ks = 0; ks < 2; ++ks) {
        unsigned int p[8];
#pragma unroll
        for (int i = 0; i < 8; ++i) {
            int t0 = ks*32 + bq + 2*i;
            float lo = (t0     < NT) ? bio[(size_t)t0 * NH + n0 + bn]       : 0.f;
            float hi = (t0 + 1 < NT) ? bio[(size_t)(t0+1) * NH + n0 + bn]   : 0.f;
            p[i] = pk2(lo, hi);
        }
        __syncthreads();
        *(int4*)(Bsl + SW64(bn*64 + bq*2))      = make_int4(p[0], p[1], p[2], p[3]);
        *(int4*)(Bsl + SW64(bn*64 + bq*2 + 16)) = make_int4(p[4], p[5], p[6], p[7]);
        __syncthreads();

        bf16x8 af[4];
#pragma unroll
        for (int mf = 0; mf < 4; ++mf)
            af[mf] = *(const bf16x8*)(attn + (size_t)(m0 + wm + mf*16 + lr) * 64 + ks*32 + lk*8);
#pragma unroll
        for (int nf = 0; nf < 4; ++nf) {
            bf16x8 bb = *(const bf16x8*)(Bsl + SW64((wn + nf*16 + lr)*64 + lk*16));
#pragma unroll
            for (int mf = 0; mf < 4; ++mf)
                acc[mf][nf] = __builtin_amdgcn_mfma_f32_16x16x32_bf16(af[mf], bb, acc[mf][nf], 0, 0, 0);
        }
    }

#pragma unroll
    for (int mf = 0; mf < 4; ++mf)
#pragma unroll
        for (int nf = 0; nf < 4; ++nf)
#pragma unroll
            for (int r = 0; r < 4; ++r)
                awL[(wm + mf*16 + lk*4 + r) * 128 + wn + nf*16 + lr] = f2bf(acc[mf][nf][r]);
    __syncthreads();

    // region 1 (aware)
#pragma unroll
    for (int i = 0; i < 8; ++i) {
        int lin = tid + i * 256;
        int row = lin >> 4, kg = lin & 15;
        uint4 v = *(const uint4*)&awL[row * 128 + kg * 8];
        int kglob = 1024 + n0 + kg * 8;
        size_t tbase = ((size_t)tm * 48 + (kglob >> 6)) * 16384;
        *(uint4*)(Asw + tbase + TSW(row, (kglob & 63) * 2)) = v;
    }
    // region 2 (h*aware), h read back as bf16 from region 0
#pragma unroll
    for (int i = 0; i < 8; ++i) {
        int lin = tid + i * 256;
        int row = lin >> 4, kg = lin & 15;
        int k0g = n0 + kg * 8;
        size_t tb0 = ((size_t)tm * 48 + (k0g >> 6)) * 16384;
        uint4 hv4 = *(const uint4*)(Asw + tb0 + TSW(row, (k0g & 63) * 2));
        unsigned int hu[4] = {hv4.x, hv4.y, hv4.z, hv4.w};
        uint4 awv = *(const uint4*)&awL[row * 128 + kg * 8];
        unsigned int awu[4] = {awv.x, awv.y, awv.z, awv.w};
        unsigned int p2[4];
#pragma unroll
        for (int j = 0; j < 4; ++j) {
            float lo = bf2f(hu[j] & 0xffffu) * bf2f(awu[j] & 0xffffu);
            float hi = bf2f(hu[j] >> 16)     * bf2f(awu[j] >> 16);
            p2[j] = pk2(lo, hi);
        }
        int k2g = 2048 + n0 + kg * 8;
        size_t tb2 = ((size_t)tm * 48 + (k2g >> 6)) * 16384;
        *(uint4*)(Asw + tb2 + TSW(row, (k2g & 63) * 2)) = make_uint4(p2[0], p2[1], p2[2], p2[3]);
    }
}

// ---------------------------------------------------------------------------
// Kernel W (fallback-support for fast gate fail is not needed; kept for safety
// in case of future use) -- NOTE: fast path uses kPre instead.
// ---------------------------------------------------------------------------
// (removed; kPre handles it)

// ---------------------------------------------------------------------------
// Kernel Bf (fast): 256x256 tile bf16 GEMM, BK=64, 8 waves, counted-vmcnt
// 4-phase schedule + fused kC epilogue (prepacked Wcrf^T). (round-11 proven)
// ---------------------------------------------------------------------------
__global__ __launch_bounds__(512, 2) void kBf(const char* __restrict__ Asw,
                                              const char* __restrict__ Wsw,
                                              const float* __restrict__ bcat,
                                              const unsigned short* __restrict__ WT,
                                              float* __restrict__ P) {
    __shared__ __align__(16) char lds[131072];  // A: buf*32768+h*16384; B at +65536

    const int tid  = threadIdx.x;
    const int lane = tid & 63;
    const int wid  = tid >> 6;
    const int widm = wid >> 2;       // 0..1
    const int widn = wid & 3;        // 0..3
    const int lr   = lane & 15;
    const int lk   = lane >> 4;

    const int id   = blockIdx.x;     // 256 blocks
    const int xcd  = id & 7;
    const int slot = id >> 3;        // 0..31
    const int Mt   = xcd * 8 + (slot >> 2);
    const int Nt   = slot & 3;
    const int m0   = Mt * 256, n0 = Nt * 256;
    const int soff = tid * 16;

    f32x4 acc00[4][2], acc01[4][2], acc10[4][2], acc11[4][2];
#pragma unroll
    for (int i = 0; i < 4; ++i)
#pragma unroll
        for (int j = 0; j < 2; ++j) {
            acc00[i][j] = (f32x4){0.f,0.f,0.f,0.f};
            acc01[i][j] = (f32x4){0.f,0.f,0.f,0.f};
            acc10[i][j] = (f32x4){0.f,0.f,0.f,0.f};
            acc11[i][j] = (f32x4){0.f,0.f,0.f,0.f};
        }

    auto stageHalf = [&](int T, int ph) {
        const bool isA = (ph == 0) || (ph == 3);
        const int  h   = isA ? (ph == 3 ? 1 : 0) : (ph - 1);
        const char* src = isA
            ? Asw + ((size_t)((2*Mt + h) * 48 + T)) * 16384
            : Wsw + ((size_t)((2*Nt + h) * 48 + T)) * 16384;
        char* dst = lds + (isA ? 0 : 65536) + (T & 1) * 32768 + h * 16384;
        gld16(src + soff,        dst + soff);
        gld16(src + soff + 8192, dst + soff + 8192);
    };
    auto loadA = [&](bf16x8 (&af)[4][2], int q, int half) {
        const char* base = lds + q * 32768 + half * 16384;
#pragma unroll
        for (int i = 0; i < 4; ++i) {
            int row = widm * 64 + i * 16 + lr;
#pragma unroll
            for (int kk = 0; kk < 2; ++kk)
                af[i][kk] = *(const bf16x8*)(base + TSW(row, kk * 64 + lk * 16));
        }
    };
    auto loadB = [&](bf16x8 (&bfr)[2][2], int q, int half) {
        const char* base = lds + 65536 + q * 32768 + half * 16384;
#pragma unroll
        for (int j = 0; j < 2; ++j) {
            int col = widn * 32 + j * 16 + lr;
#pragma unroll
            for (int kk = 0; kk < 2; ++kk)
                bfr[j][kk] = *(const bf16x8*)(base + TSW(col, kk * 64 + lk * 16));
        }
    };
    auto mma = [&](f32x4 (&ac)[4][2], bf16x8 (&af)[4][2], bf16x8 (&bfr)[2][2]) {
        __builtin_amdgcn_s_setprio(1);
#pragma unroll
        for (int kk = 0; kk < 2; ++kk)
#pragma unroll
            for (int i = 0; i < 4; ++i)
#pragma unroll
                for (int j = 0; j < 2; ++j)
                    ac[i][j] = __builtin_amdgcn_mfma_f32_16x16x32_bf16(
                        af[i][kk], bfr[j][kk], ac[i][j], 0, 0, 0);
        __builtin_amdgcn_s_setprio(0);
    };

    stageHalf(0, 0); stageHalf(0, 1); stageHalf(0, 2); stageHalf(0, 3);
    VMW(0);
    BARR();

    for (int T = 0; T < 47; ++T) {
        const int q = T & 1;
        bf16x8 af0[4][2], af1[4][2], bf0[2][2], bf1[2][2];
        stageHalf(T + 1, 0);
        VMW(6);
        BARR();
        loadA(af0, q, 0); loadB(bf0, q, 0);
        mma(acc00, af0, bf0);
        stageHalf(T + 1, 1);
        VMW(6);
        BARR();
        loadB(bf1, q, 1);
        mma(acc01, af0, bf1);
        stageHalf(T + 1, 2);
        VMW(6);
        BARR();
        loadA(af1, q, 1);
        mma(acc10, af1, bf0);
        stageHalf(T + 1, 3);
        BARR();
        mma(acc11, af1, bf1);
    }
    {   // T = 47 (buf 1), tail waits 4/2/0
        const int q = 1;
        bf16x8 af0[4][2], af1[4][2], bf0[2][2], bf1[2][2];
        VMW(4);
        BARR();
        loadA(af0, q, 0); loadB(bf0, q, 0);
        mma(acc00, af0, bf0);
        VMW(2);
        BARR();
        loadB(bf1, q, 1);
        mma(acc01, af0, bf1);
        VMW(0);
        BARR();
        loadA(af1, q, 1);
        mma(acc10, af1, bf0);
        BARR();
        mma(acc11, af1, bf1);
    }

    // ---------------- fused kC epilogue ----------------
    __syncthreads();
    auto stashQ = [&](f32x4 (&ac)[4][2], int a, int b) {
#pragma unroll
        for (int j = 0; j < 2; ++j) {
            const int lcol = b * 128 + widn * 32 + j * 16 + lr;
            const int kc = lcol >> 6, kk = lcol & 63;
            const float bc = bcat[n0 + lcol];
#pragma unroll
            for (int i = 0; i < 4; ++i)
#pragma unroll
                for (int r = 0; r < 4; ++r) {
                    int lrow = a * 128 + widm * 64 + i * 16 + lk * 4 + r;
                    float x = ac[i][j][r] + bc;
                    float g = 0.5f * x * (1.0f + erff(x * 0.70710678118654752f));
                    *(unsigned short*)(lds + kc * 32768 + TSW(lrow, kk * 2)) = f2bf(g);
                }
        }
    };
    stashQ(acc00, 0, 0); stashQ(acc01, 0, 1); stashQ(acc10, 1, 0); stashQ(acc11, 1, 1);
    __syncthreads();

    bf16x8 wfrag[3][8];
#pragma unroll
    for (int tt = 0; tt < 3; ++tt) {
        const int t = tt * 16 + lr;
#pragma unroll
        for (int ks = 0; ks < 8; ++ks)
            wfrag[tt][ks] = *(const bf16x8*)(WT + (size_t)t * 3072 + n0 + ks * 32 + lk * 8);
    }

    f32x4 pacc[2][3];
#pragma unroll
    for (int i = 0; i < 2; ++i)
#pragma unroll
        for (int j = 0; j < 3; ++j) pacc[i][j] = (f32x4){0.f, 0.f, 0.f, 0.f};
#pragma unroll
    for (int rt2 = 0; rt2 < 2; ++rt2) {
        const int lrow = wid * 32 + rt2 * 16 + lr;
#pragma unroll
        for (int ks = 0; ks < 8; ++ks) {
            const int kc = ks >> 1, kh = ks & 1;
            bf16x8 af = *(const bf16x8*)(lds + kc * 32768 + TSW(lrow, kh * 64 + lk * 16));
#pragma unroll
            for (int tt = 0; tt < 3; ++tt)
                pacc[rt2][tt] = __builtin_amdgcn_mfma_f32_16x16x32_bf16(
                    af, wfrag[tt][ks], pacc[rt2][tt], 0, 0, 0);
        }
    }

    float* Pb = P + (size_t)Nt * NM * 48;
#pragma unroll
    for (int rt2 = 0; rt2 < 2; ++rt2)
#pragma unroll
        for (int tt = 0; tt < 3; ++tt)
#pragma unroll
            for (int r = 0; r < 4; ++r) {
                int row = Mt * 256 + wid * 32 + rt2 * 16 + lk * 4 + r;
                Pb[(size_t)row * 48 + tt * 16 + lr] = pacc[rt2][tt][r];
            }
}

// ---------------------------------------------------------------------------
// Kernel Cr: out = sum_Nt P[Nt] + b_crf, pads -10000.
// ---------------------------------------------------------------------------
__global__ __launch_bounds__(256) void kCr(const float* __restrict__ P,
                                           const float* __restrict__ bcrf,
                                           float* __restrict__ out) {
    const int g = blockIdx.x * 256 + threadIdx.x;
    const size_t STRIDE = (size_t)NM * 48;
#pragma unroll
    for (int s = 0; s < 12; ++s) {
        int flat = g * 12 + s;
        int row = flat / 48, t = flat - row * 48;
        float v = P[flat] + P[STRIDE + flat] + P[2*STRIDE + flat] + P[3*STRIDE + flat];
        if (t < NT)       out[(size_t)row * NLP + t] = v + bcrf[t];
        else if (t < NLP) out[(size_t)row * NLP + t] = -10000.0f;
    }
}

// ---------------------------------------------------------------------------
// Kernel Dm: segment matrix scan (round-13 proven).
// ---------------------------------------------------------------------------
__global__ __launch_bounds__(64) void kDm(const float* __restrict__ scores,
                                          const int* __restrict__ lens,
                                          const float* __restrict__ trans,
                                          float* __restrict__ Pm,
                                          float* __restrict__ Pc) {
    __shared__ float el_all[64 * 64];
    __shared__ __align__(16) char Mb[2 * 6144];

    const int lane = threadIdx.x;
    const int b    = blockIdx.x >> 3;
    const int s    = blockIdx.x & 7;
    const int lr   = lane & 15;
    const int lk   = lane >> 4;
    const int len  = lens[b];
    const int t0   = s * 64;
    const int nsteps = (len > t0) ? ((len - t0 < 64) ? (len - t0) : 64) : 0;
    const float* sb = scores + (size_t)b * NS * NLP;
    float* Pg = Pm + (size_t)(b * 8 + s) * 2304;

    if (nsteps == 0) {
        for (int j = 0; j < 36; ++j) Pg[j * 64 + lane] = 0.f;
        if (lane < 48) Pg[lane * 48 + lane] = 1.f;
        if (lane == 0) Pc[b * 8 + s] = 0.f;
        return;
    }

    for (int i = 0; i < 64; ++i) {
        float v = 0.f;
        if (i < nsteps && lane < NLP) v = __expf(sb[(size_t)(t0 + i) * NLP + lane]);
        el_all[i * 64 + lane] = v;
    }

    bf16x8 Tf[3][2];
#pragma unroll
    for (int tt = 0; tt < 3; ++tt)
#pragma unroll
        for (int ks = 0; ks < 2; ++ks) {
            const int row = tt * 16 + lr;
            unsigned int u[4];
#pragma unroll
            for (int e2 = 0; e2 < 4; ++e2) {
                int f0 = ks * 32 + lk * 8 + 2 * e2;
                float lo = (row < NLP && f0     < NLP) ? __expf(trans[row * NLP + f0])     : 0.f;
                float hi = (row < NLP && f0 + 1 < NLP) ? __expf(trans[row * NLP + f0 + 1]) : 0.f;
                u[e2] = pk2(lo, hi);
            }
            union { unsigned int uu[4]; bf16x8 v; } cv;
            cv.uu[0]=u[0]; cv.uu[1]=u[1]; cv.uu[2]=u[2]; cv.uu[3]=u[3];
            Tf[tt][ks] = cv.v;
        }

    for (int j = 0; j < 48; ++j)
        *(unsigned int*)(Mb + j * 256 + lane * 4) = 0;
    if (lane < 48) {
        int byte = (lane * 128 + lane * 2) ^ ((lane & 7) << 4);
        *(unsigned short*)(Mb + byte) = f2bf(1.0f);
    }

    float Cacc = 0.f;

    for (int i = 0; i < nsteps; ++i) {
        const int q = i & 1;
        const char* Mr = Mb + q * 6144;

        bf16x8 Bf[3][2];
#pragma unroll
        for (int ct = 0; ct < 3; ++ct) {
#pragma unroll
            for (int ks = 0; ks < 2; ++ks) {
                int col = ct * 16 + lr;
                int byte = (col * 128 + (ks * 32 + lk * 8) * 2) ^ ((col & 7) << 4);
                Bf[ct][ks] = *(const bf16x8*)(Mr + byte);
            }
        }
        f32x4 el4[3];
#pragma unroll
        for (int tt = 0; tt < 3; ++tt)
            el4[tt] = *(const f32x4*)&el_all[i * 64 + tt * 16 + lk * 4];

        f32x4 c[3][3];
#pragma unroll
        for (int tt = 0; tt < 3; ++tt)
#pragma unroll
            for (int ct = 0; ct < 3; ++ct) {
                c[tt][ct] = __builtin_amdgcn_mfma_f32_16x16x32_bf16(
                    Tf[tt][0], Bf[ct][0], (f32x4){0.f,0.f,0.f,0.f}, 0, 0, 0);
                c[tt][ct] = __builtin_amdgcn_mfma_f32_16x16x32_bf16(
                    Tf[tt][1], Bf[ct][1], c[tt][ct], 0, 0, 0);
            }
#pragma unroll
        for (int tt = 0; tt < 3; ++tt)
#pragma unroll
            for (int ct = 0; ct < 3; ++ct)
#pragma unroll
                for (int r = 0; r < 4; ++r)
                    c[tt][ct][r] *= el4[tt][r];

        if ((i & 3) == 3) {
            float sv = rl(c[0][0][0], 0);
            float rr = __builtin_amdgcn_rcpf(sv);
#pragma unroll
            for (int tt = 0; tt < 3; ++tt)
#pragma unroll
                for (int ct = 0; ct < 3; ++ct)
#pragma unroll
                    for (int r = 0; r < 4; ++r) c[tt][ct][r] *= rr;
            Cacc -= __logf(rr);
        }

        if (i == nsteps - 1) {
#pragma unroll
            for (int tt = 0; tt < 3; ++tt)
#pragma unroll
                for (int ct = 0; ct < 3; ++ct)
#pragma unroll
                    for (int r = 0; r < 4; ++r) {
                        int row = tt * 16 + lk * 4 + r;
                        int col = ct * 16 + lr;
                        Pg[row * 48 + col] = c[tt][ct][r];
                    }
        } else {
            char* Mw = Mb + (q ^ 1) * 6144;
#pragma unroll
            for (int tt = 0; tt < 3; ++tt)
#pragma unroll
                for (int ct = 0; ct < 3; ++ct) {
                    int col = ct * 16 + lr;
                    int k   = tt * 16 + lk * 4;
                    int byte = (col * 128 + k * 2) ^ ((col & 7) << 4);
                    *(uint2*)(Mw + byte) = make_uint2(pk2(c[tt][ct][0], c[tt][ct][1]),
                                                      pk2(c[tt][ct][2], c[tt][ct][3]));
                }
        }
    }

    if (lane == 0) Pc[b * 8 + s] = Cacc;
}

// ---------------------------------------------------------------------------
// Kernel Dc: combine (round-13 proven).
// ---------------------------------------------------------------------------
__global__ __launch_bounds__(256) void kDc(const float* __restrict__ scores,
                                           const int* __restrict__ labels,
                                           const int* __restrict__ lens,
                                           const float* __restrict__ trans,
                                           const float* __restrict__ Pm,
                                           const float* __restrict__ Pc,
                                           float* __restrict__ loss) {
    __shared__ float trL[39 * 41];
    __shared__ float gred[4];

    const int b    = blockIdx.x;
    const int tid  = threadIdx.x;
    const int lane = tid & 63;
    const int wid  = tid >> 6;
    const int len  = lens[b];
    const float* sb = scores + (size_t)b * NS * NLP;

    for (int idx = tid; idx < 39 * 39; idx += 256) {
        int to = idx / 39, f = idx - to * 39;
        trL[to * 41 + f] = trans[idx];
    }
    __syncthreads();

    float g = 0.0f;
    for (int t = tid; t < len; t += 256) g += sb[(size_t)t * NLP + labels[b * NS + t]];
    for (int i = tid; i <= len; i += 256) {
        int frm = (i == 0) ? 37 : labels[b * NS + i - 1];
        int to  = (i == len) ? 38 : labels[b * NS + i];
        g += trL[to * 41 + frm];
    }
#pragma unroll
    for (int off = 32; off > 0; off >>= 1) g += __shfl_xor(g, off, 64);
    if (lane == 0) gred[wid] = g;
    __syncthreads();

    if (wid != 0) return;

    const float gold = (gred[0] + gred[1]) + (gred[2] + gred[3]);
    const bool act48 = (lane < 48);

    const float* P0 = Pm + (size_t)b * 8 * 2304;
    float v = act48 ? P0[lane * 48 + 37] : 0.f;
    float C = Pc[b * 8];

    for (int s = 1; s < 8; ++s) {
        float as_[40];
#pragma unroll
        for (int f = 0; f < 40; ++f) as_[f] = rl(v, f);
        __builtin_amdgcn_sched_barrier(0);
        const float* Ps = Pm + (size_t)(b * 8 + s) * 2304;
        float c = 0.f;
        if (act48) {
            const float4* rowp = (const float4*)(Ps + lane * 48);
#pragma unroll
            for (int q = 0; q < 10; ++q) {
                float4 rv = rowp[q];
                c = fmaf(rv.x, as_[q*4+0], c);
                c = fmaf(rv.y, as_[q*4+1], c);
                c = fmaf(rv.z, as_[q*4+2], c);
                c = fmaf(rv.w, as_[q*4+3], c);
            }
        }
        float sv = rl(c, 0);
        float rr = __builtin_amdgcn_rcpf(sv);
        v = c * rr;
        C -= __logf(rr);
        C += Pc[b * 8 + s];
    }

    const float trEnd = (lane < NLP) ? trL[38 * 41 + lane] : 0.f;
    float aend = (lane < NLP && v > 0.f) ? C + __logf(v) + trEnd : -1e30f;
    float mx = aend;
#pragma unroll
    for (int off = 32; off > 0; off >>= 1) mx = fmaxf(mx, __shfl_xor(mx, off, 64));
    float es = (lane < NLP) ? __expf(aend - mx) : 0.f;
#pragma unroll
    for (int off = 32; off > 0; off >>= 1) es += __shfl_xor(es, off, 64);
    float norm = mx + __logf(es);

    if (lane == 0) loss[b] = gold - norm;
}

// ---------------------------------------------------------------------------
// Kernel B (fallback): reg-staged mixed GEMM (round-4 version).
// ---------------------------------------------------------------------------
__global__ __launch_bounds__(256) void kB(const float* __restrict__ h,
                                          const unsigned short* __restrict__ aware,
                                          const float* __restrict__ Wcat,
                                          const float* __restrict__ bcat,
                                          unsigned short* __restrict__ x2) {
    __shared__ __align__(16) char lds[16384];
    char* Asl = lds;
    char* Bsl = lds + 8192;

    const int tid  = threadIdx.x;
    const int lane = tid & 63;
    const int wid  = tid >> 6;
    const int wm   = (wid >> 1) * 64;
    const int wn   = (wid & 1) * 64;
    const int lr   = lane & 15;
    const int lk   = lane >> 4;

    const int id   = blockIdx.x;
    const int xcd  = id & 7;
    const int slot = id >> 3;
    const int m0   = (xcd * 16 + (slot >> 3)) * 128;
    const int n0   = (slot & 7) * 128;

    const int am = tid >> 1;
    const int ak = (tid & 1) * 16;
    const int bn = tid & 127;
    const int bk = (tid >> 7) * 16;

    f32x4 acc[4][4];
#pragma unroll
    for (int i = 0; i < 4; ++i)
#pragma unroll
        for (int j = 0; j < 4; ++j) acc[i][j] = (f32x4){0.f, 0.f, 0.f, 0.f};

    const float*          hrow = h     + (size_t)(m0 + am) * NH + ak;
    const unsigned short* arow = aware + (size_t)(m0 + am) * NH + ak;
    const float*          wcol = Wcat  + (size_t)bk * NH + n0 + bn;

    float hv[16];
    unsigned int aw[8];
    float wv[16];

    auto stage = [&](int kt) {
        const int region = kt >> 10;
        const int kb = kt & 1023;
        if (region != 1) {
            const float4* hp = (const float4*)(hrow + kb);
            float4 a = hp[0], b = hp[1], c = hp[2], d = hp[3];
            hv[0]=a.x; hv[1]=a.y; hv[2]=a.z; hv[3]=a.w;
            hv[4]=b.x; hv[5]=b.y; hv[6]=b.z; hv[7]=b.w;
            hv[8]=c.x; hv[9]=c.y; hv[10]=c.z; hv[11]=c.w;
            hv[12]=d.x; hv[13]=d.y; hv[14]=d.z; hv[15]=d.w;
        }
        if (region >= 1) {
            const uint4* ap = (const uint4*)(arow + kb);
            uint4 a0 = ap[0], a1 = ap[1];
            aw[0]=a0.x; aw[1]=a0.y; aw[2]=a0.z; aw[3]=a0.w;
            aw[4]=a1.x; aw[5]=a1.y; aw[6]=a1.z; aw[7]=a1.w;
        }
        {
            const float* wp = wcol + (size_t)kt * NH;
#pragma unroll
            for (int j = 0; j < 16; ++j) wv[j] = wp[(size_t)j * NH];
        }
    };

    auto writeStage = [&](int kt) {
        const int region = kt >> 10;
        unsigned int p[8];
        if (region == 0) {
#pragma unroll
            for (int i = 0; i < 8; ++i) p[i] = pk2(hv[2*i], hv[2*i+1]);
        } else if (region == 1) {
#pragma unroll
            for (int i = 0; i < 8; ++i) p[i] = aw[i];
        } else {
#pragma unroll
            for (int i = 0; i < 8; ++i) {
                float lo = hv[2*i]   * bf2f(aw[i] & 0xffffu);
                float hi = hv[2*i+1] * bf2f(aw[i] >> 16);
                p[i] = pk2(lo, hi);
            }
        }
        *(int4*)(Asl + SW64(am*64 + ak*2))      = make_int4(p[0], p[1], p[2], p[3]);
        *(int4*)(Asl + SW64(am*64 + ak*2 + 16)) = make_int4(p[4], p[5], p[6], p[7]);
        unsigned int q[8];
#pragma unroll
        for (int i = 0; i < 8; ++i) q[i] = pk2(wv[2*i], wv[2*i+1]);
        *(int4*)(Bsl + SW64(bn*64 + bk*2))      = make_int4(q[0], q[1], q[2], q[3]);
        *(int4*)(Bsl + SW64(bn*64 + bk*2 + 16)) = make_int4(q[4], q[5], q[6], q[7]);
    };

    stage(0);
    for (int kt = 0; kt < 3072; kt += 32) {
        __syncthreads();
        writeStage(kt);
        __syncthreads();
        if (kt + 32 < 3072) stage(kt + 32);

        bf16x8 af[4], bfr[4];
#pragma unroll
        for (int mf = 0; mf < 4; ++mf)
            af[mf] = *(const bf16x8*)(Asl + SW64((wm + mf*16 + lr)*64 + lk*16));
#pragma unroll
        for (int nf = 0; nf < 4; ++nf)
            bfr[nf] = *(const bf16x8*)(Bsl + SW64((wn + nf*16 + lr)*64 + lk*16));
#pragma unroll
        for (int mf = 0; mf < 4; ++mf)
#pragma unroll
            for (int nf = 0; nf < 4; ++nf)
                acc[mf][nf] = __builtin_amdgcn_mfma_f32_16x16x32_bf16(af[mf], bfr[nf], acc[mf][nf], 0, 0, 0);
    }

#pragma unroll
    for (int nf = 0; nf < 4; ++nf) {
        const int col = n0 + wn + nf*16 + lr;
        const float bc = bcat[col];
#pragma unroll
        for (int mf = 0; mf < 4; ++mf)
#pragma unroll
            for (int r = 0; r < 4; ++r) {
                size_t row = (size_t)(m0 + wm + mf*16 + lk*4 + r);
                float x = acc[mf][nf][r] + bc;
                float g = 0.5f * x * (1.0f + erff(x * 0.70710678118654752f));
                x2[row * NH + col] = f2bf(g);
            }
    }
}

// ---------------------------------------------------------------------------
// Kernel C (fallback): ner_scores = [x2 @ W_crf + b_crf, -10000, -10000]
// ---------------------------------------------------------------------------
__global__ __launch_bounds__(256) void kC(const unsigned short* __restrict__ x2,
                                          const float* __restrict__ Wcrf,
                                          const float* __restrict__ bcrf,
                                          float* __restrict__ out) {
    __shared__ __align__(16) char Asl[8192];
    __shared__ __align__(16) char Bsl[3072];

    const int tid  = threadIdx.x;
    const int lane = tid & 63;
    const int wid  = tid >> 6;
    const int lr   = lane & 15;
    const int lk   = lane >> 4;
    const int m0   = blockIdx.x * 128;
    const int am   = tid >> 1;
    const int ak   = (tid & 1) * 16;

    for (int i = tid; i < 192; i += 256) *(int4*)(Bsl + i*16) = make_int4(0, 0, 0, 0);

    f32x4 acc[2][3];
#pragma unroll
    for (int i = 0; i < 2; ++i)
#pragma unroll
        for (int j = 0; j < 3; ++j) acc[i][j] = (f32x4){0.f, 0.f, 0.f, 0.f};

    const unsigned short* xrow = x2 + (size_t)(m0 + am) * NH + ak;

    for (int kt = 0; kt < NH; kt += 32) {
        const uint4* xp = (const uint4*)(xrow + kt);
        uint4 x0 = xp[0], x1 = xp[1];
        float wv[5];
#pragma unroll
        for (int p = 0; p < 5; ++p) {
            int i = tid + p * 256;
            wv[p] = (i < 32*NT) ? Wcrf[(size_t)kt * NT + i] : 0.f;
        }
        __syncthreads();
        *(uint4*)(Asl + SW64(am*64 + ak*2))      = x0;
        *(uint4*)(Asl + SW64(am*64 + ak*2 + 16)) = x1;
#pragma unroll
        for (int p = 0; p < 5; ++p) {
            int i = tid + p * 256;
            if (i < 32*NT) {
                int kk = i / NT;
                int t  = i - kk * NT;
                *(unsigned short*)(Bsl + SW64(t*64 + kk*2)) = f2bf(wv[p]);
            }
        }
        __syncthreads();
        bf16x8 af[2], bfr[3];
#pragma unroll
        for (int mf = 0; mf < 2; ++mf)
            af[mf] = *(const bf16x8*)(Asl + SW64((wid*32 + mf*16 + lr)*64 + lk*16));
#pragma unroll
        for (int nf = 0; nf < 3; ++nf)
            bfr[nf] = *(const bf16x8*)(Bsl + SW64((nf*16 + lr)*64 + lk*16));
#pragma unroll
        for (int mf = 0; mf < 2; ++mf)
#pragma unroll
            for (int nf = 0; nf < 3; ++nf)
                acc[mf][nf] = __builtin_amdgcn_mfma_f32_16x16x32_bf16(af[mf], bfr[nf], acc[mf][nf], 0, 0, 0);
    }

#pragma unroll
    for (int nf = 0; nf < 3; ++nf) {
        const int t = nf*16 + lr;
        const float bc = (t < NT) ? bcrf[t] : 0.f;
#pragma unroll
        for (int mf = 0; mf < 2; ++mf)
#pragma unroll
            for (int r = 0; r < 4; ++r) {
                size_t row = (size_t)(m0 + wid*32 + mf*16 + lk*4 + r);
                if (t < NT)       out[row * NLP + t] = acc[mf][nf][r] + bc;
                else if (t < NLP) out[row * NLP + t] = -10000.0f;
            }
    }
}

// ---------------------------------------------------------------------------
// Kernel Dold (fallback): round-11 exp-domain scan, scores staged in LDS.
// ---------------------------------------------------------------------------
#define CRFSTEP(EL) do {                                   \
    float as_[37];                                         \
    _Pragma("unroll")                                      \
    for (int f_ = 0; f_ < 37; ++f_) as_[f_] = rl(a, f_);   \
    __builtin_amdgcn_sched_barrier(0);                     \
    float c0 = 0.f, c1 = 0.f, c2 = 0.f, c3 = 0.f;          \
    _Pragma("unroll")                                      \
    for (int f_ = 0; f_ < 36; f_ += 4) {                   \
        c0 = fmaf(as_[f_    ], trow[f_    ], c0);          \
        c1 = fmaf(as_[f_ + 1], trow[f_ + 1], c1);          \
        c2 = fmaf(as_[f_ + 2], trow[f_ + 2], c2);          \
        c3 = fmaf(as_[f_ + 3], trow[f_ + 3], c3);          \
    }                                                      \
    c0 = fmaf(as_[36], trow[36], c0);                      \
    a = (EL) * ((c0 + c1) + (c2 + c3));                    \
} while (0)

__global__ __launch_bounds__(256) void kDold(const float* __restrict__ scores,
                                             const int* __restrict__ labels,
                                             const int* __restrict__ lens,
                                             const float* __restrict__ trans,
                                             float* __restrict__ loss) {
    __shared__ float S[NS * NLP];
    __shared__ float trL[39 * 41];
    __shared__ int   labL[NS];
    __shared__ float gred[4];

    const int b    = blockIdx.x;
    const int tid  = threadIdx.x;
    const int lane = tid & 63;
    const int wid  = tid >> 6;
    const int len  = lens[b];
    const float* sb = scores + (size_t)b * NS * NLP;

    {
        const int n4 = (len * NLP + 3) >> 2;
        const float4* src = (const float4*)sb;
        float4* dst = (float4*)S;
        for (int i = tid; i < n4; i += 256) dst[i] = src[i];
    }
    for (int i = tid; i < NS; i += 256) labL[i] = labels[b * NS + i];
    for (int idx = tid; idx < 39 * 39; idx += 256) {
        int to = idx / 39, f = idx - to * 39;
        trL[to * 41 + f] = trans[idx];
    }
    __syncthreads();

    float g = 0.0f;
    for (int t = tid; t < len; t += 256) g += S[t * NLP + labL[t]];
    for (int i = tid; i <= len; i += 256) {
        int frm = (i == 0) ? 37 : labL[i - 1];
        int to  = (i == len) ? 38 : labL[i];
        g += trL[to * 41 + frm];
    }
#pragma unroll
    for (int off = 32; off > 0; off >>= 1) g += __shfl_xor(g, off, 64);
    if (lane == 0) gred[wid] = g;
    __syncthreads();

    if (wid != 0) return;

    const float gold = (gred[0] + gred[1]) + (gred[2] + gred[3]);

    const int myrow = (lane < 39) ? lane : 0;
    float trow[39];
#pragma unroll
    for (int f = 0; f < 39; ++f) trow[f] = __expf(trL[myrow * 41 + f]);
    const float trEnd = (lane < 39) ? trL[38 * 41 + lane] : 0.f;
    const bool act = (lane < 39);

    float l0 = act ? S[lane] : -10000.f;
    float a = act ? __expf(l0) * trow[37] : 0.f;
    float C = 0.0f;

    auto ldrow = [&](int r) {
        r = (r < len) ? r : (len - 1);
        return S[act ? (r * NLP + lane) : 0];
    };
    float lg0 = ldrow(1), lg1 = ldrow(2), lg2 = ldrow(3), lg3 = ldrow(4);

    int t = 1;
    for (; t + 3 < len; t += 4) {
        float e0 = __expf(lg0), e1 = __expf(lg1), e2 = __expf(lg2), e3 = __expf(lg3);
        lg0 = ldrow(t + 4); lg1 = ldrow(t + 5); lg2 = ldrow(t + 6); lg3 = ldrow(t + 7);
        CRFSTEP(e0); CRFSTEP(e1); CRFSTEP(e2); CRFSTEP(e3);
        float s = rl(a, 0);
        float rr = __builtin_amdgcn_rcpf(s);
        a *= rr; C -= __logf(rr);
    }
    for (; t < len; ++t) {
        float el = __expf(ldrow(t));
        CRFSTEP(el);
    }

    float aend = (act && a > 0.f) ? C + __logf(a) + trEnd : -1e30f;
    float mx = aend;
#pragma unroll
    for (int off = 32; off > 0; off >>= 1) mx = fmaxf(mx, __shfl_xor(mx, off, 64));
    float es = act ? __expf(aend - mx) : 0.0f;
#pragma unroll
    for (int off = 32; off > 0; off >>= 1) es += __shfl_xor(es, off, 64);
    float norm = mx + __logf(es);

    if (lane == 0) loss[b] = gold - norm;
}

// ---------------------------------------------------------------------------
extern "C" void kernel_launch(void* const* d_in, const int* in_sizes, int n_in,
                              void* d_out, int out_size, void* d_ws, size_t ws_size,
                              hipStream_t stream) {
    const float* h        = (const float*)d_in[0];
    const int* token_nums = (const int*)d_in[2];
    const int* labels     = (const int*)d_in[3];
    const float* bio      = (const float*)d_in[4];
    const float* Wcat     = (const float*)d_in[5];
    const float* bcat     = (const float*)d_in[6];
    const float* Wcrf     = (const float*)d_in[7];
    const float* bcrf     = (const float*)d_in[8];
    const float* trans    = (const float*)d_in[9];

    float* out = (float*)d_out;
    unsigned short* attn  = (unsigned short*)d_out;  // 2MB scratch, overwritten by kCr

    const size_t ASW_BYTES = (size_t)128 * 48 * 16384;        // 96 MB
    const size_t P_BYTES   = (size_t)4 * NM * 48 * 4;         // 12.6 MB
    const size_t WSW_BYTES = (size_t)8 * 48 * 16384;          // 6 MB
    const size_t WT_BYTES  = (size_t)48 * 3072 * 2;           // 288 KB
    const size_t PM_BYTES  = (size_t)NB * 8 * 2304 * 4;       // 2.36 MB
    const size_t PC_BYTES  = (size_t)NB * 8 * 4;              // 1 KB
    const bool fast = ws_size >= ASW_BYTES + P_BYTES + WSW_BYTES + WT_BYTES + PM_BYTES + PC_BYTES;

    if (fast) {
        char*  Asw = (char*)d_ws;
        float* P   = (float*)((char*)d_ws + ASW_BYTES);
        char*  Wsw = (char*)d_ws + ASW_BYTES + P_BYTES;
        unsigned short* WT = (unsigned short*)((char*)d_ws + ASW_BYTES + P_BYTES + WSW_BYTES);
        float* Pm  = (float*)((char*)d_ws + ASW_BYTES + P_BYTES + WSW_BYTES + WT_BYTES);
        float* Pc  = Pm + (size_t)NB * 8 * 2304;

        hipLaunchKernelGGL(kPre, dim3(548), dim3(512), 0, stream,
                           h, bio, Wcat, Wcrf, attn, Asw, Wsw, WT);
        hipLaunchKernelGGL(kA2f, dim3(NH / 128, NM / 128), dim3(256), 0, stream,
                           attn, bio, Asw);
        hipLaunchKernelGGL(kBf, dim3(256), dim3(512), 0, stream, Asw, Wsw, bcat, WT, P);
        hipLaunchKernelGGL(kCr, dim3(256), dim3(256), 0, stream, P, bcrf, out);
        hipLaunchKernelGGL(kDm, dim3(NB * 8), dim3(64), 0, stream, out, token_nums, trans,
                           Pm, Pc);
        hipLaunchKernelGGL(kDc, dim3(NB), dim3(256), 0, stream, out, labels, token_nums,
                           trans, Pm, Pc, out + (size_t)NM * NLP);
    } else {
        unsigned short* aware = (unsigned short*)d_ws;
        unsigned short* x2    = aware + (size_t)NM * NH;

        hipLaunchKernelGGL(kA1, dim3(NM / 128), dim3(512), 0, stream, h, bio, attn);
        hipLaunchKernelGGL(kA2, dim3(NH / 128, NM / 128), dim3(256), 0, stream, attn, bio, aware);
        hipLaunchKernelGGL(kB, dim3((NH / 128) * (NM / 128)), dim3(256), 0, stream,
                           h, aware, Wcat, bcat, x2);
        hipLaunchKernelGGL(kC, dim3(NM / 128), dim3(256), 0, stream, x2, Wcrf, bcrf, out);
        hipLaunchKernelGGL(kDold, dim3(NB), dim3(256), 0, stream, out, labels, token_nums,
                           trans, out + (size_t)NM * NLP);
    }
}

// Round 16
// 213.875 us; speedup vs baseline: 1.0594x; 1.0594x over previous
//
#include <hip/hip_runtime.h>
#include <hip/hip_bf16.h>
#include <math.h>

#define NB 32
#define NS 512
#define NH 1024
#define NT 37
#define NLP 39
#define NM (NB*NS)   // 16384

typedef __attribute__((ext_vector_type(8))) short bf16x8;
typedef __attribute__((ext_vector_type(4))) float f32x4;

__device__ __forceinline__ float bf2f(unsigned int u) {
    unsigned int x = u << 16;
    float f;
    __builtin_memcpy(&f, &x, 4);
    return f;
}
__device__ __forceinline__ unsigned short f2bf(float f) {
    __hip_bfloat16 hb = __float2bfloat16(f);
    unsigned short u;
    __builtin_memcpy(&u, &hb, 2);
    return u;
}
__device__ __forceinline__ unsigned int pk2(float lo, float hi) {
    return ((unsigned int)f2bf(hi) << 16) | (unsigned int)f2bf(lo);
}
// bijective XOR swizzle for [row][64B] bf16 LDS tiles
__device__ __forceinline__ int SW64(int b)  { return b ^ ((b >> 2) & 0x70); }
// tile swizzle for [128/256 row][64 k] bf16 tiles (row stride 128B)
__device__ __forceinline__ int TSW(int row, int kcolByte) {
    return (row * 128 + kcolByte) ^ ((row & 7) << 4);
}
__device__ __forceinline__ float rl(float x, int l) {
    return __int_as_float(__builtin_amdgcn_readlane(__float_as_int(x), l));
}
__device__ __forceinline__ void gld16(const void* g, void* l) {
    __builtin_amdgcn_global_load_lds((const __attribute__((address_space(1))) void*)g,
                                     (__attribute__((address_space(3))) void*)l, 16, 0, 0);
}
#define VMW(N) asm volatile("s_waitcnt vmcnt(" #N ")" ::: "memory")
#define BARR() do { __builtin_amdgcn_s_barrier(); __builtin_amdgcn_sched_barrier(0); } while (0)

// ---------------------------------------------------------------------------
// Kernel Pre (fast): fused kA1 + kW + kW2, 712 blocks x 256 thr.
//  bid <256  : kA1 over 64 rows (4 MFMA waves) + Asw region-0 writes.
//  bid <640  : kW (Wcat -> Wsw swizzled tile, tile = bid-256).
//  else      : kW2 (Wcrf^T prepack), idx = (bid-640)*256+tid.
// All 256 CUs carry the h-stream (vs 128 fat blocks before).
// ---------------------------------------------------------------------------
__global__ __launch_bounds__(256) void kPre(const float* __restrict__ h,
                                            const float* __restrict__ bio,
                                            const float* __restrict__ Wcat,
                                            const float* __restrict__ Wcrf,
                                            unsigned short* __restrict__ attn,
                                            char* __restrict__ Asw,
                                            char* __restrict__ Wsw,
                                            unsigned short* __restrict__ WT) {
    __shared__ __align__(16) char shmem[48 * 2048];   // 96KB, aliased per branch
    const int bid = blockIdx.x;
    const int tid = threadIdx.x;

    if (bid < 256) {
        // ---------------- kA1 (64 rows) + region-0 writes ----------------
        char* Bl = shmem;
        const int lane = tid & 63;
        const int wid  = tid >> 6;          // 0..3
        const int lr   = lane & 15;
        const int lk   = lane >> 4;
        const int m0   = bid * 64;
        const int tm   = bid >> 1;                        // 128-row tile index
        const int rbase = (bid & 1) * 64 + wid * 16 + lr; // row within tile

        for (int idx = tid; idx < 37 * 256; idx += 256) {
            int t = idx >> 8, k4 = idx & 255;
            float4 v = *(const float4*)&bio[(size_t)t * NH + k4 * 4];
            int byte = (t * 2048 + k4 * 8) ^ ((t & 7) << 4);
            *(uint2*)(Bl + byte) = make_uint2(pk2(v.x, v.y), pk2(v.z, v.w));
        }
        for (int idx = tid; idx < 11 * 256; idx += 256) {
            int t = 37 + (idx >> 8), k4 = idx & 255;
            int byte = (t * 2048 + k4 * 8) ^ ((t & 7) << 4);
            *(uint2*)(Bl + byte) = make_uint2(0, 0);
        }
        __syncthreads();

        const int arow = m0 + wid * 16 + lr;
        const float* hp = h + (size_t)arow * NH + lk * 8;

        f32x4 sacc[3];
#pragma unroll
        for (int j = 0; j < 3; ++j) sacc[j] = (f32x4){0.f, 0.f, 0.f, 0.f};

        float4 p0 = *(const float4*)(hp);
        float4 p1 = *(const float4*)(hp + 4);
        for (int kt = 0; kt < NH; kt += 32) {
            float4 c0 = p0, c1 = p1;
            if (kt + 32 < NH) {
                p0 = *(const float4*)(hp + kt + 32);
                p1 = *(const float4*)(hp + kt + 36);
            }
            union { unsigned int u[4]; bf16x8 v; uint4 q; } af;
            af.u[0] = pk2(c0.x, c0.y); af.u[1] = pk2(c0.z, c0.w);
            af.u[2] = pk2(c1.x, c1.y); af.u[3] = pk2(c1.z, c1.w);
            // region-0 write: h as bf16, tile-major swizzled
            {
                int kg = kt + lk * 8;
                size_t tb = ((size_t)tm * 48 + (kg >> 6)) * 16384;
                *(uint4*)(Asw + tb + TSW(rbase, (kg & 63) * 2)) = af.q;
            }
#pragma unroll
            for (int nf = 0; nf < 3; ++nf) {
                int t = nf * 16 + lr;
                int byte = (t * 2048 + (kt + lk * 8) * 2) ^ ((t & 7) << 4);
                bf16x8 bf = *(const bf16x8*)(Bl + byte);
                sacc[nf] = __builtin_amdgcn_mfma_f32_16x16x32_bf16(af.v, bf, sacc[nf], 0, 0, 0);
            }
        }

#pragma unroll
        for (int r = 0; r < 4; ++r) {
            const int orow = wid * 16 + lk * 4 + r;
            float s0 = sacc[0][r] * 0.03125f;
            float s1 = sacc[1][r] * 0.03125f;
            float s2 = sacc[2][r] * 0.03125f;
            const bool v2 = (lr < 5);
            float mx = fmaxf(fmaxf(s0, s1), v2 ? s2 : -1e30f);
#pragma unroll
            for (int d = 1; d < 16; d <<= 1) mx = fmaxf(mx, __shfl_xor(mx, d, 64));
            float e0 = __expf(s0 - mx), e1 = __expf(s1 - mx);
            float e2 = v2 ? __expf(s2 - mx) : 0.f;
            float sm = e0 + e1 + e2;
#pragma unroll
            for (int d = 1; d < 16; d <<= 1) sm += __shfl_xor(sm, d, 64);
            float inv = 1.f / sm;
            size_t g = (size_t)(m0 + orow) * 64;
            attn[g + lr]      = f2bf(e0 * inv);
            attn[g + 16 + lr] = f2bf(e1 * inv);
            attn[g + 32 + lr] = f2bf(e2 * inv);
            attn[g + 48 + lr] = 0;
        }
    } else if (bid < 640) {
        // ---------------- kW: Wcat -> Wsw swizzled tiles ----------------
        unsigned short* wt = (unsigned short*)shmem;   // 16KB
        const int tile = bid - 256;
        const int tn   = tile / 48;
        const int tk   = tile - tn * 48;
        const int n00  = tn * 128;
        const int k0   = tk * 64;

        for (int lin = tid; lin < 2048; lin += 256) {
            int kk = lin >> 5, ng = lin & 31;
            float4 v = *(const float4*)&Wcat[(size_t)(k0 + kk) * NH + n00 + ng * 4];
            *(uint2*)&wt[kk * 128 + ng * 4] = make_uint2(pk2(v.x, v.y), pk2(v.z, v.w));
        }
        __syncthreads();
        for (int lin = tid; lin < 1024; lin += 256) {
            int rn = lin >> 3, kg = lin & 7;
            unsigned short t8[8];
#pragma unroll
            for (int j = 0; j < 8; ++j) t8[j] = wt[(kg * 8 + j) * 128 + rn];
            uint4 v;
            __builtin_memcpy(&v, t8, 16);
            *(uint4*)(Wsw + (size_t)tile * 16384 + TSW(rn, kg * 16)) = v;
        }
    } else {
        // ---------------- kW2: Wcrf^T prepack ----------------
        const int idx = (bid - 640) * 256 + tid;
        if (idx < 48 * 384) {
            const int t = idx / 384, kg = idx - t * 384;
            unsigned short v[8];
#pragma unroll
            for (int e = 0; e < 8; ++e) {
                int k = kg * 8 + e;
                v[e] = (t < NT) ? f2bf(Wcrf[(size_t)k * NT + t]) : (unsigned short)0;
            }
            uint4 w;
            __builtin_memcpy(&w, v, 16);
            *(uint4*)(WT + (size_t)t * 3072 + kg * 8) = w;
        }
    }
}

// ---------------------------------------------------------------------------
// Kernel A1 (fallback): scores -> softmax -> attn only.
// ---------------------------------------------------------------------------
__global__ __launch_bounds__(512) void kA1(const float* __restrict__ h,
                                           const float* __restrict__ bio,
                                           unsigned short* __restrict__ attn) {
    __shared__ __align__(16) char Bl[48 * 2048];

    const int tid  = threadIdx.x;
    const int lane = tid & 63;
    const int wid  = tid >> 6;
    const int lr   = lane & 15;
    const int lk   = lane >> 4;
    const int m0   = blockIdx.x * 128;

    for (int idx = tid; idx < 37 * 256; idx += 512) {
        int t = idx >> 8, k4 = idx & 255;
        float4 v = *(const float4*)&bio[(size_t)t * NH + k4 * 4];
        int byte = (t * 2048 + k4 * 8) ^ ((t & 7) << 4);
        *(uint2*)(Bl + byte) = make_uint2(pk2(v.x, v.y), pk2(v.z, v.w));
    }
    for (int idx = tid; idx < 11 * 256; idx += 512) {
        int t = 37 + (idx >> 8), k4 = idx & 255;
        int byte = (t * 2048 + k4 * 8) ^ ((t & 7) << 4);
        *(uint2*)(Bl + byte) = make_uint2(0, 0);
    }
    __syncthreads();

    const int arow = m0 + wid * 16 + lr;
    const float* hp = h + (size_t)arow * NH + lk * 8;

    f32x4 sacc[3];
#pragma unroll
    for (int j = 0; j < 3; ++j) sacc[j] = (f32x4){0.f, 0.f, 0.f, 0.f};

    float4 p0 = *(const float4*)(hp);
    float4 p1 = *(const float4*)(hp + 4);
    for (int kt = 0; kt < NH; kt += 32) {
        float4 c0 = p0, c1 = p1;
        if (kt + 32 < NH) {
            p0 = *(const float4*)(hp + kt + 32);
            p1 = *(const float4*)(hp + kt + 36);
        }
        union { unsigned int u[4]; bf16x8 v; } af;
        af.u[0] = pk2(c0.x, c0.y); af.u[1] = pk2(c0.z, c0.w);
        af.u[2] = pk2(c1.x, c1.y); af.u[3] = pk2(c1.z, c1.w);
#pragma unroll
        for (int nf = 0; nf < 3; ++nf) {
            int t = nf * 16 + lr;
            int byte = (t * 2048 + (kt + lk * 8) * 2) ^ ((t & 7) << 4);
            bf16x8 bf = *(const bf16x8*)(Bl + byte);
            sacc[nf] = __builtin_amdgcn_mfma_f32_16x16x32_bf16(af.v, bf, sacc[nf], 0, 0, 0);
        }
    }

#pragma unroll
    for (int r = 0; r < 4; ++r) {
        const int orow = wid * 16 + lk * 4 + r;
        float s0 = sacc[0][r] * 0.03125f;
        float s1 = sacc[1][r] * 0.03125f;
        float s2 = sacc[2][r] * 0.03125f;
        const bool v2 = (lr < 5);
        float mx = fmaxf(fmaxf(s0, s1), v2 ? s2 : -1e30f);
#pragma unroll
        for (int d = 1; d < 16; d <<= 1) mx = fmaxf(mx, __shfl_xor(mx, d, 64));
        float e0 = __expf(s0 - mx), e1 = __expf(s1 - mx);
        float e2 = v2 ? __expf(s2 - mx) : 0.f;
        float sm = e0 + e1 + e2;
#pragma unroll
        for (int d = 1; d < 16; d <<= 1) sm += __shfl_xor(sm, d, 64);
        float inv = 1.f / sm;
        size_t g = (size_t)(m0 + orow) * 64;
        attn[g + lr]      = f2bf(e0 * inv);
        attn[g + 16 + lr] = f2bf(e1 * inv);
        attn[g + 32 + lr] = f2bf(e2 * inv);
        attn[g + 48 + lr] = 0;
    }
}

// ---------------------------------------------------------------------------
// Kernel A2 (fallback): aware = attn @ bio, plain bf16 row-major out.
// ---------------------------------------------------------------------------
__global__ __launch_bounds__(256) void kA2(const unsigned short* __restrict__ attn,
                                           const float* __restrict__ bio,
                                           unsigned short* __restrict__ aware) {
    __shared__ __align__(16) char Bsl[128 * 64];

    const int tid  = threadIdx.x;
    const int lane = tid & 63;
    const int wid  = tid >> 6;
    const int wm   = (wid >> 1) * 64;
    const int wn   = (wid & 1) * 64;
    const int lr   = lane & 15;
    const int lk   = lane >> 4;
    const int n0   = blockIdx.x * 128;
    const int m0   = blockIdx.y * 128;

    const int bn = tid & 127;
    const int bq = (tid >> 7) * 16;

    f32x4 acc[4][4];
#pragma unroll
    for (int i = 0; i < 4; ++i)
#pragma unroll
        for (int j = 0; j < 4; ++j) acc[i][j] = (f32x4){0.f, 0.f, 0.f, 0.f};

#pragma unroll
    for (int ks = 0; ks < 2; ++ks) {
        unsigned int p[8];
#pragma unroll
        for (int i = 0; i < 8; ++i) {
            int t0 = ks*32 + bq + 2*i;
            float lo = (t0     < NT) ? bio[(size_t)t0 * NH + n0 + bn]       : 0.f;
            float hi = (t0 + 1 < NT) ? bio[(size_t)(t0+1) * NH + n0 + bn]   : 0.f;
            p[i] = pk2(lo, hi);
        }
        __syncthreads();
        *(int4*)(Bsl + SW64(bn*64 + bq*2))      = make_int4(p[0], p[1], p[2], p[3]);
        *(int4*)(Bsl + SW64(bn*64 + bq*2 + 16)) = make_int4(p[4], p[5], p[6], p[7]);
        __syncthreads();

        bf16x8 af[4];
#pragma unroll
        for (int mf = 0; mf < 4; ++mf)
            af[mf] = *(const bf16x8*)(attn + (size_t)(m0 + wm + mf*16 + lr) * 64 + ks*32 + lk*8);
#pragma unroll
        for (int nf = 0; nf < 4; ++nf) {
            bf16x8 bb = *(const bf16x8*)(Bsl + SW64((wn + nf*16 + lr)*64 + lk*16));
#pragma unroll
            for (int mf = 0; mf < 4; ++mf)
                acc[mf][nf] = __builtin_amdgcn_mfma_f32_16x16x32_bf16(af[mf], bb, acc[mf][nf], 0, 0, 0);
        }
    }

#pragma unroll
    for (int mf = 0; mf < 4; ++mf)
#pragma unroll
        for (int nf = 0; nf < 4; ++nf)
#pragma unroll
            for (int r = 0; r < 4; ++r) {
                size_t row = (size_t)(m0 + wm + mf*16 + lk*4 + r);
                aware[row * NH + n0 + wn + nf*16 + lr] = f2bf(acc[mf][nf][r]);
            }
}

// ---------------------------------------------------------------------------
// Kernel A2f (fast, v2): computes aware chunk; reads h as bf16 from Asw
// region 0 (written by kPre); writes only regions 1 (aware) and 2 (h*aware).
// ---------------------------------------------------------------------------
__global__ __launch_bounds__(256) void kA2f(const unsigned short* __restrict__ attn,
                                            const float* __restrict__ bio,
                                            char* __restrict__ Asw) {
    __shared__ __align__(16) char Bsl[128 * 64];
    __shared__ __align__(16) unsigned short awL[128 * 128];  // 32KB aware chunk

    const int tid  = threadIdx.x;
    const int lane = tid & 63;
    const int wid  = tid >> 6;
    const int wm   = (wid >> 1) * 64;
    const int wn   = (wid & 1) * 64;
    const int lr   = lane & 15;
    const int lk   = lane >> 4;
    const int n0   = blockIdx.x * 128;
    const int m0   = blockIdx.y * 128;
    const int tm   = blockIdx.y;

    const int bn = tid & 127;
    const int bq = (tid >> 7) * 16;

    f32x4 acc[4][4];
#pragma unroll
    for (int i = 0; i < 4; ++i)
#pragma unroll
        for (int j = 0; j < 4; ++j) acc[i][j] = (f32x4){0.f, 0.f, 0.f, 0.f};

#pragma unroll
    for (int ks = 0; ks < 2; ++ks) {
        unsigned int p[8];
#pragma unroll
        for (int i = 0; i < 8; ++i) {
            int t0 = ks*32 + bq + 2*i;
            float lo = (t0     < NT) ? bio[(size_t)t0 * NH + n0 + bn]       : 0.f;
            float hi = (t0 + 1 < NT) ? bio[(size_t)(t0+1) * NH + n0 + bn]   : 0.f;
            p[i] = pk2(lo, hi);
        }
        __syncthreads();
        *(int4*)(Bsl + SW64(bn*64 + bq*2))      = make_int4(p[0], p[1], p[2], p[3]);
        *(int4*)(Bsl + SW64(bn*64 + bq*2 + 16)) = make_int4(p[4], p[5], p[6], p[7]);
        __syncthreads();

        bf16x8 af[4];
#pragma unroll
        for (int mf = 0; mf < 4; ++mf)
            af[mf] = *(const bf16x8*)(attn + (size_t)(m0 + wm + mf*16 + lr) * 64 + ks*32 + lk*8);
#pragma unroll
        for (int nf = 0; nf < 4; ++nf) {
            bf16x8 bb = *(const bf16x8*)(Bsl + SW64((wn + nf*16 + lr)*64 + lk*16));
#pragma unroll
            for (int mf = 0; mf < 4; ++mf)
                acc[mf][nf] = __builtin_amdgcn_mfma_f32_16x16x32_bf16(af[mf], bb, acc[mf][nf], 0, 0, 0);
        }
    }

#pragma unroll
    for (int mf = 0; mf < 4; ++mf)
#pragma unroll
        for (int nf = 0; nf < 4; ++nf)
#pragma unroll
            for (int r = 0; r < 4; ++r)
                awL[(wm + mf*16 + lk*4 + r) * 128 + wn + nf*16 + lr] = f2bf(acc[mf][nf][r]);
    __syncthreads();

    // region 1 (aware)
#pragma unroll
    for (int i = 0; i < 8; ++i) {
        int lin = tid + i * 256;
        int row = lin >> 4, kg = lin & 15;
        uint4 v = *(const uint4*)&awL[row * 128 + kg * 8];
        int kglob = 1024 + n0 + kg * 8;
        size_t tbase = ((size_t)tm * 48 + (kglob >> 6)) * 16384;
        *(uint4*)(Asw + tbase + TSW(row, (kglob & 63) * 2)) = v;
    }
    // region 2 (h*aware), h read back as bf16 from region 0
#pragma unroll
    for (int i = 0; i < 8; ++i) {
        int lin = tid + i * 256;
        int row = lin >> 4, kg = lin & 15;
        int k0g = n0 + kg * 8;
        size_t tb0 = ((size_t)tm * 48 + (k0g >> 6)) * 16384;
        uint4 hv4 = *(const uint4*)(Asw + tb0 + TSW(row, (k0g & 63) * 2));
        unsigned int hu[4] = {hv4.x, hv4.y, hv4.z, hv4.w};
        uint4 awv = *(const uint4*)&awL[row * 128 + kg * 8];
        unsigned int awu[4] = {awv.x, awv.y, awv.z, awv.w};
        unsigned int p2[4];
#pragma unroll
        for (int j = 0; j < 4; ++j) {
            float lo = bf2f(hu[j] & 0xffffu) * bf2f(awu[j] & 0xffffu);
            float hi = bf2f(hu[j] >> 16)     * bf2f(awu[j] >> 16);
            p2[j] = pk2(lo, hi);
        }
        int k2g = 2048 + n0 + kg * 8;
        size_t tb2 = ((size_t)tm * 48 + (k2g >> 6)) * 16384;
        *(uint4*)(Asw + tb2 + TSW(row, (k2g & 63) * 2)) = make_uint4(p2[0], p2[1], p2[2], p2[3]);
    }
}

// ---------------------------------------------------------------------------
// Kernel Bf (fast): 256x256 tile bf16 GEMM, BK=64, 8 waves, counted-vmcnt
// 4-phase schedule + fused kC epilogue (prepacked Wcrf^T). (round-11 proven)
// ---------------------------------------------------------------------------
__global__ __launch_bounds__(512, 2) void kBf(const char* __restrict__ Asw,
                                              const char* __restrict__ Wsw,
                                              const float* __restrict__ bcat,
                                              const unsigned short* __restrict__ WT,
                                              float* __restrict__ P) {
    __shared__ __align__(16) char lds[131072];  // A: buf*32768+h*16384; B at +65536

    const int tid  = threadIdx.x;
    const int lane = tid & 63;
    const int wid  = tid >> 6;
    const int widm = wid >> 2;       // 0..1
    const int widn = wid & 3;        // 0..3
    const int lr   = lane & 15;
    const int lk   = lane >> 4;

    const int id   = blockIdx.x;     // 256 blocks
    const int xcd  = id & 7;
    const int slot = id >> 3;        // 0..31
    const int Mt   = xcd * 8 + (slot >> 2);
    const int Nt   = slot & 3;
    const int m0   = Mt * 256, n0 = Nt * 256;
    const int soff = tid * 16;

    f32x4 acc00[4][2], acc01[4][2], acc10[4][2], acc11[4][2];
#pragma unroll
    for (int i = 0; i < 4; ++i)
#pragma unroll
        for (int j = 0; j < 2; ++j) {
            acc00[i][j] = (f32x4){0.f,0.f,0.f,0.f};
            acc01[i][j] = (f32x4){0.f,0.f,0.f,0.f};
            acc10[i][j] = (f32x4){0.f,0.f,0.f,0.f};
            acc11[i][j] = (f32x4){0.f,0.f,0.f,0.f};
        }

    auto stageHalf = [&](int T, int ph) {
        const bool isA = (ph == 0) || (ph == 3);
        const int  h   = isA ? (ph == 3 ? 1 : 0) : (ph - 1);
        const char* src = isA
            ? Asw + ((size_t)((2*Mt + h) * 48 + T)) * 16384
            : Wsw + ((size_t)((2*Nt + h) * 48 + T)) * 16384;
        char* dst = lds + (isA ? 0 : 65536) + (T & 1) * 32768 + h * 16384;
        gld16(src + soff,        dst + soff);
        gld16(src + soff + 8192, dst + soff + 8192);
    };
    auto loadA = [&](bf16x8 (&af)[4][2], int q, int half) {
        const char* base = lds + q * 32768 + half * 16384;
#pragma unroll
        for (int i = 0; i < 4; ++i) {
            int row = widm * 64 + i * 16 + lr;
#pragma unroll
            for (int kk = 0; kk < 2; ++kk)
                af[i][kk] = *(const bf16x8*)(base + TSW(row, kk * 64 + lk * 16));
        }
    };
    auto loadB = [&](bf16x8 (&bfr)[2][2], int q, int half) {
        const char* base = lds + 65536 + q * 32768 + half * 16384;
#pragma unroll
        for (int j = 0; j < 2; ++j) {
            int col = widn * 32 + j * 16 + lr;
#pragma unroll
            for (int kk = 0; kk < 2; ++kk)
                bfr[j][kk] = *(const bf16x8*)(base + TSW(col, kk * 64 + lk * 16));
        }
    };
    auto mma = [&](f32x4 (&ac)[4][2], bf16x8 (&af)[4][2], bf16x8 (&bfr)[2][2]) {
        __builtin_amdgcn_s_setprio(1);
#pragma unroll
        for (int kk = 0; kk < 2; ++kk)
#pragma unroll
            for (int i = 0; i < 4; ++i)
#pragma unroll
                for (int j = 0; j < 2; ++j)
                    ac[i][j] = __builtin_amdgcn_mfma_f32_16x16x32_bf16(
                        af[i][kk], bfr[j][kk], ac[i][j], 0, 0, 0);
        __builtin_amdgcn_s_setprio(0);
    };

    stageHalf(0, 0); stageHalf(0, 1); stageHalf(0, 2); stageHalf(0, 3);
    VMW(0);
    BARR();

    for (int T = 0; T < 47; ++T) {
        const int q = T & 1;
        bf16x8 af0[4][2], af1[4][2], bf0[2][2], bf1[2][2];
        stageHalf(T + 1, 0);
        VMW(6);
        BARR();
        loadA(af0, q, 0); loadB(bf0, q, 0);
        mma(acc00, af0, bf0);
        stageHalf(T + 1, 1);
        VMW(6);
        BARR();
        loadB(bf1, q, 1);
        mma(acc01, af0, bf1);
        stageHalf(T + 1, 2);
        VMW(6);
        BARR();
        loadA(af1, q, 1);
        mma(acc10, af1, bf0);
        stageHalf(T + 1, 3);
        BARR();
        mma(acc11, af1, bf1);
    }
    {   // T = 47 (buf 1), tail waits 4/2/0
        const int q = 1;
        bf16x8 af0[4][2], af1[4][2], bf0[2][2], bf1[2][2];
        VMW(4);
        BARR();
        loadA(af0, q, 0); loadB(bf0, q, 0);
        mma(acc00, af0, bf0);
        VMW(2);
        BARR();
        loadB(bf1, q, 1);
        mma(acc01, af0, bf1);
        VMW(0);
        BARR();
        loadA(af1, q, 1);
        mma(acc10, af1, bf0);
        BARR();
        mma(acc11, af1, bf1);
    }

    // ---------------- fused kC epilogue ----------------
    __syncthreads();
    auto stashQ = [&](f32x4 (&ac)[4][2], int a, int b) {
#pragma unroll
        for (int j = 0; j < 2; ++j) {
            const int lcol = b * 128 + widn * 32 + j * 16 + lr;
            const int kc = lcol >> 6, kk = lcol & 63;
            const float bc = bcat[n0 + lcol];
#pragma unroll
            for (int i = 0; i < 4; ++i)
#pragma unroll
                for (int r = 0; r < 4; ++r) {
                    int lrow = a * 128 + widm * 64 + i * 16 + lk * 4 + r;
                    float x = ac[i][j][r] + bc;
                    float g = 0.5f * x * (1.0f + erff(x * 0.70710678118654752f));
                    *(unsigned short*)(lds + kc * 32768 + TSW(lrow, kk * 2)) = f2bf(g);
                }
        }
    };
    stashQ(acc00, 0, 0); stashQ(acc01, 0, 1); stashQ(acc10, 1, 0); stashQ(acc11, 1, 1);
    __syncthreads();

    bf16x8 wfrag[3][8];
#pragma unroll
    for (int tt = 0; tt < 3; ++tt) {
        const int t = tt * 16 + lr;
#pragma unroll
        for (int ks = 0; ks < 8; ++ks)
            wfrag[tt][ks] = *(const bf16x8*)(WT + (size_t)t * 3072 + n0 + ks * 32 + lk * 8);
    }

    f32x4 pacc[2][3];
#pragma unroll
    for (int i = 0; i < 2; ++i)
#pragma unroll
        for (int j = 0; j < 3; ++j) pacc[i][j] = (f32x4){0.f, 0.f, 0.f, 0.f};
#pragma unroll
    for (int rt2 = 0; rt2 < 2; ++rt2) {
        const int lrow = wid * 32 + rt2 * 16 + lr;
#pragma unroll
        for (int ks = 0; ks < 8; ++ks) {
            const int kc = ks >> 1, kh = ks & 1;
            bf16x8 af = *(const bf16x8*)(lds + kc * 32768 + TSW(lrow, kh * 64 + lk * 16));
#pragma unroll
            for (int tt = 0; tt < 3; ++tt)
                pacc[rt2][tt] = __builtin_amdgcn_mfma_f32_16x16x32_bf16(
                    af, wfrag[tt][ks], pacc[rt2][tt], 0, 0, 0);
        }
    }

    float* Pb = P + (size_t)Nt * NM * 48;
#pragma unroll
    for (int rt2 = 0; rt2 < 2; ++rt2)
#pragma unroll
        for (int tt = 0; tt < 3; ++tt)
#pragma unroll
            for (int r = 0; r < 4; ++r) {
                int row = Mt * 256 + wid * 32 + rt2 * 16 + lk * 4 + r;
                Pb[(size_t)row * 48 + tt * 16 + lr] = pacc[rt2][tt][r];
            }
}

// ---------------------------------------------------------------------------
// Kernel DmCr (fast): fused kCr + kDm. Block = (b,s), 256 thr.
// Phase 1 (all 4 waves): compute the block's 64x48 score slice from the 4
// split-K partials + bias, write ner_scores rows, build el table in LDS
// (no score round-trip). Phase 2 (wave 0): the proven matrix segment scan.
// ---------------------------------------------------------------------------
__global__ __launch_bounds__(256) void kDmCr(const float* __restrict__ P,
                                             const float* __restrict__ bcrf,
                                             const int* __restrict__ lens,
                                             const float* __restrict__ trans,
                                             float* __restrict__ out,
                                             float* __restrict__ Pm,
                                             float* __restrict__ Pc) {
    __shared__ float el_all[64 * 64];
    __shared__ __align__(16) char Mb[2 * 6144];

    const int tid = threadIdx.x;
    const int b   = blockIdx.x >> 3;
    const int s   = blockIdx.x & 7;
    const int t0  = s * 64;
    const size_t STRIDE = (size_t)NM * 48;

    // phase 1: scores slice -> out + el_all
    {
        const int i  = tid >> 2;            // step 0..63
        const int tg = (tid & 3) * 12;      // col base (4 groups x 12 = 48)
        const int gr = b * NS + t0 + i;     // global row
#pragma unroll
        for (int j = 0; j < 12; ++j) {
            int t = tg + j;
            size_t flat = (size_t)gr * 48 + t;
            float v = P[flat] + P[STRIDE + flat] + P[2*STRIDE + flat] + P[3*STRIDE + flat];
            float o, el;
            if (t < NT) { o = v + bcrf[t]; el = __expf(o); }
            else        { o = -10000.0f;   el = 0.f; }
            if (t < NLP) out[(size_t)gr * NLP + t] = o;
            el_all[i * 64 + t] = el;
        }
    }
    for (int z = tid; z < 64 * 16; z += 256)
        el_all[(z >> 4) * 64 + 48 + (z & 15)] = 0.f;
    __syncthreads();

    if (tid >= 64) return;     // waves 1-3 done (no further barriers)

    const int lane = tid;
    const int lr   = lane & 15;
    const int lk   = lane >> 4;
    const int len  = lens[b];
    const int nsteps = (len > t0) ? ((len - t0 < 64) ? (len - t0) : 64) : 0;
    float* Pg = Pm + (size_t)(b * 8 + s) * 2304;

    if (nsteps == 0) {
        for (int j = 0; j < 36; ++j) Pg[j * 64 + lane] = 0.f;
        if (lane < 48) Pg[lane * 48 + lane] = 1.f;
        if (lane == 0) Pc[b * 8 + s] = 0.f;
        return;
    }

    // T fragments: T[row][f] = exp(trans[row][f]), zero-padded
    bf16x8 Tf[3][2];
#pragma unroll
    for (int tt = 0; tt < 3; ++tt)
#pragma unroll
        for (int ks = 0; ks < 2; ++ks) {
            const int row = tt * 16 + lr;
            unsigned int u[4];
#pragma unroll
            for (int e2 = 0; e2 < 4; ++e2) {
                int f0 = ks * 32 + lk * 8 + 2 * e2;
                float lo = (row < NLP && f0     < NLP) ? __expf(trans[row * NLP + f0])     : 0.f;
                float hi = (row < NLP && f0 + 1 < NLP) ? __expf(trans[row * NLP + f0 + 1]) : 0.f;
                u[e2] = pk2(lo, hi);
            }
            union { unsigned int uu[4]; bf16x8 v; } cv;
            cv.uu[0]=u[0]; cv.uu[1]=u[1]; cv.uu[2]=u[2]; cv.uu[3]=u[3];
            Tf[tt][ks] = cv.v;
        }

    for (int j = 0; j < 48; ++j)
        *(unsigned int*)(Mb + j * 256 + lane * 4) = 0;
    if (lane < 48) {
        int byte = (lane * 128 + lane * 2) ^ ((lane & 7) << 4);
        *(unsigned short*)(Mb + byte) = f2bf(1.0f);
    }

    float Cacc = 0.f;

    for (int i = 0; i < nsteps; ++i) {
        const int q = i & 1;
        const char* Mr = Mb + q * 6144;

        bf16x8 Bf[3][2];
#pragma unroll
        for (int ct = 0; ct < 3; ++ct) {
#pragma unroll
            for (int ks = 0; ks < 2; ++ks) {
                int col = ct * 16 + lr;
                int byte = (col * 128 + (ks * 32 + lk * 8) * 2) ^ ((col & 7) << 4);
                Bf[ct][ks] = *(const bf16x8*)(Mr + byte);
            }
        }
        f32x4 el4[3];
#pragma unroll
        for (int tt = 0; tt < 3; ++tt)
            el4[tt] = *(const f32x4*)&el_all[i * 64 + tt * 16 + lk * 4];

        f32x4 c[3][3];
#pragma unroll
        for (int tt = 0; tt < 3; ++tt)
#pragma unroll
            for (int ct = 0; ct < 3; ++ct) {
                c[tt][ct] = __builtin_amdgcn_mfma_f32_16x16x32_bf16(
                    Tf[tt][0], Bf[ct][0], (f32x4){0.f,0.f,0.f,0.f}, 0, 0, 0);
                c[tt][ct] = __builtin_amdgcn_mfma_f32_16x16x32_bf16(
                    Tf[tt][1], Bf[ct][1], c[tt][ct], 0, 0, 0);
            }
#pragma unroll
        for (int tt = 0; tt < 3; ++tt)
#pragma unroll
            for (int ct = 0; ct < 3; ++ct)
#pragma unroll
                for (int r = 0; r < 4; ++r)
                    c[tt][ct][r] *= el4[tt][r];

        if ((i & 3) == 3) {
            float sv = rl(c[0][0][0], 0);
            float rr = __builtin_amdgcn_rcpf(sv);
#pragma unroll
            for (int tt = 0; tt < 3; ++tt)
#pragma unroll
                for (int ct = 0; ct < 3; ++ct)
#pragma unroll
                    for (int r = 0; r < 4; ++r) c[tt][ct][r] *= rr;
            Cacc -= __logf(rr);
        }

        if (i == nsteps - 1) {
#pragma unroll
            for (int tt = 0; tt < 3; ++tt)
#pragma unroll
                for (int ct = 0; ct < 3; ++ct)
#pragma unroll
                    for (int r = 0; r < 4; ++r) {
                        int row = tt * 16 + lk * 4 + r;
                        int col = ct * 16 + lr;
                        Pg[row * 48 + col] = c[tt][ct][r];
                    }
        } else {
            char* Mw = Mb + (q ^ 1) * 6144;
#pragma unroll
            for (int tt = 0; tt < 3; ++tt)
#pragma unroll
                for (int ct = 0; ct < 3; ++ct) {
                    int col = ct * 16 + lr;
                    int k   = tt * 16 + lk * 4;
                    int byte = (col * 128 + k * 2) ^ ((col & 7) << 4);
                    *(uint2*)(Mw + byte) = make_uint2(pk2(c[tt][ct][0], c[tt][ct][1]),
                                                      pk2(c[tt][ct][2], c[tt][ct][3]));
                }
        }
    }

    if (lane == 0) Pc[b * 8 + s] = Cacc;
}

// ---------------------------------------------------------------------------
// Kernel Dc: combine (round-13 proven).
// ---------------------------------------------------------------------------
__global__ __launch_bounds__(256) void kDc(const float* __restrict__ scores,
                                           const int* __restrict__ labels,
                                           const int* __restrict__ lens,
                                           const float* __restrict__ trans,
                                           const float* __restrict__ Pm,
                                           const float* __restrict__ Pc,
                                           float* __restrict__ loss) {
    __shared__ float trL[39 * 41];
    __shared__ float gred[4];

    const int b    = blockIdx.x;
    const int tid  = threadIdx.x;
    const int lane = tid & 63;
    const int wid  = tid >> 6;
    const int len  = lens[b];
    const float* sb = scores + (size_t)b * NS * NLP;

    for (int idx = tid; idx < 39 * 39; idx += 256) {
        int to = idx / 39, f = idx - to * 39;
        trL[to * 41 + f] = trans[idx];
    }
    __syncthreads();

    float g = 0.0f;
    for (int t = tid; t < len; t += 256) g += sb[(size_t)t * NLP + labels[b * NS + t]];
    for (int i = tid; i <= len; i += 256) {
        int frm = (i == 0) ? 37 : labels[b * NS + i - 1];
        int to  = (i == len) ? 38 : labels[b * NS + i];
        g += trL[to * 41 + frm];
    }
#pragma unroll
    for (int off = 32; off > 0; off >>= 1) g += __shfl_xor(g, off, 64);
    if (lane == 0) gred[wid] = g;
    __syncthreads();

    if (wid != 0) return;

    const float gold = (gred[0] + gred[1]) + (gred[2] + gred[3]);
    const bool act48 = (lane < 48);

    const float* P0 = Pm + (size_t)b * 8 * 2304;
    float v = act48 ? P0[lane * 48 + 37] : 0.f;
    float C = Pc[b * 8];

    for (int s = 1; s < 8; ++s) {
        float as_[40];
#pragma unroll
        for (int f = 0; f < 40; ++f) as_[f] = rl(v, f);
        __builtin_amdgcn_sched_barrier(0);
        const float* Ps = Pm + (size_t)(b * 8 + s) * 2304;
        float c = 0.f;
        if (act48) {
            const float4* rowp = (const float4*)(Ps + lane * 48);
#pragma unroll
            for (int q = 0; q < 10; ++q) {
                float4 rv = rowp[q];
                c = fmaf(rv.x, as_[q*4+0], c);
                c = fmaf(rv.y, as_[q*4+1], c);
                c = fmaf(rv.z, as_[q*4+2], c);
                c = fmaf(rv.w, as_[q*4+3], c);
            }
        }
        float sv = rl(c, 0);
        float rr = __builtin_amdgcn_rcpf(sv);
        v = c * rr;
        C -= __logf(rr);
        C += Pc[b * 8 + s];
    }

    const float trEnd = (lane < NLP) ? trL[38 * 41 + lane] : 0.f;
    float aend = (lane < NLP && v > 0.f) ? C + __logf(v) + trEnd : -1e30f;
    float mx = aend;
#pragma unroll
    for (int off = 32; off > 0; off >>= 1) mx = fmaxf(mx, __shfl_xor(mx, off, 64));
    float es = (lane < NLP) ? __expf(aend - mx) : 0.f;
#pragma unroll
    for (int off = 32; off > 0; off >>= 1) es += __shfl_xor(es, off, 64);
    float norm = mx + __logf(es);

    if (lane == 0) loss[b] = gold - norm;
}

// ---------------------------------------------------------------------------
// Kernel B (fallback): reg-staged mixed GEMM (round-4 version).
// ---------------------------------------------------------------------------
__global__ __launch_bounds__(256) void kB(const float* __restrict__ h,
                                          const unsigned short* __restrict__ aware,
                                          const float* __restrict__ Wcat,
                                          const float* __restrict__ bcat,
                                          unsigned short* __restrict__ x2) {
    __shared__ __align__(16) char lds[16384];
    char* Asl = lds;
    char* Bsl = lds + 8192;

    const int tid  = threadIdx.x;
    const int lane = tid & 63;
    const int wid  = tid >> 6;
    const int wm   = (wid >> 1) * 64;
    const int wn   = (wid & 1) * 64;
    const int lr   = lane & 15;
    const int lk   = lane >> 4;

    const int id   = blockIdx.x;
    const int xcd  = id & 7;
    const int slot = id >> 3;
    const int m0   = (xcd * 16 + (slot >> 3)) * 128;
    const int n0   = (slot & 7) * 128;

    const int am = tid >> 1;
    const int ak = (tid & 1) * 16;
    const int bn = tid & 127;
    const int bk = (tid >> 7) * 16;

    f32x4 acc[4][4];
#pragma unroll
    for (int i = 0; i < 4; ++i)
#pragma unroll
        for (int j = 0; j < 4; ++j) acc[i][j] = (f32x4){0.f, 0.f, 0.f, 0.f};

    const float*          hrow = h     + (size_t)(m0 + am) * NH + ak;
    const unsigned short* arow = aware + (size_t)(m0 + am) * NH + ak;
    const float*          wcol = Wcat  + (size_t)bk * NH + n0 + bn;

    float hv[16];
    unsigned int aw[8];
    float wv[16];

    auto stage = [&](int kt) {
        const int region = kt >> 10;
        const int kb = kt & 1023;
        if (region != 1) {
            const float4* hp = (const float4*)(hrow + kb);
            float4 a = hp[0], b = hp[1], c = hp[2], d = hp[3];
            hv[0]=a.x; hv[1]=a.y; hv[2]=a.z; hv[3]=a.w;
            hv[4]=b.x; hv[5]=b.y; hv[6]=b.z; hv[7]=b.w;
            hv[8]=c.x; hv[9]=c.y; hv[10]=c.z; hv[11]=c.w;
            hv[12]=d.x; hv[13]=d.y; hv[14]=d.z; hv[15]=d.w;
        }
        if (region >= 1) {
            const uint4* ap = (const uint4*)(arow + kb);
            uint4 a0 = ap[0], a1 = ap[1];
            aw[0]=a0.x; aw[1]=a0.y; aw[2]=a0.z; aw[3]=a0.w;
            aw[4]=a1.x; aw[5]=a1.y; aw[6]=a1.z; aw[7]=a1.w;
        }
        {
            const float* wp = wcol + (size_t)kt * NH;
#pragma unroll
            for (int j = 0; j < 16; ++j) wv[j] = wp[(size_t)j * NH];
        }
    };

    auto writeStage = [&](int kt) {
        const int region = kt >> 10;
        unsigned int p[8];
        if (region == 0) {
#pragma unroll
            for (int i = 0; i < 8; ++i) p[i] = pk2(hv[2*i], hv[2*i+1]);
        } else if (region == 1) {
#pragma unroll
            for (int i = 0; i < 8; ++i) p[i] = aw[i];
        } else {
#pragma unroll
            for (int i = 0; i < 8; ++i) {
                float lo = hv[2*i]   * bf2f(aw[i] & 0xffffu);
                float hi = hv[2*i+1] * bf2f(aw[i] >> 16);
                p[i] = pk2(lo, hi);
            }
        }
        *(int4*)(Asl + SW64(am*64 + ak*2))      = make_int4(p[0], p[1], p[2], p[3]);
        *(int4*)(Asl + SW64(am*64 + ak*2 + 16)) = make_int4(p[4], p[5], p[6], p[7]);
        unsigned int q[8];
#pragma unroll
        for (int i = 0; i < 8; ++i) q[i] = pk2(wv[2*i], wv[2*i+1]);
        *(int4*)(Bsl + SW64(bn*64 + bk*2))      = make_int4(q[0], q[1], q[2], q[3]);
        *(int4*)(Bsl + SW64(bn*64 + bk*2 + 16)) = make_int4(q[4], q[5], q[6], q[7]);
    };

    stage(0);
    for (int kt = 0; kt < 3072; kt += 32) {
        __syncthreads();
        writeStage(kt);
        __syncthreads();
        if (kt + 32 < 3072) stage(kt + 32);

        bf16x8 af[4], bfr[4];
#pragma unroll
        for (int mf = 0; mf < 4; ++mf)
            af[mf] = *(const bf16x8*)(Asl + SW64((wm + mf*16 + lr)*64 + lk*16));
#pragma unroll
        for (int nf = 0; nf < 4; ++nf)
            bfr[nf] = *(const bf16x8*)(Bsl + SW64((wn + nf*16 + lr)*64 + lk*16));
#pragma unroll
        for (int mf = 0; mf < 4; ++mf)
#pragma unroll
            for (int nf = 0; nf < 4; ++nf)
                acc[mf][nf] = __builtin_amdgcn_mfma_f32_16x16x32_bf16(af[mf], bfr[nf], acc[mf][nf], 0, 0, 0);
    }

#pragma unroll
    for (int nf = 0; nf < 4; ++nf) {
        const int col = n0 + wn + nf*16 + lr;
        const float bc = bcat[col];
#pragma unroll
        for (int mf = 0; mf < 4; ++mf)
#pragma unroll
            for (int r = 0; r < 4; ++r) {
                size_t row = (size_t)(m0 + wm + mf*16 + lk*4 + r);
                float x = acc[mf][nf][r] + bc;
                float g = 0.5f * x * (1.0f + erff(x * 0.70710678118654752f));
                x2[row * NH + col] = f2bf(g);
            }
    }
}

// ---------------------------------------------------------------------------
// Kernel C (fallback): ner_scores = [x2 @ W_crf + b_crf, -10000, -10000]
// ---------------------------------------------------------------------------
__global__ __launch_bounds__(256) void kC(const unsigned short* __restrict__ x2,
                                          const float* __restrict__ Wcrf,
                                          const float* __restrict__ bcrf,
                                          float* __restrict__ out) {
    __shared__ __align__(16) char Asl[8192];
    __shared__ __align__(16) char Bsl[3072];

    const int tid  = threadIdx.x;
    const int lane = tid & 63;
    const int wid  = tid >> 6;
    const int lr   = lane & 15;
    const int lk   = lane >> 4;
    const int m0   = blockIdx.x * 128;
    const int am   = tid >> 1;
    const int ak   = (tid & 1) * 16;

    for (int i = tid; i < 192; i += 256) *(int4*)(Bsl + i*16) = make_int4(0, 0, 0, 0);

    f32x4 acc[2][3];
#pragma unroll
    for (int i = 0; i < 2; ++i)
#pragma unroll
        for (int j = 0; j < 3; ++j) acc[i][j] = (f32x4){0.f, 0.f, 0.f, 0.f};

    const unsigned short* xrow = x2 + (size_t)(m0 + am) * NH + ak;

    for (int kt = 0; kt < NH; kt += 32) {
        const uint4* xp = (const uint4*)(xrow + kt);
        uint4 x0 = xp[0], x1 = xp[1];
        float wv[5];
#pragma unroll
        for (int p = 0; p < 5; ++p) {
            int i = tid + p * 256;
            wv[p] = (i < 32*NT) ? Wcrf[(size_t)kt * NT + i] : 0.f;
        }
        __syncthreads();
        *(uint4*)(Asl + SW64(am*64 + ak*2))      = x0;
        *(uint4*)(Asl + SW64(am*64 + ak*2 + 16)) = x1;
#pragma unroll
        for (int p = 0; p < 5; ++p) {
            int i = tid + p * 256;
            if (i < 32*NT) {
                int kk = i / NT;
                int t  = i - kk * NT;
                *(unsigned short*)(Bsl + SW64(t*64 + kk*2)) = f2bf(wv[p]);
            }
        }
        __syncthreads();
        bf16x8 af[2], bfr[3];
#pragma unroll
        for (int mf = 0; mf < 2; ++mf)
            af[mf] = *(const bf16x8*)(Asl + SW64((wid*32 + mf*16 + lr)*64 + lk*16));
#pragma unroll
        for (int nf = 0; nf < 3; ++nf)
            bfr[nf] = *(const bf16x8*)(Bsl + SW64((nf*16 + lr)*64 + lk*16));
#pragma unroll
        for (int mf = 0; mf < 2; ++mf)
#pragma unroll
            for (int nf = 0; nf < 3; ++nf)
                acc[mf][nf] = __builtin_amdgcn_mfma_f32_16x16x32_bf16(af[mf], bfr[nf], acc[mf][nf], 0, 0, 0);
    }

#pragma unroll
    for (int nf = 0; nf < 3; ++nf) {
        const int t = nf*16 + lr;
        const float bc = (t < NT) ? bcrf[t] : 0.f;
#pragma unroll
        for (int mf = 0; mf < 2; ++mf)
#pragma unroll
            for (int r = 0; r < 4; ++r) {
                size_t row = (size_t)(m0 + wid*32 + mf*16 + lk*4 + r);
                if (t < NT)       out[row * NLP + t] = acc[mf][nf][r] + bc;
                else if (t < NLP) out[row * NLP + t] = -10000.0f;
            }
    }
}

// ---------------------------------------------------------------------------
// Kernel Dold (fallback): round-11 exp-domain scan, scores staged in LDS.
// ---------------------------------------------------------------------------
#define CRFSTEP(EL) do {                                   \
    float as_[37];                                         \
    _Pragma("unroll")                                      \
    for (int f_ = 0; f_ < 37; ++f_) as_[f_] = rl(a, f_);   \
    __builtin_amdgcn_sched_barrier(0);                     \
    float c0 = 0.f, c1 = 0.f, c2 = 0.f, c3 = 0.f;          \
    _Pragma("unroll")                                      \
    for (int f_ = 0; f_ < 36; f_ += 4) {                   \
        c0 = fmaf(as_[f_    ], trow[f_    ], c0);          \
        c1 = fmaf(as_[f_ + 1], trow[f_ + 1], c1);          \
        c2 = fmaf(as_[f_ + 2], trow[f_ + 2], c2);          \
        c3 = fmaf(as_[f_ + 3], trow[f_ + 3], c3);          \
    }                                                      \
    c0 = fmaf(as_[36], trow[36], c0);                      \
    a = (EL) * ((c0 + c1) + (c2 + c3));                    \
} while (0)

__global__ __launch_bounds__(256) void kDold(const float* __restrict__ scores,
                                             const int* __restrict__ labels,
                                             const int* __restrict__ lens,
                                             const float* __restrict__ trans,
                                             float* __restrict__ loss) {
    __shared__ float S[NS * NLP];
    __shared__ float trL[39 * 41];
    __shared__ int   labL[NS];
    __shared__ float gred[4];

    const int b    = blockIdx.x;
    const int tid  = threadIdx.x;
    const int lane = tid & 63;
    const int wid  = tid >> 6;
    const int len  = lens[b];
    const float* sb = scores + (size_t)b * NS * NLP;

    {
        const int n4 = (len * NLP + 3) >> 2;
        const float4* src = (const float4*)sb;
        float4* dst = (float4*)S;
        for (int i = tid; i < n4; i += 256) dst[i] = src[i];
    }
    for (int i = tid; i < NS; i += 256) labL[i] = labels[b * NS + i];
    for (int idx = tid; idx < 39 * 39; idx += 256) {
        int to = idx / 39, f = idx - to * 39;
        trL[to * 41 + f] = trans[idx];
    }
    __syncthreads();

    float g = 0.0f;
    for (int t = tid; t < len; t += 256) g += S[t * NLP + labL[t]];
    for (int i = tid; i <= len; i += 256) {
        int frm = (i == 0) ? 37 : labL[i - 1];
        int to  = (i == len) ? 38 : labL[i];
        g += trL[to * 41 + frm];
    }
#pragma unroll
    for (int off = 32; off > 0; off >>= 1) g += __shfl_xor(g, off, 64);
    if (lane == 0) gred[wid] = g;
    __syncthreads();

    if (wid != 0) return;

    const float gold = (gred[0] + gred[1]) + (gred[2] + gred[3]);

    const int myrow = (lane < 39) ? lane : 0;
    float trow[39];
#pragma unroll
    for (int f = 0; f < 39; ++f) trow[f] = __expf(trL[myrow * 41 + f]);
    const float trEnd = (lane < 39) ? trL[38 * 41 + lane] : 0.f;
    const bool act = (lane < 39);

    float l0 = act ? S[lane] : -10000.f;
    float a = act ? __expf(l0) * trow[37] : 0.f;
    float C = 0.0f;

    auto ldrow = [&](int r) {
        r = (r < len) ? r : (len - 1);
        return S[act ? (r * NLP + lane) : 0];
    };
    float lg0 = ldrow(1), lg1 = ldrow(2), lg2 = ldrow(3), lg3 = ldrow(4);

    int t = 1;
    for (; t + 3 < len; t += 4) {
        float e0 = __expf(lg0), e1 = __expf(lg1), e2 = __expf(lg2), e3 = __expf(lg3);
        lg0 = ldrow(t + 4); lg1 = ldrow(t + 5); lg2 = ldrow(t + 6); lg3 = ldrow(t + 7);
        CRFSTEP(e0); CRFSTEP(e1); CRFSTEP(e2); CRFSTEP(e3);
        float s = rl(a, 0);
        float rr = __builtin_amdgcn_rcpf(s);
        a *= rr; C -= __logf(rr);
    }
    for (; t < len; ++t) {
        float el = __expf(ldrow(t));
        CRFSTEP(el);
    }

    float aend = (act && a > 0.f) ? C + __logf(a) + trEnd : -1e30f;
    float mx = aend;
#pragma unroll
    for (int off = 32; off > 0; off >>= 1) mx = fmaxf(mx, __shfl_xor(mx, off, 64));
    float es = act ? __expf(aend - mx) : 0.0f;
#pragma unroll
    for (int off = 32; off > 0; off >>= 1) es += __shfl_xor(es, off, 64);
    float norm = mx + __logf(es);

    if (lane == 0) loss[b] = gold - norm;
}

// ---------------------------------------------------------------------------
extern "C" void kernel_launch(void* const* d_in, const int* in_sizes, int n_in,
                              void* d_out, int out_size, void* d_ws, size_t ws_size,
                              hipStream_t stream) {
    const float* h        = (const float*)d_in[0];
    const int* token_nums = (const int*)d_in[2];
    const int* labels     = (const int*)d_in[3];
    const float* bio      = (const float*)d_in[4];
    const float* Wcat     = (const float*)d_in[5];
    const float* bcat     = (const float*)d_in[6];
    const float* Wcrf     = (const float*)d_in[7];
    const float* bcrf     = (const float*)d_in[8];
    const float* trans    = (const float*)d_in[9];

    float* out = (float*)d_out;
    unsigned short* attn  = (unsigned short*)d_out;  // 2MB scratch, overwritten by kDmCr

    const size_t ASW_BYTES = (size_t)128 * 48 * 16384;        // 96 MB
    const size_t P_BYTES   = (size_t)4 * NM * 48 * 4;         // 12.6 MB
    const size_t WSW_BYTES = (size_t)8 * 48 * 16384;          // 6 MB
    const size_t WT_BYTES  = (size_t)48 * 3072 * 2;           // 288 KB
    const size_t PM_BYTES  = (size_t)NB * 8 * 2304 * 4;       // 2.36 MB
    const size_t PC_BYTES  = (size_t)NB * 8 * 4;              // 1 KB
    const bool fast = ws_size >= ASW_BYTES + P_BYTES + WSW_BYTES + WT_BYTES + PM_BYTES + PC_BYTES;

    if (fast) {
        char*  Asw = (char*)d_ws;
        float* P   = (float*)((char*)d_ws + ASW_BYTES);
        char*  Wsw = (char*)d_ws + ASW_BYTES + P_BYTES;
        unsigned short* WT = (unsigned short*)((char*)d_ws + ASW_BYTES + P_BYTES + WSW_BYTES);
        float* Pm  = (float*)((char*)d_ws + ASW_BYTES + P_BYTES + WSW_BYTES + WT_BYTES);
        float* Pc  = Pm + (size_t)NB * 8 * 2304;

        hipLaunchKernelGGL(kPre, dim3(712), dim3(256), 0, stream,
                           h, bio, Wcat, Wcrf, attn, Asw, Wsw, WT);
        hipLaunchKernelGGL(kA2f, dim3(NH / 128, NM / 128), dim3(256), 0, stream,
                           attn, bio, Asw);
        hipLaunchKernelGGL(kBf, dim3(256), dim3(512), 0, stream, Asw, Wsw, bcat, WT, P);
        hipLaunchKernelGGL(kDmCr, dim3(NB * 8), dim3(256), 0, stream,
                           P, bcrf, token_nums, trans, out, Pm, Pc);
        hipLaunchKernelGGL(kDc, dim3(NB), dim3(256), 0, stream, out, labels, token_nums,
                           trans, Pm, Pc, out + (size_t)NM * NLP);
    } else {
        unsigned short* aware = (unsigned short*)d_ws;
        unsigned short* x2    = aware + (size_t)NM * NH;

        hipLaunchKernelGGL(kA1, dim3(NM / 128), dim3(512), 0, stream, h, bio, attn);
        hipLaunchKernelGGL(kA2, dim3(NH / 128, NM / 128), dim3(256), 0, stream, attn, bio, aware);
        hipLaunchKernelGGL(kB, dim3((NH / 128) * (NM / 128)), dim3(256), 0, stream,
                           h, aware, Wcat, bcat, x2);
        hipLaunchKernelGGL(kC, dim3(NM / 128), dim3(256), 0, stream, x2, Wcrf, bcrf, out);
        hipLaunchKernelGGL(kDold, dim3(NB), dim3(256), 0, stream, out, labels, token_nums,
                           trans, out + (size_t)NM * NLP);
    }
}

// Round 17
// 212.610 us; speedup vs baseline: 1.0657x; 1.0060x over previous
//
#include <hip/hip_runtime.h>
#include <hip/hip_bf16.h>
#include <math.h>

#define NB 32
#define NS 512
#define NH 1024
#define NT 37
#define NLP 39
#define NM (NB*NS)   // 16384

typedef __attribute__((ext_vector_type(8))) short bf16x8;
typedef __attribute__((ext_vector_type(4))) float f32x4;

__device__ __forceinline__ float bf2f(unsigned int u) {
    unsigned int x = u << 16;
    float f;
    __builtin_memcpy(&f, &x, 4);
    return f;
}
__device__ __forceinline__ unsigned short f2bf(float f) {
    __hip_bfloat16 hb = __float2bfloat16(f);
    unsigned short u;
    __builtin_memcpy(&u, &hb, 2);
    return u;
}
__device__ __forceinline__ unsigned int pk2(float lo, float hi) {
    return ((unsigned int)f2bf(hi) << 16) | (unsigned int)f2bf(lo);
}
// bijective XOR swizzle for [row][64B] bf16 LDS tiles
__device__ __forceinline__ int SW64(int b)  { return b ^ ((b >> 2) & 0x70); }
// tile swizzle for [128/256 row][64 k] bf16 tiles (row stride 128B)
__device__ __forceinline__ int TSW(int row, int kcolByte) {
    return (row * 128 + kcolByte) ^ ((row & 7) << 4);
}
__device__ __forceinline__ float rl(float x, int l) {
    return __int_as_float(__builtin_amdgcn_readlane(__float_as_int(x), l));
}
__device__ __forceinline__ void gld16(const void* g, void* l) {
    __builtin_amdgcn_global_load_lds((const __attribute__((address_space(1))) void*)g,
                                     (__attribute__((address_space(3))) void*)l, 16, 0, 0);
}
#define VMW(N) asm volatile("s_waitcnt vmcnt(" #N ")" ::: "memory")
#define BARR() do { __builtin_amdgcn_s_barrier(); __builtin_amdgcn_sched_barrier(0); } while (0)

// ---------------------------------------------------------------------------
// Kernel Pre (fast): fused kA1 + kW + kW2, 712 blocks x 256 thr.
// ---------------------------------------------------------------------------
__global__ __launch_bounds__(256) void kPre(const float* __restrict__ h,
                                            const float* __restrict__ bio,
                                            const float* __restrict__ Wcat,
                                            const float* __restrict__ Wcrf,
                                            unsigned short* __restrict__ attn,
                                            char* __restrict__ Asw,
                                            char* __restrict__ Wsw,
                                            unsigned short* __restrict__ WT) {
    __shared__ __align__(16) char shmem[48 * 2048];   // 96KB, aliased per branch
    const int bid = blockIdx.x;
    const int tid = threadIdx.x;

    if (bid < 256) {
        // ---------------- kA1 (64 rows) + region-0 writes ----------------
        char* Bl = shmem;
        const int lane = tid & 63;
        const int wid  = tid >> 6;          // 0..3
        const int lr   = lane & 15;
        const int lk   = lane >> 4;
        const int m0   = bid * 64;
        const int tm   = bid >> 1;                        // 128-row tile index
        const int rbase = (bid & 1) * 64 + wid * 16 + lr; // row within tile

        for (int idx = tid; idx < 37 * 256; idx += 256) {
            int t = idx >> 8, k4 = idx & 255;
            float4 v = *(const float4*)&bio[(size_t)t * NH + k4 * 4];
            int byte = (t * 2048 + k4 * 8) ^ ((t & 7) << 4);
            *(uint2*)(Bl + byte) = make_uint2(pk2(v.x, v.y), pk2(v.z, v.w));
        }
        for (int idx = tid; idx < 11 * 256; idx += 256) {
            int t = 37 + (idx >> 8), k4 = idx & 255;
            int byte = (t * 2048 + k4 * 8) ^ ((t & 7) << 4);
            *(uint2*)(Bl + byte) = make_uint2(0, 0);
        }
        __syncthreads();

        const int arow = m0 + wid * 16 + lr;
        const float* hp = h + (size_t)arow * NH + lk * 8;

        f32x4 sacc[3];
#pragma unroll
        for (int j = 0; j < 3; ++j) sacc[j] = (f32x4){0.f, 0.f, 0.f, 0.f};

        float4 p0 = *(const float4*)(hp);
        float4 p1 = *(const float4*)(hp + 4);
        for (int kt = 0; kt < NH; kt += 32) {
            float4 c0 = p0, c1 = p1;
            if (kt + 32 < NH) {
                p0 = *(const float4*)(hp + kt + 32);
                p1 = *(const float4*)(hp + kt + 36);
            }
            union { unsigned int u[4]; bf16x8 v; uint4 q; } af;
            af.u[0] = pk2(c0.x, c0.y); af.u[1] = pk2(c0.z, c0.w);
            af.u[2] = pk2(c1.x, c1.y); af.u[3] = pk2(c1.z, c1.w);
            {
                int kg = kt + lk * 8;
                size_t tb = ((size_t)tm * 48 + (kg >> 6)) * 16384;
                *(uint4*)(Asw + tb + TSW(rbase, (kg & 63) * 2)) = af.q;
            }
#pragma unroll
            for (int nf = 0; nf < 3; ++nf) {
                int t = nf * 16 + lr;
                int byte = (t * 2048 + (kt + lk * 8) * 2) ^ ((t & 7) << 4);
                bf16x8 bf = *(const bf16x8*)(Bl + byte);
                sacc[nf] = __builtin_amdgcn_mfma_f32_16x16x32_bf16(af.v, bf, sacc[nf], 0, 0, 0);
            }
        }

#pragma unroll
        for (int r = 0; r < 4; ++r) {
            const int orow = wid * 16 + lk * 4 + r;
            float s0 = sacc[0][r] * 0.03125f;
            float s1 = sacc[1][r] * 0.03125f;
            float s2 = sacc[2][r] * 0.03125f;
            const bool v2 = (lr < 5);
            float mx = fmaxf(fmaxf(s0, s1), v2 ? s2 : -1e30f);
#pragma unroll
            for (int d = 1; d < 16; d <<= 1) mx = fmaxf(mx, __shfl_xor(mx, d, 64));
            float e0 = __expf(s0 - mx), e1 = __expf(s1 - mx);
            float e2 = v2 ? __expf(s2 - mx) : 0.f;
            float sm = e0 + e1 + e2;
#pragma unroll
            for (int d = 1; d < 16; d <<= 1) sm += __shfl_xor(sm, d, 64);
            float inv = 1.f / sm;
            size_t g = (size_t)(m0 + orow) * 64;
            attn[g + lr]      = f2bf(e0 * inv);
            attn[g + 16 + lr] = f2bf(e1 * inv);
            attn[g + 32 + lr] = f2bf(e2 * inv);
            attn[g + 48 + lr] = 0;
        }
    } else if (bid < 640) {
        // ---------------- kW: Wcat -> Wsw swizzled tiles ----------------
        unsigned short* wt = (unsigned short*)shmem;   // 16KB
        const int tile = bid - 256;
        const int tn   = tile / 48;
        const int tk   = tile - tn * 48;
        const int n00  = tn * 128;
        const int k0   = tk * 64;

        for (int lin = tid; lin < 2048; lin += 256) {
            int kk = lin >> 5, ng = lin & 31;
            float4 v = *(const float4*)&Wcat[(size_t)(k0 + kk) * NH + n00 + ng * 4];
            *(uint2*)&wt[kk * 128 + ng * 4] = make_uint2(pk2(v.x, v.y), pk2(v.z, v.w));
        }
        __syncthreads();
        for (int lin = tid; lin < 1024; lin += 256) {
            int rn = lin >> 3, kg = lin & 7;
            unsigned short t8[8];
#pragma unroll
            for (int j = 0; j < 8; ++j) t8[j] = wt[(kg * 8 + j) * 128 + rn];
            uint4 v;
            __builtin_memcpy(&v, t8, 16);
            *(uint4*)(Wsw + (size_t)tile * 16384 + TSW(rn, kg * 16)) = v;
        }
    } else {
        // ---------------- kW2: Wcrf^T prepack ----------------
        const int idx = (bid - 640) * 256 + tid;
        if (idx < 48 * 384) {
            const int t = idx / 384, kg = idx - t * 384;
            unsigned short v[8];
#pragma unroll
            for (int e = 0; e < 8; ++e) {
                int k = kg * 8 + e;
                v[e] = (t < NT) ? f2bf(Wcrf[(size_t)k * NT + t]) : (unsigned short)0;
            }
            uint4 w;
            __builtin_memcpy(&w, v, 16);
            *(uint4*)(WT + (size_t)t * 3072 + kg * 8) = w;
        }
    }
}

// ---------------------------------------------------------------------------
// Kernel A1 (fallback): scores -> softmax -> attn only.
// ---------------------------------------------------------------------------
__global__ __launch_bounds__(512) void kA1(const float* __restrict__ h,
                                           const float* __restrict__ bio,
                                           unsigned short* __restrict__ attn) {
    __shared__ __align__(16) char Bl[48 * 2048];

    const int tid  = threadIdx.x;
    const int lane = tid & 63;
    const int wid  = tid >> 6;
    const int lr   = lane & 15;
    const int lk   = lane >> 4;
    const int m0   = blockIdx.x * 128;

    for (int idx = tid; idx < 37 * 256; idx += 512) {
        int t = idx >> 8, k4 = idx & 255;
        float4 v = *(const float4*)&bio[(size_t)t * NH + k4 * 4];
        int byte = (t * 2048 + k4 * 8) ^ ((t & 7) << 4);
        *(uint2*)(Bl + byte) = make_uint2(pk2(v.x, v.y), pk2(v.z, v.w));
    }
    for (int idx = tid; idx < 11 * 256; idx += 512) {
        int t = 37 + (idx >> 8), k4 = idx & 255;
        int byte = (t * 2048 + k4 * 8) ^ ((t & 7) << 4);
        *(uint2*)(Bl + byte) = make_uint2(0, 0);
    }
    __syncthreads();

    const int arow = m0 + wid * 16 + lr;
    const float* hp = h + (size_t)arow * NH + lk * 8;

    f32x4 sacc[3];
#pragma unroll
    for (int j = 0; j < 3; ++j) sacc[j] = (f32x4){0.f, 0.f, 0.f, 0.f};

    float4 p0 = *(const float4*)(hp);
    float4 p1 = *(const float4*)(hp + 4);
    for (int kt = 0; kt < NH; kt += 32) {
        float4 c0 = p0, c1 = p1;
        if (kt + 32 < NH) {
            p0 = *(const float4*)(hp + kt + 32);
            p1 = *(const float4*)(hp + kt + 36);
        }
        union { unsigned int u[4]; bf16x8 v; } af;
        af.u[0] = pk2(c0.x, c0.y); af.u[1] = pk2(c0.z, c0.w);
        af.u[2] = pk2(c1.x, c1.y); af.u[3] = pk2(c1.z, c1.w);
#pragma unroll
        for (int nf = 0; nf < 3; ++nf) {
            int t = nf * 16 + lr;
            int byte = (t * 2048 + (kt + lk * 8) * 2) ^ ((t & 7) << 4);
            bf16x8 bf = *(const bf16x8*)(Bl + byte);
            sacc[nf] = __builtin_amdgcn_mfma_f32_16x16x32_bf16(af.v, bf, sacc[nf], 0, 0, 0);
        }
    }

#pragma unroll
    for (int r = 0; r < 4; ++r) {
        const int orow = wid * 16 + lk * 4 + r;
        float s0 = sacc[0][r] * 0.03125f;
        float s1 = sacc[1][r] * 0.03125f;
        float s2 = sacc[2][r] * 0.03125f;
        const bool v2 = (lr < 5);
        float mx = fmaxf(fmaxf(s0, s1), v2 ? s2 : -1e30f);
#pragma unroll
        for (int d = 1; d < 16; d <<= 1) mx = fmaxf(mx, __shfl_xor(mx, d, 64));
        float e0 = __expf(s0 - mx), e1 = __expf(s1 - mx);
        float e2 = v2 ? __expf(s2 - mx) : 0.f;
        float sm = e0 + e1 + e2;
#pragma unroll
        for (int d = 1; d < 16; d <<= 1) sm += __shfl_xor(sm, d, 64);
        float inv = 1.f / sm;
        size_t g = (size_t)(m0 + orow) * 64;
        attn[g + lr]      = f2bf(e0 * inv);
        attn[g + 16 + lr] = f2bf(e1 * inv);
        attn[g + 32 + lr] = f2bf(e2 * inv);
        attn[g + 48 + lr] = 0;
    }
}

// ---------------------------------------------------------------------------
// Kernel A2 (fallback): aware = attn @ bio, plain bf16 row-major out.
// ---------------------------------------------------------------------------
__global__ __launch_bounds__(256) void kA2(const unsigned short* __restrict__ attn,
                                           const float* __restrict__ bio,
                                           unsigned short* __restrict__ aware) {
    __shared__ __align__(16) char Bsl[128 * 64];

    const int tid  = threadIdx.x;
    const int lane = tid & 63;
    const int wid  = tid >> 6;
    const int wm   = (wid >> 1) * 64;
    const int wn   = (wid & 1) * 64;
    const int lr   = lane & 15;
    const int lk   = lane >> 4;
    const int n0   = blockIdx.x * 128;
    const int m0   = blockIdx.y * 128;

    const int bn = tid & 127;
    const int bq = (tid >> 7) * 16;

    f32x4 acc[4][4];
#pragma unroll
    for (int i = 0; i < 4; ++i)
#pragma unroll
        for (int j = 0; j < 4; ++j) acc[i][j] = (f32x4){0.f, 0.f, 0.f, 0.f};

#pragma unroll
    for (int ks = 0; ks < 2; ++ks) {
        unsigned int p[8];
#pragma unroll
        for (int i = 0; i < 8; ++i) {
            int t0 = ks*32 + bq + 2*i;
            float lo = (t0     < NT) ? bio[(size_t)t0 * NH + n0 + bn]       : 0.f;
            float hi = (t0 + 1 < NT) ? bio[(size_t)(t0+1) * NH + n0 + bn]   : 0.f;
            p[i] = pk2(lo, hi);
        }
        __syncthreads();
        *(int4*)(Bsl + SW64(bn*64 + bq*2))      = make_int4(p[0], p[1], p[2], p[3]);
        *(int4*)(Bsl + SW64(bn*64 + bq*2 + 16)) = make_int4(p[4], p[5], p[6], p[7]);
        __syncthreads();

        bf16x8 af[4];
#pragma unroll
        for (int mf = 0; mf < 4; ++mf)
            af[mf] = *(const bf16x8*)(attn + (size_t)(m0 + wm + mf*16 + lr) * 64 + ks*32 + lk*8);
#pragma unroll
        for (int nf = 0; nf < 4; ++nf) {
            bf16x8 bb = *(const bf16x8*)(Bsl + SW64((wn + nf*16 + lr)*64 + lk*16));
#pragma unroll
            for (int mf = 0; mf < 4; ++mf)
                acc[mf][nf] = __builtin_amdgcn_mfma_f32_16x16x32_bf16(af[mf], bb, acc[mf][nf], 0, 0, 0);
        }
    }

#pragma unroll
    for (int mf = 0; mf < 4; ++mf)
#pragma unroll
        for (int nf = 0; nf < 4; ++nf)
#pragma unroll
            for (int r = 0; r < 4; ++r) {
                size_t row = (size_t)(m0 + wm + mf*16 + lk*4 + r);
                aware[row * NH + n0 + wn + nf*16 + lr] = f2bf(acc[mf][nf][r]);
            }
}

// ---------------------------------------------------------------------------
// Kernel A2f (fast, v2): computes aware chunk; reads h as bf16 from Asw
// region 0 (written by kPre); writes only regions 1 (aware) and 2 (h*aware).
// ---------------------------------------------------------------------------
__global__ __launch_bounds__(256) void kA2f(const unsigned short* __restrict__ attn,
                                            const float* __restrict__ bio,
                                            char* __restrict__ Asw) {
    __shared__ __align__(16) char Bsl[128 * 64];
    __shared__ __align__(16) unsigned short awL[128 * 128];  // 32KB aware chunk

    const int tid  = threadIdx.x;
    const int lane = tid & 63;
    const int wid  = tid >> 6;
    const int wm   = (wid >> 1) * 64;
    const int wn   = (wid & 1) * 64;
    const int lr   = lane & 15;
    const int lk   = lane >> 4;
    const int n0   = blockIdx.x * 128;
    const int m0   = blockIdx.y * 128;
    const int tm   = blockIdx.y;

    const int bn = tid & 127;
    const int bq = (tid >> 7) * 16;

    f32x4 acc[4][4];
#pragma unroll
    for (int i = 0; i < 4; ++i)
#pragma unroll
        for (int j = 0; j < 4; ++j) acc[i][j] = (f32x4){0.f, 0.f, 0.f, 0.f};

#pragma unroll
    for (int ks = 0; ks < 2; ++ks) {
        unsigned int p[8];
#pragma unroll
        for (int i = 0; i < 8; ++i) {
            int t0 = ks*32 + bq + 2*i;
            float lo = (t0     < NT) ? bio[(size_t)t0 * NH + n0 + bn]       : 0.f;
            float hi = (t0 + 1 < NT) ? bio[(size_t)(t0+1) * NH + n0 + bn]   : 0.f;
            p[i] = pk2(lo, hi);
        }
        __syncthreads();
        *(int4*)(Bsl + SW64(bn*64 + bq*2))      = make_int4(p[0], p[1], p[2], p[3]);
        *(int4*)(Bsl + SW64(bn*64 + bq*2 + 16)) = make_int4(p[4], p[5], p[6], p[7]);
        __syncthreads();

        bf16x8 af[4];
#pragma unroll
        for (int mf = 0; mf < 4; ++mf)
            af[mf] = *(const bf16x8*)(attn + (size_t)(m0 + wm + mf*16 + lr) * 64 + ks*32 + lk*8);
#pragma unroll
        for (int nf = 0; nf < 4; ++nf) {
            bf16x8 bb = *(const bf16x8*)(Bsl + SW64((wn + nf*16 + lr)*64 + lk*16));
#pragma unroll
            for (int mf = 0; mf < 4; ++mf)
                acc[mf][nf] = __builtin_amdgcn_mfma_f32_16x16x32_bf16(af[mf], bb, acc[mf][nf], 0, 0, 0);
        }
    }

#pragma unroll
    for (int mf = 0; mf < 4; ++mf)
#pragma unroll
        for (int nf = 0; nf < 4; ++nf)
#pragma unroll
            for (int r = 0; r < 4; ++r)
                awL[(wm + mf*16 + lk*4 + r) * 128 + wn + nf*16 + lr] = f2bf(acc[mf][nf][r]);
    __syncthreads();

    // region 1 (aware)
#pragma unroll
    for (int i = 0; i < 8; ++i) {
        int lin = tid + i * 256;
        int row = lin >> 4, kg = lin & 15;
        uint4 v = *(const uint4*)&awL[row * 128 + kg * 8];
        int kglob = 1024 + n0 + kg * 8;
        size_t tbase = ((size_t)tm * 48 + (kglob >> 6)) * 16384;
        *(uint4*)(Asw + tbase + TSW(row, (kglob & 63) * 2)) = v;
    }
    // region 2 (h*aware), h read back as bf16 from region 0
#pragma unroll
    for (int i = 0; i < 8; ++i) {
        int lin = tid + i * 256;
        int row = lin >> 4, kg = lin & 15;
        int k0g = n0 + kg * 8;
        size_t tb0 = ((size_t)tm * 48 + (k0g >> 6)) * 16384;
        uint4 hv4 = *(const uint4*)(Asw + tb0 + TSW(row, (k0g & 63) * 2));
        unsigned int hu[4] = {hv4.x, hv4.y, hv4.z, hv4.w};
        uint4 awv = *(const uint4*)&awL[row * 128 + kg * 8];
        unsigned int awu[4] = {awv.x, awv.y, awv.z, awv.w};
        unsigned int p2[4];
#pragma unroll
        for (int j = 0; j < 4; ++j) {
            float lo = bf2f(hu[j] & 0xffffu) * bf2f(awu[j] & 0xffffu);
            float hi = bf2f(hu[j] >> 16)     * bf2f(awu[j] >> 16);
            p2[j] = pk2(lo, hi);
        }
        int k2g = 2048 + n0 + kg * 8;
        size_t tb2 = ((size_t)tm * 48 + (k2g >> 6)) * 16384;
        *(uint4*)(Asw + tb2 + TSW(row, (k2g & 63) * 2)) = make_uint4(p2[0], p2[1], p2[2], p2[3]);
    }
}

// ---------------------------------------------------------------------------
// Kernel Bf (fast): 256x256 tile bf16 GEMM, BK=64, 8 waves. Round-17 schedule:
// reads issued BEFORE the phase barrier (latency rides across it, m201 style),
// ONE counted vmcnt per K-tile (VMW(2): after issuing stage(T+1,0), waiting to
// <=2 outstanding confirms all 4 of tile T's halves). WAR guard: buf-q reads
// are register-consumed by mma10 before barrier #4; tile T+2's buf-q writes
// issue after it. + fused kC epilogue (prepacked Wcrf^T).
// ---------------------------------------------------------------------------
__global__ __launch_bounds__(512, 2) void kBf(const char* __restrict__ Asw,
                                              const char* __restrict__ Wsw,
                                              const float* __restrict__ bcat,
                                              const unsigned short* __restrict__ WT,
                                              float* __restrict__ P) {
    __shared__ __align__(16) char lds[131072];  // A: buf*32768+h*16384; B at +65536

    const int tid  = threadIdx.x;
    const int lane = tid & 63;
    const int wid  = tid >> 6;
    const int widm = wid >> 2;       // 0..1
    const int widn = wid & 3;        // 0..3
    const int lr   = lane & 15;
    const int lk   = lane >> 4;

    const int id   = blockIdx.x;     // 256 blocks
    const int xcd  = id & 7;
    const int slot = id >> 3;        // 0..31
    const int Mt   = xcd * 8 + (slot >> 2);
    const int Nt   = slot & 3;
    const int m0   = Mt * 256, n0 = Nt * 256;
    const int soff = tid * 16;

    f32x4 acc00[4][2], acc01[4][2], acc10[4][2], acc11[4][2];
#pragma unroll
    for (int i = 0; i < 4; ++i)
#pragma unroll
        for (int j = 0; j < 2; ++j) {
            acc00[i][j] = (f32x4){0.f,0.f,0.f,0.f};
            acc01[i][j] = (f32x4){0.f,0.f,0.f,0.f};
            acc10[i][j] = (f32x4){0.f,0.f,0.f,0.f};
            acc11[i][j] = (f32x4){0.f,0.f,0.f,0.f};
        }

    auto stageHalf = [&](int T, int ph) {
        const bool isA = (ph == 0) || (ph == 3);
        const int  h   = isA ? (ph == 3 ? 1 : 0) : (ph - 1);
        const char* src = isA
            ? Asw + ((size_t)((2*Mt + h) * 48 + T)) * 16384
            : Wsw + ((size_t)((2*Nt + h) * 48 + T)) * 16384;
        char* dst = lds + (isA ? 0 : 65536) + (T & 1) * 32768 + h * 16384;
        gld16(src + soff,        dst + soff);
        gld16(src + soff + 8192, dst + soff + 8192);
    };
    auto loadA = [&](bf16x8 (&af)[4][2], int q, int half) {
        const char* base = lds + q * 32768 + half * 16384;
#pragma unroll
        for (int i = 0; i < 4; ++i) {
            int row = widm * 64 + i * 16 + lr;
#pragma unroll
            for (int kk = 0; kk < 2; ++kk)
                af[i][kk] = *(const bf16x8*)(base + TSW(row, kk * 64 + lk * 16));
        }
    };
    auto loadB = [&](bf16x8 (&bfr)[2][2], int q, int half) {
        const char* base = lds + 65536 + q * 32768 + half * 16384;
#pragma unroll
        for (int j = 0; j < 2; ++j) {
            int col = widn * 32 + j * 16 + lr;
#pragma unroll
            for (int kk = 0; kk < 2; ++kk)
                bfr[j][kk] = *(const bf16x8*)(base + TSW(col, kk * 64 + lk * 16));
        }
    };
    auto mma = [&](f32x4 (&ac)[4][2], bf16x8 (&af)[4][2], bf16x8 (&bfr)[2][2]) {
        __builtin_amdgcn_s_setprio(1);
#pragma unroll
        for (int kk = 0; kk < 2; ++kk)
#pragma unroll
            for (int i = 0; i < 4; ++i)
#pragma unroll
                for (int j = 0; j < 2; ++j)
                    ac[i][j] = __builtin_amdgcn_mfma_f32_16x16x32_bf16(
                        af[i][kk], bfr[j][kk], ac[i][j], 0, 0, 0);
        __builtin_amdgcn_s_setprio(0);
    };

    // prologue: stage tile 0 fully, drain once
    stageHalf(0, 0); stageHalf(0, 1); stageHalf(0, 2); stageHalf(0, 3);
    VMW(0);
    BARR();

    for (int T = 0; T < 48; ++T) {
        const int q = T & 1;
        const bool pf = (T + 1 < 48);
        bf16x8 af0[4][2], af1[4][2], bf0[2][2], bf1[2][2];

        // ready check for buf q (tile T): T==0 covered by prologue drain.
        if (T > 0) {
            if (pf) { stageHalf(T + 1, 0); VMW(2); }
            else    { VMW(0); }
            BARR();
        } else if (pf) {
            stageHalf(T + 1, 0);
        }

        // ph0: reads, stage, barrier -> mma
        loadA(af0, q, 0); loadB(bf0, q, 0);
        if (pf) stageHalf(T + 1, 1);
        BARR();
        mma(acc00, af0, bf0);

        // ph1
        loadB(bf1, q, 1);
        if (pf) stageHalf(T + 1, 2);
        BARR();
        mma(acc01, af0, bf1);

        // ph2
        loadA(af1, q, 1);
        if (pf) stageHalf(T + 1, 3);
        BARR();
        mma(acc10, af1, bf0);

        // ph3: WAR guard barrier (all buf-q reads consumed by mma10)
        BARR();
        mma(acc11, af1, bf1);
    }

    // ---------------- fused kC epilogue ----------------
    __syncthreads();
    auto stashQ = [&](f32x4 (&ac)[4][2], int a, int b) {
#pragma unroll
        for (int j = 0; j < 2; ++j) {
            const int lcol = b * 128 + widn * 32 + j * 16 + lr;
            const int kc = lcol >> 6, kk = lcol & 63;
            const float bc = bcat[n0 + lcol];
#pragma unroll
            for (int i = 0; i < 4; ++i)
#pragma unroll
                for (int r = 0; r < 4; ++r) {
                    int lrow = a * 128 + widm * 64 + i * 16 + lk * 4 + r;
                    float x = ac[i][j][r] + bc;
                    float g = 0.5f * x * (1.0f + erff(x * 0.70710678118654752f));
                    *(unsigned short*)(lds + kc * 32768 + TSW(lrow, kk * 2)) = f2bf(g);
                }
        }
    };
    stashQ(acc00, 0, 0); stashQ(acc01, 0, 1); stashQ(acc10, 1, 0); stashQ(acc11, 1, 1);
    __syncthreads();

    bf16x8 wfrag[3][8];
#pragma unroll
    for (int tt = 0; tt < 3; ++tt) {
        const int t = tt * 16 + lr;
#pragma unroll
        for (int ks = 0; ks < 8; ++ks)
            wfrag[tt][ks] = *(const bf16x8*)(WT + (size_t)t * 3072 + n0 + ks * 32 + lk * 8);
    }

    f32x4 pacc[2][3];
#pragma unroll
    for (int i = 0; i < 2; ++i)
#pragma unroll
        for (int j = 0; j < 3; ++j) pacc[i][j] = (f32x4){0.f, 0.f, 0.f, 0.f};
#pragma unroll
    for (int rt2 = 0; rt2 < 2; ++rt2) {
        const int lrow = wid * 32 + rt2 * 16 + lr;
#pragma unroll
        for (int ks = 0; ks < 8; ++ks) {
            const int kc = ks >> 1, kh = ks & 1;
            bf16x8 af = *(const bf16x8*)(lds + kc * 32768 + TSW(lrow, kh * 64 + lk * 16));
#pragma unroll
            for (int tt = 0; tt < 3; ++tt)
                pacc[rt2][tt] = __builtin_amdgcn_mfma_f32_16x16x32_bf16(
                    af, wfrag[tt][ks], pacc[rt2][tt], 0, 0, 0);
        }
    }

    float* Pb = P + (size_t)Nt * NM * 48;
#pragma unroll
    for (int rt2 = 0; rt2 < 2; ++rt2)
#pragma unroll
        for (int tt = 0; tt < 3; ++tt)
#pragma unroll
            for (int r = 0; r < 4; ++r) {
                int row = Mt * 256 + wid * 32 + rt2 * 16 + lk * 4 + r;
                Pb[(size_t)row * 48 + tt * 16 + lr] = pacc[rt2][tt][r];
            }
}

// ---------------------------------------------------------------------------
// Kernel DmCr (fast): fused kCr + kDm (round-16 proven).
// ---------------------------------------------------------------------------
__global__ __launch_bounds__(256) void kDmCr(const float* __restrict__ P,
                                             const float* __restrict__ bcrf,
                                             const int* __restrict__ lens,
                                             const float* __restrict__ trans,
                                             float* __restrict__ out,
                                             float* __restrict__ Pm,
                                             float* __restrict__ Pc) {
    __shared__ float el_all[64 * 64];
    __shared__ __align__(16) char Mb[2 * 6144];

    const int tid = threadIdx.x;
    const int b   = blockIdx.x >> 3;
    const int s   = blockIdx.x & 7;
    const int t0  = s * 64;
    const size_t STRIDE = (size_t)NM * 48;

    {
        const int i  = tid >> 2;
        const int tg = (tid & 3) * 12;
        const int gr = b * NS + t0 + i;
#pragma unroll
        for (int j = 0; j < 12; ++j) {
            int t = tg + j;
            size_t flat = (size_t)gr * 48 + t;
            float v = P[flat] + P[STRIDE + flat] + P[2*STRIDE + flat] + P[3*STRIDE + flat];
            float o, el;
            if (t < NT) { o = v + bcrf[t]; el = __expf(o); }
            else        { o = -10000.0f;   el = 0.f; }
            if (t < NLP) out[(size_t)gr * NLP + t] = o;
            el_all[i * 64 + t] = el;
        }
    }
    for (int z = tid; z < 64 * 16; z += 256)
        el_all[(z >> 4) * 64 + 48 + (z & 15)] = 0.f;
    __syncthreads();

    if (tid >= 64) return;

    const int lane = tid;
    const int lr   = lane & 15;
    const int lk   = lane >> 4;
    const int len  = lens[b];
    const int nsteps = (len > t0) ? ((len - t0 < 64) ? (len - t0) : 64) : 0;
    float* Pg = Pm + (size_t)(b * 8 + s) * 2304;

    if (nsteps == 0) {
        for (int j = 0; j < 36; ++j) Pg[j * 64 + lane] = 0.f;
        if (lane < 48) Pg[lane * 48 + lane] = 1.f;
        if (lane == 0) Pc[b * 8 + s] = 0.f;
        return;
    }

    bf16x8 Tf[3][2];
#pragma unroll
    for (int tt = 0; tt < 3; ++tt)
#pragma unroll
        for (int ks = 0; ks < 2; ++ks) {
            const int row = tt * 16 + lr;
            unsigned int u[4];
#pragma unroll
            for (int e2 = 0; e2 < 4; ++e2) {
                int f0 = ks * 32 + lk * 8 + 2 * e2;
                float lo = (row < NLP && f0     < NLP) ? __expf(trans[row * NLP + f0])     : 0.f;
                float hi = (row < NLP && f0 + 1 < NLP) ? __expf(trans[row * NLP + f0 + 1]) : 0.f;
                u[e2] = pk2(lo, hi);
            }
            union { unsigned int uu[4]; bf16x8 v; } cv;
            cv.uu[0]=u[0]; cv.uu[1]=u[1]; cv.uu[2]=u[2]; cv.uu[3]=u[3];
            Tf[tt][ks] = cv.v;
        }

    for (int j = 0; j < 48; ++j)
        *(unsigned int*)(Mb + j * 256 + lane * 4) = 0;
    if (lane < 48) {
        int byte = (lane * 128 + lane * 2) ^ ((lane & 7) << 4);
        *(unsigned short*)(Mb + byte) = f2bf(1.0f);
    }

    float Cacc = 0.f;

    for (int i = 0; i < nsteps; ++i) {
        const int q = i & 1;
        const char* Mr = Mb + q * 6144;

        bf16x8 Bf[3][2];
#pragma unroll
        for (int ct = 0; ct < 3; ++ct) {
#pragma unroll
            for (int ks = 0; ks < 2; ++ks) {
                int col = ct * 16 + lr;
                int byte = (col * 128 + (ks * 32 + lk * 8) * 2) ^ ((col & 7) << 4);
                Bf[ct][ks] = *(const bf16x8*)(Mr + byte);
            }
        }
        f32x4 el4[3];
#pragma unroll
        for (int tt = 0; tt < 3; ++tt)
            el4[tt] = *(const f32x4*)&el_all[i * 64 + tt * 16 + lk * 4];

        f32x4 c[3][3];
#pragma unroll
        for (int tt = 0; tt < 3; ++tt)
#pragma unroll
            for (int ct = 0; ct < 3; ++ct) {
                c[tt][ct] = __builtin_amdgcn_mfma_f32_16x16x32_bf16(
                    Tf[tt][0], Bf[ct][0], (f32x4){0.f,0.f,0.f,0.f}, 0, 0, 0);
                c[tt][ct] = __builtin_amdgcn_mfma_f32_16x16x32_bf16(
                    Tf[tt][1], Bf[ct][1], c[tt][ct], 0, 0, 0);
            }
#pragma unroll
        for (int tt = 0; tt < 3; ++tt)
#pragma unroll
            for (int ct = 0; ct < 3; ++ct)
#pragma unroll
                for (int r = 0; r < 4; ++r)
                    c[tt][ct][r] *= el4[tt][r];

        if ((i & 3) == 3) {
            float sv = rl(c[0][0][0], 0);
            float rr = __builtin_amdgcn_rcpf(sv);
#pragma unroll
            for (int tt = 0; tt < 3; ++tt)
#pragma unroll
                for (int ct = 0; ct < 3; ++ct)
#pragma unroll
                    for (int r = 0; r < 4; ++r) c[tt][ct][r] *= rr;
            Cacc -= __logf(rr);
        }

        if (i == nsteps - 1) {
#pragma unroll
            for (int tt = 0; tt < 3; ++tt)
#pragma unroll
                for (int ct = 0; ct < 3; ++ct)
#pragma unroll
                    for (int r = 0; r < 4; ++r) {
                        int row = tt * 16 + lk * 4 + r;
                        int col = ct * 16 + lr;
                        Pg[row * 48 + col] = c[tt][ct][r];
                    }
        } else {
            char* Mw = Mb + (q ^ 1) * 6144;
#pragma unroll
            for (int tt = 0; tt < 3; ++tt)
#pragma unroll
                for (int ct = 0; ct < 3; ++ct) {
                    int col = ct * 16 + lr;
                    int k   = tt * 16 + lk * 4;
                    int byte = (col * 128 + k * 2) ^ ((col & 7) << 4);
                    *(uint2*)(Mw + byte) = make_uint2(pk2(c[tt][ct][0], c[tt][ct][1]),
                                                      pk2(c[tt][ct][2], c[tt][ct][3]));
                }
        }
    }

    if (lane == 0) Pc[b * 8 + s] = Cacc;
}

// ---------------------------------------------------------------------------
// Kernel Dc: combine (round-13 proven).
// ---------------------------------------------------------------------------
__global__ __launch_bounds__(256) void kDc(const float* __restrict__ scores,
                                           const int* __restrict__ labels,
                                           const int* __restrict__ lens,
                                           const float* __restrict__ trans,
                                           const float* __restrict__ Pm,
                                           const float* __restrict__ Pc,
                                           float* __restrict__ loss) {
    __shared__ float trL[39 * 41];
    __shared__ float gred[4];

    const int b    = blockIdx.x;
    const int tid  = threadIdx.x;
    const int lane = tid & 63;
    const int wid  = tid >> 6;
    const int len  = lens[b];
    const float* sb = scores + (size_t)b * NS * NLP;

    for (int idx = tid; idx < 39 * 39; idx += 256) {
        int to = idx / 39, f = idx - to * 39;
        trL[to * 41 + f] = trans[idx];
    }
    __syncthreads();

    float g = 0.0f;
    for (int t = tid; t < len; t += 256) g += sb[(size_t)t * NLP + labels[b * NS + t]];
    for (int i = tid; i <= len; i += 256) {
        int frm = (i == 0) ? 37 : labels[b * NS + i - 1];
        int to  = (i == len) ? 38 : labels[b * NS + i];
        g += trL[to * 41 + frm];
    }
#pragma unroll
    for (int off = 32; off > 0; off >>= 1) g += __shfl_xor(g, off, 64);
    if (lane == 0) gred[wid] = g;
    __syncthreads();

    if (wid != 0) return;

    const float gold = (gred[0] + gred[1]) + (gred[2] + gred[3]);
    const bool act48 = (lane < 48);

    const float* P0 = Pm + (size_t)b * 8 * 2304;
    float v = act48 ? P0[lane * 48 + 37] : 0.f;
    float C = Pc[b * 8];

    for (int s = 1; s < 8; ++s) {
        float as_[40];
#pragma unroll
        for (int f = 0; f < 40; ++f) as_[f] = rl(v, f);
        __builtin_amdgcn_sched_barrier(0);
        const float* Ps = Pm + (size_t)(b * 8 + s) * 2304;
        float c = 0.f;
        if (act48) {
            const float4* rowp = (const float4*)(Ps + lane * 48);
#pragma unroll
            for (int q = 0; q < 10; ++q) {
                float4 rv = rowp[q];
                c = fmaf(rv.x, as_[q*4+0], c);
                c = fmaf(rv.y, as_[q*4+1], c);
                c = fmaf(rv.z, as_[q*4+2], c);
                c = fmaf(rv.w, as_[q*4+3], c);
            }
        }
        float sv = rl(c, 0);
        float rr = __builtin_amdgcn_rcpf(sv);
        v = c * rr;
        C -= __logf(rr);
        C += Pc[b * 8 + s];
    }

    const float trEnd = (lane < NLP) ? trL[38 * 41 + lane] : 0.f;
    float aend = (lane < NLP && v > 0.f) ? C + __logf(v) + trEnd : -1e30f;
    float mx = aend;
#pragma unroll
    for (int off = 32; off > 0; off >>= 1) mx = fmaxf(mx, __shfl_xor(mx, off, 64));
    float es = (lane < NLP) ? __expf(aend - mx) : 0.f;
#pragma unroll
    for (int off = 32; off > 0; off >>= 1) es += __shfl_xor(es, off, 64);
    float norm = mx + __logf(es);

    if (lane == 0) loss[b] = gold - norm;
}

// ---------------------------------------------------------------------------
// Kernel B (fallback): reg-staged mixed GEMM (round-4 version).
// ---------------------------------------------------------------------------
__global__ __launch_bounds__(256) void kB(const float* __restrict__ h,
                                          const unsigned short* __restrict__ aware,
                                          const float* __restrict__ Wcat,
                                          const float* __restrict__ bcat,
                                          unsigned short* __restrict__ x2) {
    __shared__ __align__(16) char lds[16384];
    char* Asl = lds;
    char* Bsl = lds + 8192;

    const int tid  = threadIdx.x;
    const int lane = tid & 63;
    const int wid  = tid >> 6;
    const int wm   = (wid >> 1) * 64;
    const int wn   = (wid & 1) * 64;
    const int lr   = lane & 15;
    const int lk   = lane >> 4;

    const int id   = blockIdx.x;
    const int xcd  = id & 7;
    const int slot = id >> 3;
    const int m0   = (xcd * 16 + (slot >> 3)) * 128;
    const int n0   = (slot & 7) * 128;

    const int am = tid >> 1;
    const int ak = (tid & 1) * 16;
    const int bn = tid & 127;
    const int bk = (tid >> 7) * 16;

    f32x4 acc[4][4];
#pragma unroll
    for (int i = 0; i < 4; ++i)
#pragma unroll
        for (int j = 0; j < 4; ++j) acc[i][j] = (f32x4){0.f, 0.f, 0.f, 0.f};

    const float*          hrow = h     + (size_t)(m0 + am) * NH + ak;
    const unsigned short* arow = aware + (size_t)(m0 + am) * NH + ak;
    const float*          wcol = Wcat  + (size_t)bk * NH + n0 + bn;

    float hv[16];
    unsigned int aw[8];
    float wv[16];

    auto stage = [&](int kt) {
        const int region = kt >> 10;
        const int kb = kt & 1023;
        if (region != 1) {
            const float4* hp = (const float4*)(hrow + kb);
            float4 a = hp[0], b = hp[1], c = hp[2], d = hp[3];
            hv[0]=a.x; hv[1]=a.y; hv[2]=a.z; hv[3]=a.w;
            hv[4]=b.x; hv[5]=b.y; hv[6]=b.z; hv[7]=b.w;
            hv[8]=c.x; hv[9]=c.y; hv[10]=c.z; hv[11]=c.w;
            hv[12]=d.x; hv[13]=d.y; hv[14]=d.z; hv[15]=d.w;
        }
        if (region >= 1) {
            const uint4* ap = (const uint4*)(arow + kb);
            uint4 a0 = ap[0], a1 = ap[1];
            aw[0]=a0.x; aw[1]=a0.y; aw[2]=a0.z; aw[3]=a0.w;
            aw[4]=a1.x; aw[5]=a1.y; aw[6]=a1.z; aw[7]=a1.w;
        }
        {
            const float* wp = wcol + (size_t)kt * NH;
#pragma unroll
            for (int j = 0; j < 16; ++j) wv[j] = wp[(size_t)j * NH];
        }
    };

    auto writeStage = [&](int kt) {
        const int region = kt >> 10;
        unsigned int p[8];
        if (region == 0) {
#pragma unroll
            for (int i = 0; i < 8; ++i) p[i] = pk2(hv[2*i], hv[2*i+1]);
        } else if (region == 1) {
#pragma unroll
            for (int i = 0; i < 8; ++i) p[i] = aw[i];
        } else {
#pragma unroll
            for (int i = 0; i < 8; ++i) {
                float lo = hv[2*i]   * bf2f(aw[i] & 0xffffu);
                float hi = hv[2*i+1] * bf2f(aw[i] >> 16);
                p[i] = pk2(lo, hi);
            }
        }
        *(int4*)(Asl + SW64(am*64 + ak*2))      = make_int4(p[0], p[1], p[2], p[3]);
        *(int4*)(Asl + SW64(am*64 + ak*2 + 16)) = make_int4(p[4], p[5], p[6], p[7]);
        unsigned int q[8];
#pragma unroll
        for (int i = 0; i < 8; ++i) q[i] = pk2(wv[2*i], wv[2*i+1]);
        *(int4*)(Bsl + SW64(bn*64 + bk*2))      = make_int4(q[0], q[1], q[2], q[3]);
        *(int4*)(Bsl + SW64(bn*64 + bk*2 + 16)) = make_int4(q[4], q[5], q[6], q[7]);
    };

    stage(0);
    for (int kt = 0; kt < 3072; kt += 32) {
        __syncthreads();
        writeStage(kt);
        __syncthreads();
        if (kt + 32 < 3072) stage(kt + 32);

        bf16x8 af[4], bfr[4];
#pragma unroll
        for (int mf = 0; mf < 4; ++mf)
            af[mf] = *(const bf16x8*)(Asl + SW64((wm + mf*16 + lr)*64 + lk*16));
#pragma unroll
        for (int nf = 0; nf < 4; ++nf)
            bfr[nf] = *(const bf16x8*)(Bsl + SW64((wn + nf*16 + lr)*64 + lk*16));
#pragma unroll
        for (int mf = 0; mf < 4; ++mf)
#pragma unroll
            for (int nf = 0; nf < 4; ++nf)
                acc[mf][nf] = __builtin_amdgcn_mfma_f32_16x16x32_bf16(af[mf], bfr[nf], acc[mf][nf], 0, 0, 0);
    }

#pragma unroll
    for (int nf = 0; nf < 4; ++nf) {
        const int col = n0 + wn + nf*16 + lr;
        const float bc = bcat[col];
#pragma unroll
        for (int mf = 0; mf < 4; ++mf)
#pragma unroll
            for (int r = 0; r < 4; ++r) {
                size_t row = (size_t)(m0 + wm + mf*16 + lk*4 + r);
                float x = acc[mf][nf][r] + bc;
                float g = 0.5f * x * (1.0f + erff(x * 0.70710678118654752f));
                x2[row * NH + col] = f2bf(g);
            }
    }
}

// ---------------------------------------------------------------------------
// Kernel C (fallback): ner_scores = [x2 @ W_crf + b_crf, -10000, -10000]
// ---------------------------------------------------------------------------
__global__ __launch_bounds__(256) void kC(const unsigned short* __restrict__ x2,
                                          const float* __restrict__ Wcrf,
                                          const float* __restrict__ bcrf,
                                          float* __restrict__ out) {
    __shared__ __align__(16) char Asl[8192];
    __shared__ __align__(16) char Bsl[3072];

    const int tid  = threadIdx.x;
    const int lane = tid & 63;
    const int wid  = tid >> 6;
    const int lr   = lane & 15;
    const int lk   = lane >> 4;
    const int m0   = blockIdx.x * 128;
    const int am   = tid >> 1;
    const int ak   = (tid & 1) * 16;

    for (int i = tid; i < 192; i += 256) *(int4*)(Bsl + i*16) = make_int4(0, 0, 0, 0);

    f32x4 acc[2][3];
#pragma unroll
    for (int i = 0; i < 2; ++i)
#pragma unroll
        for (int j = 0; j < 3; ++j) acc[i][j] = (f32x4){0.f, 0.f, 0.f, 0.f};

    const unsigned short* xrow = x2 + (size_t)(m0 + am) * NH + ak;

    for (int kt = 0; kt < NH; kt += 32) {
        const uint4* xp = (const uint4*)(xrow + kt);
        uint4 x0 = xp[0], x1 = xp[1];
        float wv[5];
#pragma unroll
        for (int p = 0; p < 5; ++p) {
            int i = tid + p * 256;
            wv[p] = (i < 32*NT) ? Wcrf[(size_t)kt * NT + i] : 0.f;
        }
        __syncthreads();
        *(uint4*)(Asl + SW64(am*64 + ak*2))      = x0;
        *(uint4*)(Asl + SW64(am*64 + ak*2 + 16)) = x1;
#pragma unroll
        for (int p = 0; p < 5; ++p) {
            int i = tid + p * 256;
            if (i < 32*NT) {
                int kk = i / NT;
                int t  = i - kk * NT;
                *(unsigned short*)(Bsl + SW64(t*64 + kk*2)) = f2bf(wv[p]);
            }
        }
        __syncthreads();
        bf16x8 af[2], bfr[3];
#pragma unroll
        for (int mf = 0; mf < 2; ++mf)
            af[mf] = *(const bf16x8*)(Asl + SW64((wid*32 + mf*16 + lr)*64 + lk*16));
#pragma unroll
        for (int nf = 0; nf < 3; ++nf)
            bfr[nf] = *(const bf16x8*)(Bsl + SW64((nf*16 + lr)*64 + lk*16));
#pragma unroll
        for (int mf = 0; mf < 2; ++mf)
#pragma unroll
            for (int nf = 0; nf < 3; ++nf)
                acc[mf][nf] = __builtin_amdgcn_mfma_f32_16x16x32_bf16(af[mf], bfr[nf], acc[mf][nf], 0, 0, 0);
    }

#pragma unroll
    for (int nf = 0; nf < 3; ++nf) {
        const int t = nf*16 + lr;
        const float bc = (t < NT) ? bcrf[t] : 0.f;
#pragma unroll
        for (int mf = 0; mf < 2; ++mf)
#pragma unroll
            for (int r = 0; r < 4; ++r) {
                size_t row = (size_t)(m0 + wid*32 + mf*16 + lk*4 + r);
                if (t < NT)       out[row * NLP + t] = acc[mf][nf][r] + bc;
                else if (t < NLP) out[row * NLP + t] = -10000.0f;
            }
    }
}

// ---------------------------------------------------------------------------
// Kernel Dold (fallback): round-11 exp-domain scan, scores staged in LDS.
// ---------------------------------------------------------------------------
#define CRFSTEP(EL) do {                                   \
    float as_[37];                                         \
    _Pragma("unroll")                                      \
    for (int f_ = 0; f_ < 37; ++f_) as_[f_] = rl(a, f_);   \
    __builtin_amdgcn_sched_barrier(0);                     \
    float c0 = 0.f, c1 = 0.f, c2 = 0.f, c3 = 0.f;          \
    _Pragma("unroll")                                      \
    for (int f_ = 0; f_ < 36; f_ += 4) {                   \
        c0 = fmaf(as_[f_    ], trow[f_    ], c0);          \
        c1 = fmaf(as_[f_ + 1], trow[f_ + 1], c1);          \
        c2 = fmaf(as_[f_ + 2], trow[f_ + 2], c2);          \
        c3 = fmaf(as_[f_ + 3], trow[f_ + 3], c3);          \
    }                                                      \
    c0 = fmaf(as_[36], trow[36], c0);                      \
    a = (EL) * ((c0 + c1) + (c2 + c3));                    \
} while (0)

__global__ __launch_bounds__(256) void kDold(const float* __restrict__ scores,
                                             const int* __restrict__ labels,
                                             const int* __restrict__ lens,
                                             const float* __restrict__ trans,
                                             float* __restrict__ loss) {
    __shared__ float S[NS * NLP];
    __shared__ float trL[39 * 41];
    __shared__ int   labL[NS];
    __shared__ float gred[4];

    const int b    = blockIdx.x;
    const int tid  = threadIdx.x;
    const int lane = tid & 63;
    const int wid  = tid >> 6;
    const int len  = lens[b];
    const float* sb = scores + (size_t)b * NS * NLP;

    {
        const int n4 = (len * NLP + 3) >> 2;
        const float4* src = (const float4*)sb;
        float4* dst = (float4*)S;
        for (int i = tid; i < n4; i += 256) dst[i] = src[i];
    }
    for (int i = tid; i < NS; i += 256) labL[i] = labels[b * NS + i];
    for (int idx = tid; idx < 39 * 39; idx += 256) {
        int to = idx / 39, f = idx - to * 39;
        trL[to * 41 + f] = trans[idx];
    }
    __syncthreads();

    float g = 0.0f;
    for (int t = tid; t < len; t += 256) g += S[t * NLP + labL[t]];
    for (int i = tid; i <= len; i += 256) {
        int frm = (i == 0) ? 37 : labL[i - 1];
        int to  = (i == len) ? 38 : labL[i];
        g += trL[to * 41 + frm];
    }
#pragma unroll
    for (int off = 32; off > 0; off >>= 1) g += __shfl_xor(g, off, 64);
    if (lane == 0) gred[wid] = g;
    __syncthreads();

    if (wid != 0) return;

    const float gold = (gred[0] + gred[1]) + (gred[2] + gred[3]);

    const int myrow = (lane < 39) ? lane : 0;
    float trow[39];
#pragma unroll
    for (int f = 0; f < 39; ++f) trow[f] = __expf(trL[myrow * 41 + f]);
    const float trEnd = (lane < 39) ? trL[38 * 41 + lane] : 0.f;
    const bool act = (lane < 39);

    float l0 = act ? S[lane] : -10000.f;
    float a = act ? __expf(l0) * trow[37] : 0.f;
    float C = 0.0f;

    auto ldrow = [&](int r) {
        r = (r < len) ? r : (len - 1);
        return S[act ? (r * NLP + lane) : 0];
    };
    float lg0 = ldrow(1), lg1 = ldrow(2), lg2 = ldrow(3), lg3 = ldrow(4);

    int t = 1;
    for (; t + 3 < len; t += 4) {
        float e0 = __expf(lg0), e1 = __expf(lg1), e2 = __expf(lg2), e3 = __expf(lg3);
        lg0 = ldrow(t + 4); lg1 = ldrow(t + 5); lg2 = ldrow(t + 6); lg3 = ldrow(t + 7);
        CRFSTEP(e0); CRFSTEP(e1); CRFSTEP(e2); CRFSTEP(e3);
        float s = rl(a, 0);
        float rr = __builtin_amdgcn_rcpf(s);
        a *= rr; C -= __logf(rr);
    }
    for (; t < len; ++t) {
        float el = __expf(ldrow(t));
        CRFSTEP(el);
    }

    float aend = (act && a > 0.f) ? C + __logf(a) + trEnd : -1e30f;
    float mx = aend;
#pragma unroll
    for (int off = 32; off > 0; off >>= 1) mx = fmaxf(mx, __shfl_xor(mx, off, 64));
    float es = act ? __expf(aend - mx) : 0.0f;
#pragma unroll
    for (int off = 32; off > 0; off >>= 1) es += __shfl_xor(es, off, 64);
    float norm = mx + __logf(es);

    if (lane == 0) loss[b] = gold - norm;
}

// ---------------------------------------------------------------------------
extern "C" void kernel_launch(void* const* d_in, const int* in_sizes, int n_in,
                              void* d_out, int out_size, void* d_ws, size_t ws_size,
                              hipStream_t stream) {
    const float* h        = (const float*)d_in[0];
    const int* token_nums = (const int*)d_in[2];
    const int* labels     = (const int*)d_in[3];
    const float* bio      = (const float*)d_in[4];
    const float* Wcat     = (const float*)d_in[5];
    const float* bcat     = (const float*)d_in[6];
    const float* Wcrf     = (const float*)d_in[7];
    const float* bcrf     = (const float*)d_in[8];
    const float* trans    = (const float*)d_in[9];

    float* out = (float*)d_out;
    unsigned short* attn  = (unsigned short*)d_out;  // 2MB scratch, overwritten by kDmCr

    const size_t ASW_BYTES = (size_t)128 * 48 * 16384;        // 96 MB
    const size_t P_BYTES   = (size_t)4 * NM * 48 * 4;         // 12.6 MB
    const size_t WSW_BYTES = (size_t)8 * 48 * 16384;          // 6 MB
    const size_t WT_BYTES  = (size_t)48 * 3072 * 2;           // 288 KB
    const size_t PM_BYTES  = (size_t)NB * 8 * 2304 * 4;       // 2.36 MB
    const size_t PC_BYTES  = (size_t)NB * 8 * 4;              // 1 KB
    const bool fast = ws_size >= ASW_BYTES + P_BYTES + WSW_BYTES + WT_BYTES + PM_BYTES + PC_BYTES;

    if (fast) {
        char*  Asw = (char*)d_ws;
        float* P   = (float*)((char*)d_ws + ASW_BYTES);
        char*  Wsw = (char*)d_ws + ASW_BYTES + P_BYTES;
        unsigned short* WT = (unsigned short*)((char*)d_ws + ASW_BYTES + P_BYTES + WSW_BYTES);
        float* Pm  = (float*)((char*)d_ws + ASW_BYTES + P_BYTES + WSW_BYTES + WT_BYTES);
        float* Pc  = Pm + (size_t)NB * 8 * 2304;

        hipLaunchKernelGGL(kPre, dim3(712), dim3(256), 0, stream,
                           h, bio, Wcat, Wcrf, attn, Asw, Wsw, WT);
        hipLaunchKernelGGL(kA2f, dim3(NH / 128, NM / 128), dim3(256), 0, stream,
                           attn, bio, Asw);
        hipLaunchKernelGGL(kBf, dim3(256), dim3(512), 0, stream, Asw, Wsw, bcat, WT, P);
        hipLaunchKernelGGL(kDmCr, dim3(NB * 8), dim3(256), 0, stream,
                           P, bcrf, token_nums, trans, out, Pm, Pc);
        hipLaunchKernelGGL(kDc, dim3(NB), dim3(256), 0, stream, out, labels, token_nums,
                           trans, Pm, Pc, out + (size_t)NM * NLP);
    } else {
        unsigned short* aware = (unsigned short*)d_ws;
        unsigned short* x2    = aware + (size_t)NM * NH;

        hipLaunchKernelGGL(kA1, dim3(NM / 128), dim3(512), 0, stream, h, bio, attn);
        hipLaunchKernelGGL(kA2, dim3(NH / 128, NM / 128), dim3(256), 0, stream, attn, bio, aware);
        hipLaunchKernelGGL(kB, dim3((NH / 128) * (NM / 128)), dim3(256), 0, stream,
                           h, aware, Wcat, bcat, x2);
        hipLaunchKernelGGL(kC, dim3(NM / 128), dim3(256), 0, stream, x2, Wcrf, bcrf, out);
        hipLaunchKernelGGL(kDold, dim3(NB), dim3(256), 0, stream, out, labels, token_nums,
                           trans, out + (size_t)NM * NLP);
    }
}

// Round 18
// 198.683 us; speedup vs baseline: 1.1404x; 1.0701x over previous
//
#include <hip/hip_runtime.h>
#include <hip/hip_bf16.h>
#include <math.h>

#define NB 32
#define NS 512
#define NH 1024
#define NT 37
#define NLP 39
#define NM (NB*NS)   // 16384
#define NSEG 16
#define SEGLEN 32

typedef __attribute__((ext_vector_type(8))) short bf16x8;
typedef __attribute__((ext_vector_type(4))) float f32x4;

__device__ __forceinline__ float bf2f(unsigned int u) {
    unsigned int x = u << 16;
    float f;
    __builtin_memcpy(&f, &x, 4);
    return f;
}
__device__ __forceinline__ unsigned short f2bf(float f) {
    __hip_bfloat16 hb = __float2bfloat16(f);
    unsigned short u;
    __builtin_memcpy(&u, &hb, 2);
    return u;
}
__device__ __forceinline__ unsigned int pk2(float lo, float hi) {
    return ((unsigned int)f2bf(hi) << 16) | (unsigned int)f2bf(lo);
}
// bijective XOR swizzle for [row][64B] bf16 LDS tiles
__device__ __forceinline__ int SW64(int b)  { return b ^ ((b >> 2) & 0x70); }
// tile swizzle for [128/256 row][64 k] bf16 tiles (row stride 128B)
__device__ __forceinline__ int TSW(int row, int kcolByte) {
    return (row * 128 + kcolByte) ^ ((row & 7) << 4);
}
__device__ __forceinline__ float rl(float x, int l) {
    return __int_as_float(__builtin_amdgcn_readlane(__float_as_int(x), l));
}
__device__ __forceinline__ void gld16(const void* g, void* l) {
    __builtin_amdgcn_global_load_lds((const __attribute__((address_space(1))) void*)g,
                                     (__attribute__((address_space(3))) void*)l, 16, 0, 0);
}
#define VMW(N) asm volatile("s_waitcnt vmcnt(" #N ")" ::: "memory")
#define BARR() do { __builtin_amdgcn_s_barrier(); __builtin_amdgcn_sched_barrier(0); } while (0)

// ---------------------------------------------------------------------------
// Kernel Pre (fast): fused kA1 + kW + kW2, 712 blocks x 256 thr.
// ---------------------------------------------------------------------------
__global__ __launch_bounds__(256) void kPre(const float* __restrict__ h,
                                            const float* __restrict__ bio,
                                            const float* __restrict__ Wcat,
                                            const float* __restrict__ Wcrf,
                                            unsigned short* __restrict__ attn,
                                            char* __restrict__ Asw,
                                            char* __restrict__ Wsw,
                                            unsigned short* __restrict__ WT) {
    __shared__ __align__(16) char shmem[48 * 2048];   // 96KB, aliased per branch
    const int bid = blockIdx.x;
    const int tid = threadIdx.x;

    if (bid < 256) {
        // ---------------- kA1 (64 rows) + region-0 writes ----------------
        char* Bl = shmem;
        const int lane = tid & 63;
        const int wid  = tid >> 6;          // 0..3
        const int lr   = lane & 15;
        const int lk   = lane >> 4;
        const int m0   = bid * 64;
        const int tm   = bid >> 1;                        // 128-row tile index
        const int rbase = (bid & 1) * 64 + wid * 16 + lr; // row within tile

        for (int idx = tid; idx < 37 * 256; idx += 256) {
            int t = idx >> 8, k4 = idx & 255;
            float4 v = *(const float4*)&bio[(size_t)t * NH + k4 * 4];
            int byte = (t * 2048 + k4 * 8) ^ ((t & 7) << 4);
            *(uint2*)(Bl + byte) = make_uint2(pk2(v.x, v.y), pk2(v.z, v.w));
        }
        for (int idx = tid; idx < 11 * 256; idx += 256) {
            int t = 37 + (idx >> 8), k4 = idx & 255;
            int byte = (t * 2048 + k4 * 8) ^ ((t & 7) << 4);
            *(uint2*)(Bl + byte) = make_uint2(0, 0);
        }
        __syncthreads();

        const int arow = m0 + wid * 16 + lr;
        const float* hp = h + (size_t)arow * NH + lk * 8;

        f32x4 sacc[3];
#pragma unroll
        for (int j = 0; j < 3; ++j) sacc[j] = (f32x4){0.f, 0.f, 0.f, 0.f};

        float4 p0 = *(const float4*)(hp);
        float4 p1 = *(const float4*)(hp + 4);
        for (int kt = 0; kt < NH; kt += 32) {
            float4 c0 = p0, c1 = p1;
            if (kt + 32 < NH) {
                p0 = *(const float4*)(hp + kt + 32);
                p1 = *(const float4*)(hp + kt + 36);
            }
            union { unsigned int u[4]; bf16x8 v; uint4 q; } af;
            af.u[0] = pk2(c0.x, c0.y); af.u[1] = pk2(c0.z, c0.w);
            af.u[2] = pk2(c1.x, c1.y); af.u[3] = pk2(c1.z, c1.w);
            {
                int kg = kt + lk * 8;
                size_t tb = ((size_t)tm * 48 + (kg >> 6)) * 16384;
                *(uint4*)(Asw + tb + TSW(rbase, (kg & 63) * 2)) = af.q;
            }
#pragma unroll
            for (int nf = 0; nf < 3; ++nf) {
                int t = nf * 16 + lr;
                int byte = (t * 2048 + (kt + lk * 8) * 2) ^ ((t & 7) << 4);
                bf16x8 bf = *(const bf16x8*)(Bl + byte);
                sacc[nf] = __builtin_amdgcn_mfma_f32_16x16x32_bf16(af.v, bf, sacc[nf], 0, 0, 0);
            }
        }

#pragma unroll
        for (int r = 0; r < 4; ++r) {
            const int orow = wid * 16 + lk * 4 + r;
            float s0 = sacc[0][r] * 0.03125f;
            float s1 = sacc[1][r] * 0.03125f;
            float s2 = sacc[2][r] * 0.03125f;
            const bool v2 = (lr < 5);
            float mx = fmaxf(fmaxf(s0, s1), v2 ? s2 : -1e30f);
#pragma unroll
            for (int d = 1; d < 16; d <<= 1) mx = fmaxf(mx, __shfl_xor(mx, d, 64));
            float e0 = __expf(s0 - mx), e1 = __expf(s1 - mx);
            float e2 = v2 ? __expf(s2 - mx) : 0.f;
            float sm = e0 + e1 + e2;
#pragma unroll
            for (int d = 1; d < 16; d <<= 1) sm += __shfl_xor(sm, d, 64);
            float inv = 1.f / sm;
            size_t g = (size_t)(m0 + orow) * 64;
            attn[g + lr]      = f2bf(e0 * inv);
            attn[g + 16 + lr] = f2bf(e1 * inv);
            attn[g + 32 + lr] = f2bf(e2 * inv);
            attn[g + 48 + lr] = 0;
        }
    } else if (bid < 640) {
        // ---------------- kW: Wcat -> Wsw swizzled tiles ----------------
        unsigned short* wt = (unsigned short*)shmem;   // 16KB
        const int tile = bid - 256;
        const int tn   = tile / 48;
        const int tk   = tile - tn * 48;
        const int n00  = tn * 128;
        const int k0   = tk * 64;

        for (int lin = tid; lin < 2048; lin += 256) {
            int kk = lin >> 5, ng = lin & 31;
            float4 v = *(const float4*)&Wcat[(size_t)(k0 + kk) * NH + n00 + ng * 4];
            *(uint2*)&wt[kk * 128 + ng * 4] = make_uint2(pk2(v.x, v.y), pk2(v.z, v.w));
        }
        __syncthreads();
        for (int lin = tid; lin < 1024; lin += 256) {
            int rn = lin >> 3, kg = lin & 7;
            unsigned short t8[8];
#pragma unroll
            for (int j = 0; j < 8; ++j) t8[j] = wt[(kg * 8 + j) * 128 + rn];
            uint4 v;
            __builtin_memcpy(&v, t8, 16);
            *(uint4*)(Wsw + (size_t)tile * 16384 + TSW(rn, kg * 16)) = v;
        }
    } else {
        // ---------------- kW2: Wcrf^T prepack ----------------
        const int idx = (bid - 640) * 256 + tid;
        if (idx < 48 * 384) {
            const int t = idx / 384, kg = idx - t * 384;
            unsigned short v[8];
#pragma unroll
            for (int e = 0; e < 8; ++e) {
                int k = kg * 8 + e;
                v[e] = (t < NT) ? f2bf(Wcrf[(size_t)k * NT + t]) : (unsigned short)0;
            }
            uint4 w;
            __builtin_memcpy(&w, v, 16);
            *(uint4*)(WT + (size_t)t * 3072 + kg * 8) = w;
        }
    }
}

// ---------------------------------------------------------------------------
// Kernel A1 (fallback): scores -> softmax -> attn only.
// ---------------------------------------------------------------------------
__global__ __launch_bounds__(512) void kA1(const float* __restrict__ h,
                                           const float* __restrict__ bio,
                                           unsigned short* __restrict__ attn) {
    __shared__ __align__(16) char Bl[48 * 2048];

    const int tid  = threadIdx.x;
    const int lane = tid & 63;
    const int wid  = tid >> 6;
    const int lr   = lane & 15;
    const int lk   = lane >> 4;
    const int m0   = blockIdx.x * 128;

    for (int idx = tid; idx < 37 * 256; idx += 512) {
        int t = idx >> 8, k4 = idx & 255;
        float4 v = *(const float4*)&bio[(size_t)t * NH + k4 * 4];
        int byte = (t * 2048 + k4 * 8) ^ ((t & 7) << 4);
        *(uint2*)(Bl + byte) = make_uint2(pk2(v.x, v.y), pk2(v.z, v.w));
    }
    for (int idx = tid; idx < 11 * 256; idx += 512) {
        int t = 37 + (idx >> 8), k4 = idx & 255;
        int byte = (t * 2048 + k4 * 8) ^ ((t & 7) << 4);
        *(uint2*)(Bl + byte) = make_uint2(0, 0);
    }
    __syncthreads();

    const int arow = m0 + wid * 16 + lr;
    const float* hp = h + (size_t)arow * NH + lk * 8;

    f32x4 sacc[3];
#pragma unroll
    for (int j = 0; j < 3; ++j) sacc[j] = (f32x4){0.f, 0.f, 0.f, 0.f};

    float4 p0 = *(const float4*)(hp);
    float4 p1 = *(const float4*)(hp + 4);
    for (int kt = 0; kt < NH; kt += 32) {
        float4 c0 = p0, c1 = p1;
        if (kt + 32 < NH) {
            p0 = *(const float4*)(hp + kt + 32);
            p1 = *(const float4*)(hp + kt + 36);
        }
        union { unsigned int u[4]; bf16x8 v; } af;
        af.u[0] = pk2(c0.x, c0.y); af.u[1] = pk2(c0.z, c0.w);
        af.u[2] = pk2(c1.x, c1.y); af.u[3] = pk2(c1.z, c1.w);
#pragma unroll
        for (int nf = 0; nf < 3; ++nf) {
            int t = nf * 16 + lr;
            int byte = (t * 2048 + (kt + lk * 8) * 2) ^ ((t & 7) << 4);
            bf16x8 bf = *(const bf16x8*)(Bl + byte);
            sacc[nf] = __builtin_amdgcn_mfma_f32_16x16x32_bf16(af.v, bf, sacc[nf], 0, 0, 0);
        }
    }

#pragma unroll
    for (int r = 0; r < 4; ++r) {
        const int orow = wid * 16 + lk * 4 + r;
        float s0 = sacc[0][r] * 0.03125f;
        float s1 = sacc[1][r] * 0.03125f;
        float s2 = sacc[2][r] * 0.03125f;
        const bool v2 = (lr < 5);
        float mx = fmaxf(fmaxf(s0, s1), v2 ? s2 : -1e30f);
#pragma unroll
        for (int d = 1; d < 16; d <<= 1) mx = fmaxf(mx, __shfl_xor(mx, d, 64));
        float e0 = __expf(s0 - mx), e1 = __expf(s1 - mx);
        float e2 = v2 ? __expf(s2 - mx) : 0.f;
        float sm = e0 + e1 + e2;
#pragma unroll
        for (int d = 1; d < 16; d <<= 1) sm += __shfl_xor(sm, d, 64);
        float inv = 1.f / sm;
        size_t g = (size_t)(m0 + orow) * 64;
        attn[g + lr]      = f2bf(e0 * inv);
        attn[g + 16 + lr] = f2bf(e1 * inv);
        attn[g + 32 + lr] = f2bf(e2 * inv);
        attn[g + 48 + lr] = 0;
    }
}

// ---------------------------------------------------------------------------
// Kernel A2 (fallback): aware = attn @ bio, plain bf16 row-major out.
// ---------------------------------------------------------------------------
__global__ __launch_bounds__(256) void kA2(const unsigned short* __restrict__ attn,
                                           const float* __restrict__ bio,
                                           unsigned short* __restrict__ aware) {
    __shared__ __align__(16) char Bsl[128 * 64];

    const int tid  = threadIdx.x;
    const int lane = tid & 63;
    const int wid  = tid >> 6;
    const int wm   = (wid >> 1) * 64;
    const int wn   = (wid & 1) * 64;
    const int lr   = lane & 15;
    const int lk   = lane >> 4;
    const int n0   = blockIdx.x * 128;
    const int m0   = blockIdx.y * 128;

    const int bn = tid & 127;
    const int bq = (tid >> 7) * 16;

    f32x4 acc[4][4];
#pragma unroll
    for (int i = 0; i < 4; ++i)
#pragma unroll
        for (int j = 0; j < 4; ++j) acc[i][j] = (f32x4){0.f, 0.f, 0.f, 0.f};

#pragma unroll
    for (int ks = 0; ks < 2; ++ks) {
        unsigned int p[8];
#pragma unroll
        for (int i = 0; i < 8; ++i) {
            int t0 = ks*32 + bq + 2*i;
            float lo = (t0     < NT) ? bio[(size_t)t0 * NH + n0 + bn]       : 0.f;
            float hi = (t0 + 1 < NT) ? bio[(size_t)(t0+1) * NH + n0 + bn]   : 0.f;
            p[i] = pk2(lo, hi);
        }
        __syncthreads();
        *(int4*)(Bsl + SW64(bn*64 + bq*2))      = make_int4(p[0], p[1], p[2], p[3]);
        *(int4*)(Bsl + SW64(bn*64 + bq*2 + 16)) = make_int4(p[4], p[5], p[6], p[7]);
        __syncthreads();

        bf16x8 af[4];
#pragma unroll
        for (int mf = 0; mf < 4; ++mf)
            af[mf] = *(const bf16x8*)(attn + (size_t)(m0 + wm + mf*16 + lr) * 64 + ks*32 + lk*8);
#pragma unroll
        for (int nf = 0; nf < 4; ++nf) {
            bf16x8 bb = *(const bf16x8*)(Bsl + SW64((wn + nf*16 + lr)*64 + lk*16));
#pragma unroll
            for (int mf = 0; mf < 4; ++mf)
                acc[mf][nf] = __builtin_amdgcn_mfma_f32_16x16x32_bf16(af[mf], bb, acc[mf][nf], 0, 0, 0);
        }
    }

#pragma unroll
    for (int mf = 0; mf < 4; ++mf)
#pragma unroll
        for (int nf = 0; nf < 4; ++nf)
#pragma unroll
            for (int r = 0; r < 4; ++r) {
                size_t row = (size_t)(m0 + wm + mf*16 + lk*4 + r);
                aware[row * NH + n0 + wn + nf*16 + lr] = f2bf(acc[mf][nf][r]);
            }
}

// ---------------------------------------------------------------------------
// Kernel A2f (fast, v2): computes aware chunk; reads h as bf16 from Asw
// region 0 (written by kPre); writes only regions 1 (aware) and 2 (h*aware).
// ---------------------------------------------------------------------------
__global__ __launch_bounds__(256) void kA2f(const unsigned short* __restrict__ attn,
                                            const float* __restrict__ bio,
                                            char* __restrict__ Asw) {
    __shared__ __align__(16) char Bsl[128 * 64];
    __shared__ __align__(16) unsigned short awL[128 * 128];  // 32KB aware chunk

    const int tid  = threadIdx.x;
    const int lane = tid & 63;
    const int wid  = tid >> 6;
    const int wm   = (wid >> 1) * 64;
    const int wn   = (wid & 1) * 64;
    const int lr   = lane & 15;
    const int lk   = lane >> 4;
    const int n0   = blockIdx.x * 128;
    const int m0   = blockIdx.y * 128;
    const int tm   = blockIdx.y;

    const int bn = tid & 127;
    const int bq = (tid >> 7) * 16;

    f32x4 acc[4][4];
#pragma unroll
    for (int i = 0; i < 4; ++i)
#pragma unroll
        for (int j = 0; j < 4; ++j) acc[i][j] = (f32x4){0.f, 0.f, 0.f, 0.f};

#pragma unroll
    for (int ks = 0; ks < 2; ++ks) {
        unsigned int p[8];
#pragma unroll
        for (int i = 0; i < 8; ++i) {
            int t0 = ks*32 + bq + 2*i;
            float lo = (t0     < NT) ? bio[(size_t)t0 * NH + n0 + bn]       : 0.f;
            float hi = (t0 + 1 < NT) ? bio[(size_t)(t0+1) * NH + n0 + bn]   : 0.f;
            p[i] = pk2(lo, hi);
        }
        __syncthreads();
        *(int4*)(Bsl + SW64(bn*64 + bq*2))      = make_int4(p[0], p[1], p[2], p[3]);
        *(int4*)(Bsl + SW64(bn*64 + bq*2 + 16)) = make_int4(p[4], p[5], p[6], p[7]);
        __syncthreads();

        bf16x8 af[4];
#pragma unroll
        for (int mf = 0; mf < 4; ++mf)
            af[mf] = *(const bf16x8*)(attn + (size_t)(m0 + wm + mf*16 + lr) * 64 + ks*32 + lk*8);
#pragma unroll
        for (int nf = 0; nf < 4; ++nf) {
            bf16x8 bb = *(const bf16x8*)(Bsl + SW64((wn + nf*16 + lr)*64 + lk*16));
#pragma unroll
            for (int mf = 0; mf < 4; ++mf)
                acc[mf][nf] = __builtin_amdgcn_mfma_f32_16x16x32_bf16(af[mf], bb, acc[mf][nf], 0, 0, 0);
        }
    }

#pragma unroll
    for (int mf = 0; mf < 4; ++mf)
#pragma unroll
        for (int nf = 0; nf < 4; ++nf)
#pragma unroll
            for (int r = 0; r < 4; ++r)
                awL[(wm + mf*16 + lk*4 + r) * 128 + wn + nf*16 + lr] = f2bf(acc[mf][nf][r]);
    __syncthreads();

    // region 1 (aware)
#pragma unroll
    for (int i = 0; i < 8; ++i) {
        int lin = tid + i * 256;
        int row = lin >> 4, kg = lin & 15;
        uint4 v = *(const uint4*)&awL[row * 128 + kg * 8];
        int kglob = 1024 + n0 + kg * 8;
        size_t tbase = ((size_t)tm * 48 + (kglob >> 6)) * 16384;
        *(uint4*)(Asw + tbase + TSW(row, (kglob & 63) * 2)) = v;
    }
    // region 2 (h*aware), h read back as bf16 from region 0
#pragma unroll
    for (int i = 0; i < 8; ++i) {
        int lin = tid + i * 256;
        int row = lin >> 4, kg = lin & 15;
        int k0g = n0 + kg * 8;
        size_t tb0 = ((size_t)tm * 48 + (k0g >> 6)) * 16384;
        uint4 hv4 = *(const uint4*)(Asw + tb0 + TSW(row, (k0g & 63) * 2));
        unsigned int hu[4] = {hv4.x, hv4.y, hv4.z, hv4.w};
        uint4 awv = *(const uint4*)&awL[row * 128 + kg * 8];
        unsigned int awu[4] = {awv.x, awv.y, awv.z, awv.w};
        unsigned int p2[4];
#pragma unroll
        for (int j = 0; j < 4; ++j) {
            float lo = bf2f(hu[j] & 0xffffu) * bf2f(awu[j] & 0xffffu);
            float hi = bf2f(hu[j] >> 16)     * bf2f(awu[j] >> 16);
            p2[j] = pk2(lo, hi);
        }
        int k2g = 2048 + n0 + kg * 8;
        size_t tb2 = ((size_t)tm * 48 + (k2g >> 6)) * 16384;
        *(uint4*)(Asw + tb2 + TSW(row, (k2g & 63) * 2)) = make_uint4(p2[0], p2[1], p2[2], p2[3]);
    }
}

// ---------------------------------------------------------------------------
// Kernel Bf (fast): 256x256 tile bf16 GEMM, BK=64, 8 waves. Round-18 schedule:
// TWO barriers per K-tile. BARR_A (after counted VMW(2)): buf q fully staged.
// Then all 24 ds_reads + remaining 3 stage-halves (writes go to buf q^1 only),
// then 4 MFMA clusters (register consumption of all buf-q reads), then BARR_B
// (WAR guard: next iteration's staging may overwrite buf q^1... which was last
// read in iteration T-1; buf q is next overwritten by stage(T+2) issued after
// BARR_B). + fused kC epilogue (prepacked Wcrf^T).
// ---------------------------------------------------------------------------
__global__ __launch_bounds__(512, 2) void kBf(const char* __restrict__ Asw,
                                              const char* __restrict__ Wsw,
                                              const float* __restrict__ bcat,
                                              const unsigned short* __restrict__ WT,
                                              float* __restrict__ P) {
    __shared__ __align__(16) char lds[131072];  // A: buf*32768+h*16384; B at +65536

    const int tid  = threadIdx.x;
    const int lane = tid & 63;
    const int wid  = tid >> 6;
    const int widm = wid >> 2;       // 0..1
    const int widn = wid & 3;        // 0..3
    const int lr   = lane & 15;
    const int lk   = lane >> 4;

    const int id   = blockIdx.x;     // 256 blocks
    const int xcd  = id & 7;
    const int slot = id >> 3;        // 0..31
    const int Mt   = xcd * 8 + (slot >> 2);
    const int Nt   = slot & 3;
    const int m0   = Mt * 256, n0 = Nt * 256;
    const int soff = tid * 16;

    f32x4 acc00[4][2], acc01[4][2], acc10[4][2], acc11[4][2];
#pragma unroll
    for (int i = 0; i < 4; ++i)
#pragma unroll
        for (int j = 0; j < 2; ++j) {
            acc00[i][j] = (f32x4){0.f,0.f,0.f,0.f};
            acc01[i][j] = (f32x4){0.f,0.f,0.f,0.f};
            acc10[i][j] = (f32x4){0.f,0.f,0.f,0.f};
            acc11[i][j] = (f32x4){0.f,0.f,0.f,0.f};
        }

    auto stageHalf = [&](int T, int ph) {
        const bool isA = (ph == 0) || (ph == 3);
        const int  h   = isA ? (ph == 3 ? 1 : 0) : (ph - 1);
        const char* src = isA
            ? Asw + ((size_t)((2*Mt + h) * 48 + T)) * 16384
            : Wsw + ((size_t)((2*Nt + h) * 48 + T)) * 16384;
        char* dst = lds + (isA ? 0 : 65536) + (T & 1) * 32768 + h * 16384;
        gld16(src + soff,        dst + soff);
        gld16(src + soff + 8192, dst + soff + 8192);
    };
    auto loadA = [&](bf16x8 (&af)[4][2], int q, int half) {
        const char* base = lds + q * 32768 + half * 16384;
#pragma unroll
        for (int i = 0; i < 4; ++i) {
            int row = widm * 64 + i * 16 + lr;
#pragma unroll
            for (int kk = 0; kk < 2; ++kk)
                af[i][kk] = *(const bf16x8*)(base + TSW(row, kk * 64 + lk * 16));
        }
    };
    auto loadB = [&](bf16x8 (&bfr)[2][2], int q, int half) {
        const char* base = lds + 65536 + q * 32768 + half * 16384;
#pragma unroll
        for (int j = 0; j < 2; ++j) {
            int col = widn * 32 + j * 16 + lr;
#pragma unroll
            for (int kk = 0; kk < 2; ++kk)
                bfr[j][kk] = *(const bf16x8*)(base + TSW(col, kk * 64 + lk * 16));
        }
    };
    auto mma = [&](f32x4 (&ac)[4][2], bf16x8 (&af)[4][2], bf16x8 (&bfr)[2][2]) {
        __builtin_amdgcn_s_setprio(1);
#pragma unroll
        for (int kk = 0; kk < 2; ++kk)
#pragma unroll
            for (int i = 0; i < 4; ++i)
#pragma unroll
                for (int j = 0; j < 2; ++j)
                    ac[i][j] = __builtin_amdgcn_mfma_f32_16x16x32_bf16(
                        af[i][kk], bfr[j][kk], ac[i][j], 0, 0, 0);
        __builtin_amdgcn_s_setprio(0);
    };

    // prologue: stage tile 0 fully, drain once
    stageHalf(0, 0); stageHalf(0, 1); stageHalf(0, 2); stageHalf(0, 3);
    VMW(0);
    BARR();

    for (int T = 0; T < 48; ++T) {
        const int q = T & 1;
        const bool pf = (T + 1 < 48);
        bf16x8 af0[4][2], af1[4][2], bf0[2][2], bf1[2][2];

        // BARR_A: buf q ready (T==0 covered by prologue drain+barrier)
        if (T > 0) {
            if (pf) { stageHalf(T + 1, 0); VMW(2); }
            else    { VMW(0); }
            BARR();
        } else if (pf) {
            stageHalf(T + 1, 0);
        }

        // all reads of buf q, interleaved with staging buf q^1
        loadA(af0, q, 0); loadB(bf0, q, 0);
        if (pf) stageHalf(T + 1, 1);
        loadB(bf1, q, 1); loadA(af1, q, 1);
        if (pf) { stageHalf(T + 1, 2); stageHalf(T + 1, 3); }

        // MFMA clusters (consume all reads -> lgkm drained by last mma)
        mma(acc00, af0, bf0);
        mma(acc01, af0, bf1);
        mma(acc10, af1, bf0);
        mma(acc11, af1, bf1);

        // BARR_B: all waves consumed buf q; stage(T+2) may overwrite it next
        BARR();
    }

    // ---------------- fused kC epilogue ----------------
    __syncthreads();
    auto stashQ = [&](f32x4 (&ac)[4][2], int a, int b) {
#pragma unroll
        for (int j = 0; j < 2; ++j) {
            const int lcol = b * 128 + widn * 32 + j * 16 + lr;
            const int kc = lcol >> 6, kk = lcol & 63;
            const float bc = bcat[n0 + lcol];
#pragma unroll
            for (int i = 0; i < 4; ++i)
#pragma unroll
                for (int r = 0; r < 4; ++r) {
                    int lrow = a * 128 + widm * 64 + i * 16 + lk * 4 + r;
                    float x = ac[i][j][r] + bc;
                    float g = 0.5f * x * (1.0f + erff(x * 0.70710678118654752f));
                    *(unsigned short*)(lds + kc * 32768 + TSW(lrow, kk * 2)) = f2bf(g);
                }
        }
    };
    stashQ(acc00, 0, 0); stashQ(acc01, 0, 1); stashQ(acc10, 1, 0); stashQ(acc11, 1, 1);
    __syncthreads();

    bf16x8 wfrag[3][8];
#pragma unroll
    for (int tt = 0; tt < 3; ++tt) {
        const int t = tt * 16 + lr;
#pragma unroll
        for (int ks = 0; ks < 8; ++ks)
            wfrag[tt][ks] = *(const bf16x8*)(WT + (size_t)t * 3072 + n0 + ks * 32 + lk * 8);
    }

    f32x4 pacc[2][3];
#pragma unroll
    for (int i = 0; i < 2; ++i)
#pragma unroll
        for (int j = 0; j < 3; ++j) pacc[i][j] = (f32x4){0.f, 0.f, 0.f, 0.f};
#pragma unroll
    for (int rt2 = 0; rt2 < 2; ++rt2) {
        const int lrow = wid * 32 + rt2 * 16 + lr;
#pragma unroll
        for (int ks = 0; ks < 8; ++ks) {
            const int kc = ks >> 1, kh = ks & 1;
            bf16x8 af = *(const bf16x8*)(lds + kc * 32768 + TSW(lrow, kh * 64 + lk * 16));
#pragma unroll
            for (int tt = 0; tt < 3; ++tt)
                pacc[rt2][tt] = __builtin_amdgcn_mfma_f32_16x16x32_bf16(
                    af, wfrag[tt][ks], pacc[rt2][tt], 0, 0, 0);
        }
    }

    float* Pb = P + (size_t)Nt * NM * 48;
#pragma unroll
    for (int rt2 = 0; rt2 < 2; ++rt2)
#pragma unroll
        for (int tt = 0; tt < 3; ++tt)
#pragma unroll
            for (int r = 0; r < 4; ++r) {
                int row = Mt * 256 + wid * 32 + rt2 * 16 + lk * 4 + r;
                Pb[(size_t)row * 48 + tt * 16 + lr] = pacc[rt2][tt][r];
            }
}

// ---------------------------------------------------------------------------
// Kernel DmCr (fast): fused kCr + kDm, 16 segments of 32 steps (2 blocks/CU,
// scans overlap). Phase 1 (4 waves): score slice from split-K partials + bias
// -> out + el table in LDS. Phase 2 (wave 0): matrix segment scan.
// ---------------------------------------------------------------------------
__global__ __launch_bounds__(256) void kDmCr(const float* __restrict__ P,
                                             const float* __restrict__ bcrf,
                                             const int* __restrict__ lens,
                                             const float* __restrict__ trans,
                                             float* __restrict__ out,
                                             float* __restrict__ Pm,
                                             float* __restrict__ Pc) {
    __shared__ float el_all[SEGLEN * 64];
    __shared__ __align__(16) char Mb[2 * 6144];

    const int tid = threadIdx.x;
    const int b   = blockIdx.x >> 4;
    const int s   = blockIdx.x & 15;
    const int t0  = s * SEGLEN;
    const size_t STRIDE = (size_t)NM * 48;

    // phase 1: scores slice -> out + el_all (32 rows x 48 cols, 6 per thread)
    {
        const int i  = tid >> 3;            // step 0..31
        const int tg = (tid & 7) * 6;       // col base (8 groups x 6 = 48)
        const int gr = b * NS + t0 + i;     // global row
#pragma unroll
        for (int j = 0; j < 6; ++j) {
            int t = tg + j;
            size_t flat = (size_t)gr * 48 + t;
            float v = P[flat] + P[STRIDE + flat] + P[2*STRIDE + flat] + P[3*STRIDE + flat];
            float o, el;
            if (t < NT) { o = v + bcrf[t]; el = __expf(o); }
            else        { o = -10000.0f;   el = 0.f; }
            if (t < NLP) out[(size_t)gr * NLP + t] = o;
            el_all[i * 64 + t] = el;
        }
    }
    for (int z = tid; z < SEGLEN * 16; z += 256)
        el_all[(z >> 4) * 64 + 48 + (z & 15)] = 0.f;
    __syncthreads();

    if (tid >= 64) return;

    const int lane = tid;
    const int lr   = lane & 15;
    const int lk   = lane >> 4;
    const int len  = lens[b];
    const int nsteps = (len > t0) ? ((len - t0 < SEGLEN) ? (len - t0) : SEGLEN) : 0;
    float* Pg = Pm + (size_t)(b * NSEG + s) * 2304;

    if (nsteps == 0) {
        for (int j = 0; j < 36; ++j) Pg[j * 64 + lane] = 0.f;
        if (lane < 48) Pg[lane * 48 + lane] = 1.f;
        if (lane == 0) Pc[b * NSEG + s] = 0.f;
        return;
    }

    bf16x8 Tf[3][2];
#pragma unroll
    for (int tt = 0; tt < 3; ++tt)
#pragma unroll
        for (int ks = 0; ks < 2; ++ks) {
            const int row = tt * 16 + lr;
            unsigned int u[4];
#pragma unroll
            for (int e2 = 0; e2 < 4; ++e2) {
                int f0 = ks * 32 + lk * 8 + 2 * e2;
                float lo = (row < NLP && f0     < NLP) ? __expf(trans[row * NLP + f0])     : 0.f;
                float hi = (row < NLP && f0 + 1 < NLP) ? __expf(trans[row * NLP + f0 + 1]) : 0.f;
                u[e2] = pk2(lo, hi);
            }
            union { unsigned int uu[4]; bf16x8 v; } cv;
            cv.uu[0]=u[0]; cv.uu[1]=u[1]; cv.uu[2]=u[2]; cv.uu[3]=u[3];
            Tf[tt][ks] = cv.v;
        }

    for (int j = 0; j < 48; ++j)
        *(unsigned int*)(Mb + j * 256 + lane * 4) = 0;
    if (lane < 48) {
        int byte = (lane * 128 + lane * 2) ^ ((lane & 7) << 4);
        *(unsigned short*)(Mb + byte) = f2bf(1.0f);
    }

    float Cacc = 0.f;

    for (int i = 0; i < nsteps; ++i) {
        const int q = i & 1;
        const char* Mr = Mb + q * 6144;

        bf16x8 Bf[3][2];
#pragma unroll
        for (int ct = 0; ct < 3; ++ct) {
#pragma unroll
            for (int ks = 0; ks < 2; ++ks) {
                int col = ct * 16 + lr;
                int byte = (col * 128 + (ks * 32 + lk * 8) * 2) ^ ((col & 7) << 4);
                Bf[ct][ks] = *(const bf16x8*)(Mr + byte);
            }
        }
        f32x4 el4[3];
#pragma unroll
        for (int tt = 0; tt < 3; ++tt)
            el4[tt] = *(const f32x4*)&el_all[i * 64 + tt * 16 + lk * 4];

        f32x4 c[3][3];
#pragma unroll
        for (int tt = 0; tt < 3; ++tt)
#pragma unroll
            for (int ct = 0; ct < 3; ++ct) {
                c[tt][ct] = __builtin_amdgcn_mfma_f32_16x16x32_bf16(
                    Tf[tt][0], Bf[ct][0], (f32x4){0.f,0.f,0.f,0.f}, 0, 0, 0);
                c[tt][ct] = __builtin_amdgcn_mfma_f32_16x16x32_bf16(
                    Tf[tt][1], Bf[ct][1], c[tt][ct], 0, 0, 0);
            }
#pragma unroll
        for (int tt = 0; tt < 3; ++tt)
#pragma unroll
            for (int ct = 0; ct < 3; ++ct)
#pragma unroll
                for (int r = 0; r < 4; ++r)
                    c[tt][ct][r] *= el4[tt][r];

        if ((i & 3) == 3) {
            float sv = rl(c[0][0][0], 0);
            float rr = __builtin_amdgcn_rcpf(sv);
#pragma unroll
            for (int tt = 0; tt < 3; ++tt)
#pragma unroll
                for (int ct = 0; ct < 3; ++ct)
#pragma unroll
                    for (int r = 0; r < 4; ++r) c[tt][ct][r] *= rr;
            Cacc -= __logf(rr);
        }

        if (i == nsteps - 1) {
#pragma unroll
            for (int tt = 0; tt < 3; ++tt)
#pragma unroll
                for (int ct = 0; ct < 3; ++ct)
#pragma unroll
                    for (int r = 0; r < 4; ++r) {
                        int row = tt * 16 + lk * 4 + r;
                        int col = ct * 16 + lr;
                        Pg[row * 48 + col] = c[tt][ct][r];
                    }
        } else {
            char* Mw = Mb + (q ^ 1) * 6144;
#pragma unroll
            for (int tt = 0; tt < 3; ++tt)
#pragma unroll
                for (int ct = 0; ct < 3; ++ct) {
                    int col = ct * 16 + lr;
                    int k   = tt * 16 + lk * 4;
                    int byte = (col * 128 + k * 2) ^ ((col & 7) << 4);
                    *(uint2*)(Mw + byte) = make_uint2(pk2(c[tt][ct][0], c[tt][ct][1]),
                                                      pk2(c[tt][ct][2], c[tt][ct][3]));
                }
        }
    }

    if (lane == 0) Pc[b * NSEG + s] = Cacc;
}

// ---------------------------------------------------------------------------
// Kernel Dc: combine over 16 segments.
// ---------------------------------------------------------------------------
__global__ __launch_bounds__(256) void kDc(const float* __restrict__ scores,
                                           const int* __restrict__ labels,
                                           const int* __restrict__ lens,
                                           const float* __restrict__ trans,
                                           const float* __restrict__ Pm,
                                           const float* __restrict__ Pc,
                                           float* __restrict__ loss) {
    __shared__ float trL[39 * 41];
    __shared__ float gred[4];

    const int b    = blockIdx.x;
    const int tid  = threadIdx.x;
    const int lane = tid & 63;
    const int wid  = tid >> 6;
    const int len  = lens[b];
    const float* sb = scores + (size_t)b * NS * NLP;

    for (int idx = tid; idx < 39 * 39; idx += 256) {
        int to = idx / 39, f = idx - to * 39;
        trL[to * 41 + f] = trans[idx];
    }
    __syncthreads();

    float g = 0.0f;
    for (int t = tid; t < len; t += 256) g += sb[(size_t)t * NLP + labels[b * NS + t]];
    for (int i = tid; i <= len; i += 256) {
        int frm = (i == 0) ? 37 : labels[b * NS + i - 1];
        int to  = (i == len) ? 38 : labels[b * NS + i];
        g += trL[to * 41 + frm];
    }
#pragma unroll
    for (int off = 32; off > 0; off >>= 1) g += __shfl_xor(g, off, 64);
    if (lane == 0) gred[wid] = g;
    __syncthreads();

    if (wid != 0) return;

    const float gold = (gred[0] + gred[1]) + (gred[2] + gred[3]);
    const bool act48 = (lane < 48);

    const float* P0 = Pm + (size_t)b * NSEG * 2304;
    float v = act48 ? P0[lane * 48 + 37] : 0.f;
    float C = Pc[b * NSEG];

    for (int s = 1; s < NSEG; ++s) {
        float as_[40];
#pragma unroll
        for (int f = 0; f < 40; ++f) as_[f] = rl(v, f);
        __builtin_amdgcn_sched_barrier(0);
        const float* Ps = Pm + (size_t)(b * NSEG + s) * 2304;
        float c = 0.f;
        if (act48) {
            const float4* rowp = (const float4*)(Ps + lane * 48);
#pragma unroll
            for (int q = 0; q < 10; ++q) {
                float4 rv = rowp[q];
                c = fmaf(rv.x, as_[q*4+0], c);
                c = fmaf(rv.y, as_[q*4+1], c);
                c = fmaf(rv.z, as_[q*4+2], c);
                c = fmaf(rv.w, as_[q*4+3], c);
            }
        }
        float sv = rl(c, 0);
        float rr = __builtin_amdgcn_rcpf(sv);
        v = c * rr;
        C -= __logf(rr);
        C += Pc[b * NSEG + s];
    }

    const float trEnd = (lane < NLP) ? trL[38 * 41 + lane] : 0.f;
    float aend = (lane < NLP && v > 0.f) ? C + __logf(v) + trEnd : -1e30f;
    float mx = aend;
#pragma unroll
    for (int off = 32; off > 0; off >>= 1) mx = fmaxf(mx, __shfl_xor(mx, off, 64));
    float es = (lane < NLP) ? __expf(aend - mx) : 0.f;
#pragma unroll
    for (int off = 32; off > 0; off >>= 1) es += __shfl_xor(es, off, 64);
    float norm = mx + __logf(es);

    if (lane == 0) loss[b] = gold - norm;
}

// ---------------------------------------------------------------------------
// Kernel B (fallback): reg-staged mixed GEMM (round-4 version).
// ---------------------------------------------------------------------------
__global__ __launch_bounds__(256) void kB(const float* __restrict__ h,
                                          const unsigned short* __restrict__ aware,
                                          const float* __restrict__ Wcat,
                                          const float* __restrict__ bcat,
                                          unsigned short* __restrict__ x2) {
    __shared__ __align__(16) char lds[16384];
    char* Asl = lds;
    char* Bsl = lds + 8192;

    const int tid  = threadIdx.x;
    const int lane = tid & 63;
    const int wid  = tid >> 6;
    const int wm   = (wid >> 1) * 64;
    const int wn   = (wid & 1) * 64;
    const int lr   = lane & 15;
    const int lk   = lane >> 4;

    const int id   = blockIdx.x;
    const int xcd  = id & 7;
    const int slot = id >> 3;
    const int m0   = (xcd * 16 + (slot >> 3)) * 128;
    const int n0   = (slot & 7) * 128;

    const int am = tid >> 1;
    const int ak = (tid & 1) * 16;
    const int bn = tid & 127;
    const int bk = (tid >> 7) * 16;

    f32x4 acc[4][4];
#pragma unroll
    for (int i = 0; i < 4; ++i)
#pragma unroll
        for (int j = 0; j < 4; ++j) acc[i][j] = (f32x4){0.f, 0.f, 0.f, 0.f};

    const float*          hrow = h     + (size_t)(m0 + am) * NH + ak;
    const unsigned short* arow = aware + (size_t)(m0 + am) * NH + ak;
    const float*          wcol = Wcat  + (size_t)bk * NH + n0 + bn;

    float hv[16];
    unsigned int aw[8];
    float wv[16];

    auto stage = [&](int kt) {
        const int region = kt >> 10;
        const int kb = kt & 1023;
        if (region != 1) {
            const float4* hp = (const float4*)(hrow + kb);
            float4 a = hp[0], b = hp[1], c = hp[2], d = hp[3];
            hv[0]=a.x; hv[1]=a.y; hv[2]=a.z; hv[3]=a.w;
            hv[4]=b.x; hv[5]=b.y; hv[6]=b.z; hv[7]=b.w;
            hv[8]=c.x; hv[9]=c.y; hv[10]=c.z; hv[11]=c.w;
            hv[12]=d.x; hv[13]=d.y; hv[14]=d.z; hv[15]=d.w;
        }
        if (region >= 1) {
            const uint4* ap = (const uint4*)(arow + kb);
            uint4 a0 = ap[0], a1 = ap[1];
            aw[0]=a0.x; aw[1]=a0.y; aw[2]=a0.z; aw[3]=a0.w;
            aw[4]=a1.x; aw[5]=a1.y; aw[6]=a1.z; aw[7]=a1.w;
        }
        {
            const float* wp = wcol + (size_t)kt * NH;
#pragma unroll
            for (int j = 0; j < 16; ++j) wv[j] = wp[(size_t)j * NH];
        }
    };

    auto writeStage = [&](int kt) {
        const int region = kt >> 10;
        unsigned int p[8];
        if (region == 0) {
#pragma unroll
            for (int i = 0; i < 8; ++i) p[i] = pk2(hv[2*i], hv[2*i+1]);
        } else if (region == 1) {
#pragma unroll
            for (int i = 0; i < 8; ++i) p[i] = aw[i];
        } else {
#pragma unroll
            for (int i = 0; i < 8; ++i) {
                float lo = hv[2*i]   * bf2f(aw[i] & 0xffffu);
                float hi = hv[2*i+1] * bf2f(aw[i] >> 16);
                p[i] = pk2(lo, hi);
            }
        }
        *(int4*)(Asl + SW64(am*64 + ak*2))      = make_int4(p[0], p[1], p[2], p[3]);
        *(int4*)(Asl + SW64(am*64 + ak*2 + 16)) = make_int4(p[4], p[5], p[6], p[7]);
        unsigned int q[8];
#pragma unroll
        for (int i = 0; i < 8; ++i) q[i] = pk2(wv[2*i], wv[2*i+1]);
        *(int4*)(Bsl + SW64(bn*64 + bk*2))      = make_int4(q[0], q[1], q[2], q[3]);
        *(int4*)(Bsl + SW64(bn*64 + bk*2 + 16)) = make_int4(q[4], q[5], q[6], q[7]);
    };

    stage(0);
    for (int kt = 0; kt < 3072; kt += 32) {
        __syncthreads();
        writeStage(kt);
        __syncthreads();
        if (kt + 32 < 3072) stage(kt + 32);

        bf16x8 af[4], bfr[4];
#pragma unroll
        for (int mf = 0; mf < 4; ++mf)
            af[mf] = *(const bf16x8*)(Asl + SW64((wm + mf*16 + lr)*64 + lk*16));
#pragma unroll
        for (int nf = 0; nf < 4; ++nf)
            bfr[nf] = *(const bf16x8*)(Bsl + SW64((wn + nf*16 + lr)*64 + lk*16));
#pragma unroll
        for (int mf = 0; mf < 4; ++mf)
#pragma unroll
            for (int nf = 0; nf < 4; ++nf)
                acc[mf][nf] = __builtin_amdgcn_mfma_f32_16x16x32_bf16(af[mf], bfr[nf], acc[mf][nf], 0, 0, 0);
    }

#pragma unroll
    for (int nf = 0; nf < 4; ++nf) {
        const int col = n0 + wn + nf*16 + lr;
        const float bc = bcat[col];
#pragma unroll
        for (int mf = 0; mf < 4; ++mf)
#pragma unroll
            for (int r = 0; r < 4; ++r) {
                size_t row = (size_t)(m0 + wm + mf*16 + lk*4 + r);
                float x = acc[mf][nf][r] + bc;
                float g = 0.5f * x * (1.0f + erff(x * 0.70710678118654752f));
                x2[row * NH + col] = f2bf(g);
            }
    }
}

// ---------------------------------------------------------------------------
// Kernel C (fallback): ner_scores = [x2 @ W_crf + b_crf, -10000, -10000]
// ---------------------------------------------------------------------------
__global__ __launch_bounds__(256) void kC(const unsigned short* __restrict__ x2,
                                          const float* __restrict__ Wcrf,
                                          const float* __restrict__ bcrf,
                                          float* __restrict__ out) {
    __shared__ __align__(16) char Asl[8192];
    __shared__ __align__(16) char Bsl[3072];

    const int tid  = threadIdx.x;
    const int lane = tid & 63;
    const int wid  = tid >> 6;
    const int lr   = lane & 15;
    const int lk   = lane >> 4;
    const int m0   = blockIdx.x * 128;
    const int am   = tid >> 1;
    const int ak   = (tid & 1) * 16;

    for (int i = tid; i < 192; i += 256) *(int4*)(Bsl + i*16) = make_int4(0, 0, 0, 0);

    f32x4 acc[2][3];
#pragma unroll
    for (int i = 0; i < 2; ++i)
#pragma unroll
        for (int j = 0; j < 3; ++j) acc[i][j] = (f32x4){0.f, 0.f, 0.f, 0.f};

    const unsigned short* xrow = x2 + (size_t)(m0 + am) * NH + ak;

    for (int kt = 0; kt < NH; kt += 32) {
        const uint4* xp = (const uint4*)(xrow + kt);
        uint4 x0 = xp[0], x1 = xp[1];
        float wv[5];
#pragma unroll
        for (int p = 0; p < 5; ++p) {
            int i = tid + p * 256;
            wv[p] = (i < 32*NT) ? Wcrf[(size_t)kt * NT + i] : 0.f;
        }
        __syncthreads();
        *(uint4*)(Asl + SW64(am*64 + ak*2))      = x0;
        *(uint4*)(Asl + SW64(am*64 + ak*2 + 16)) = x1;
#pragma unroll
        for (int p = 0; p < 5; ++p) {
            int i = tid + p * 256;
            if (i < 32*NT) {
                int kk = i / NT;
                int t  = i - kk * NT;
                *(unsigned short*)(Bsl + SW64(t*64 + kk*2)) = f2bf(wv[p]);
            }
        }
        __syncthreads();
        bf16x8 af[2], bfr[3];
#pragma unroll
        for (int mf = 0; mf < 2; ++mf)
            af[mf] = *(const bf16x8*)(Asl + SW64((wid*32 + mf*16 + lr)*64 + lk*16));
#pragma unroll
        for (int nf = 0; nf < 3; ++nf)
            bfr[nf] = *(const bf16x8*)(Bsl + SW64((nf*16 + lr)*64 + lk*16));
#pragma unroll
        for (int mf = 0; mf < 2; ++mf)
#pragma unroll
            for (int nf = 0; nf < 3; ++nf)
                acc[mf][nf] = __builtin_amdgcn_mfma_f32_16x16x32_bf16(af[mf], bfr[nf], acc[mf][nf], 0, 0, 0);
    }

#pragma unroll
    for (int nf = 0; nf < 3; ++nf) {
        const int t = nf*16 + lr;
        const float bc = (t < NT) ? bcrf[t] : 0.f;
#pragma unroll
        for (int mf = 0; mf < 2; ++mf)
#pragma unroll
            for (int r = 0; r < 4; ++r) {
                size_t row = (size_t)(m0 + wid*32 + mf*16 + lk*4 + r);
                if (t < NT)       out[row * NLP + t] = acc[mf][nf][r] + bc;
                else if (t < NLP) out[row * NLP + t] = -10000.0f;
            }
    }
}

// ---------------------------------------------------------------------------
// Kernel Dold (fallback): round-11 exp-domain scan, scores staged in LDS.
// ---------------------------------------------------------------------------
#define CRFSTEP(EL) do {                                   \
    float as_[37];                                         \
    _Pragma("unroll")                                      \
    for (int f_ = 0; f_ < 37; ++f_) as_[f_] = rl(a, f_);   \
    __builtin_amdgcn_sched_barrier(0);                     \
    float c0 = 0.f, c1 = 0.f, c2 = 0.f, c3 = 0.f;          \
    _Pragma("unroll")                                      \
    for (int f_ = 0; f_ < 36; f_ += 4) {                   \
        c0 = fmaf(as_[f_    ], trow[f_    ], c0);          \
        c1 = fmaf(as_[f_ + 1], trow[f_ + 1], c1);          \
        c2 = fmaf(as_[f_ + 2], trow[f_ + 2], c2);          \
        c3 = fmaf(as_[f_ + 3], trow[f_ + 3], c3);          \
    }                                                      \
    c0 = fmaf(as_[36], trow[36], c0);                      \
    a = (EL) * ((c0 + c1) + (c2 + c3));                    \
} while (0)

__global__ __launch_bounds__(256) void kDold(const float* __restrict__ scores,
                                             const int* __restrict__ labels,
                                             const int* __restrict__ lens,
                                             const float* __restrict__ trans,
                                             float* __restrict__ loss) {
    __shared__ float S[NS * NLP];
    __shared__ float trL[39 * 41];
    __shared__ int   labL[NS];
    __shared__ float gred[4];

    const int b    = blockIdx.x;
    const int tid  = threadIdx.x;
    const int lane = tid & 63;
    const int wid  = tid >> 6;
    const int len  = lens[b];
    const float* sb = scores + (size_t)b * NS * NLP;

    {
        const int n4 = (len * NLP + 3) >> 2;
        const float4* src = (const float4*)sb;
        float4* dst = (float4*)S;
        for (int i = tid; i < n4; i += 256) dst[i] = src[i];
    }
    for (int i = tid; i < NS; i += 256) labL[i] = labels[b * NS + i];
    for (int idx = tid; idx < 39 * 39; idx += 256) {
        int to = idx / 39, f = idx - to * 39;
        trL[to * 41 + f] = trans[idx];
    }
    __syncthreads();

    float g = 0.0f;
    for (int t = tid; t < len; t += 256) g += S[t * NLP + labL[t]];
    for (int i = tid; i <= len; i += 256) {
        int frm = (i == 0) ? 37 : labL[i - 1];
        int to  = (i == len) ? 38 : labL[i];
        g += trL[to * 41 + frm];
    }
#pragma unroll
    for (int off = 32; off > 0; off >>= 1) g += __shfl_xor(g, off, 64);
    if (lane == 0) gred[wid] = g;
    __syncthreads();

    if (wid != 0) return;

    const float gold = (gred[0] + gred[1]) + (gred[2] + gred[3]);

    const int myrow = (lane < 39) ? lane : 0;
    float trow[39];
#pragma unroll
    for (int f = 0; f < 39; ++f) trow[f] = __expf(trL[myrow * 41 + f]);
    const float trEnd = (lane < 39) ? trL[38 * 41 + lane] : 0.f;
    const bool act = (lane < 39);

    float l0 = act ? S[lane] : -10000.f;
    float a = act ? __expf(l0) * trow[37] : 0.f;
    float C = 0.0f;

    auto ldrow = [&](int r) {
        r = (r < len) ? r : (len - 1);
        return S[act ? (r * NLP + lane) : 0];
    };
    float lg0 = ldrow(1), lg1 = ldrow(2), lg2 = ldrow(3), lg3 = ldrow(4);

    int t = 1;
    for (; t + 3 < len; t += 4) {
        float e0 = __expf(lg0), e1 = __expf(lg1), e2 = __expf(lg2), e3 = __expf(lg3);
        lg0 = ldrow(t + 4); lg1 = ldrow(t + 5); lg2 = ldrow(t + 6); lg3 = ldrow(t + 7);
        CRFSTEP(e0); CRFSTEP(e1); CRFSTEP(e2); CRFSTEP(e3);
        float s = rl(a, 0);
        float rr = __builtin_amdgcn_rcpf(s);
        a *= rr; C -= __logf(rr);
    }
    for (; t < len; ++t) {
        float el = __expf(ldrow(t));
        CRFSTEP(el);
    }

    float aend = (act && a > 0.f) ? C + __logf(a) + trEnd : -1e30f;
    float mx = aend;
#pragma unroll
    for (int off = 32; off > 0; off >>= 1) mx = fmaxf(mx, __shfl_xor(mx, off, 64));
    float es = act ? __expf(aend - mx) : 0.0f;
#pragma unroll
    for (int off = 32; off > 0; off >>= 1) es += __shfl_xor(es, off, 64);
    float norm = mx + __logf(es);

    if (lane == 0) loss[b] = gold - norm;
}

// ---------------------------------------------------------------------------
extern "C" void kernel_launch(void* const* d_in, const int* in_sizes, int n_in,
                              void* d_out, int out_size, void* d_ws, size_t ws_size,
                              hipStream_t stream) {
    const float* h        = (const float*)d_in[0];
    const int* token_nums = (const int*)d_in[2];
    const int* labels     = (const int*)d_in[3];
    const float* bio      = (const float*)d_in[4];
    const float* Wcat     = (const float*)d_in[5];
    const float* bcat     = (const float*)d_in[6];
    const float* Wcrf     = (const float*)d_in[7];
    const float* bcrf     = (const float*)d_in[8];
    const float* trans    = (const float*)d_in[9];

    float* out = (float*)d_out;
    unsigned short* attn  = (unsigned short*)d_out;  // 2MB scratch, overwritten by kDmCr

    const size_t ASW_BYTES = (size_t)128 * 48 * 16384;        // 96 MB
    const size_t P_BYTES   = (size_t)4 * NM * 48 * 4;         // 12.6 MB
    const size_t WSW_BYTES = (size_t)8 * 48 * 16384;          // 6 MB
    const size_t WT_BYTES  = (size_t)48 * 3072 * 2;           // 288 KB
    const size_t PM_BYTES  = (size_t)NB * NSEG * 2304 * 4;    // 4.7 MB
    const size_t PC_BYTES  = (size_t)NB * NSEG * 4;           // 2 KB
    const bool fast = ws_size >= ASW_BYTES + P_BYTES + WSW_BYTES + WT_BYTES + PM_BYTES + PC_BYTES;

    if (fast) {
        char*  Asw = (char*)d_ws;
        float* P   = (float*)((char*)d_ws + ASW_BYTES);
        char*  Wsw = (char*)d_ws + ASW_BYTES + P_BYTES;
        unsigned short* WT = (unsigned short*)((char*)d_ws + ASW_BYTES + P_BYTES + WSW_BYTES);
        float* Pm  = (float*)((char*)d_ws + ASW_BYTES + P_BYTES + WSW_BYTES + WT_BYTES);
        float* Pc  = Pm + (size_t)NB * NSEG * 2304;

        hipLaunchKernelGGL(kPre, dim3(712), dim3(256), 0, stream,
                           h, bio, Wcat, Wcrf, attn, Asw, Wsw, WT);
        hipLaunchKernelGGL(kA2f, dim3(NH / 128, NM / 128), dim3(256), 0, stream,
                           attn, bio, Asw);
        hipLaunchKernelGGL(kBf, dim3(256), dim3(512), 0, stream, Asw, Wsw, bcat, WT, P);
        hipLaunchKernelGGL(kDmCr, dim3(NB * NSEG), dim3(256), 0, stream,
                           P, bcrf, token_nums, trans, out, Pm, Pc);
        hipLaunchKernelGGL(kDc, dim3(NB), dim3(256), 0, stream, out, labels, token_nums,
                           trans, Pm, Pc, out + (size_t)NM * NLP);
    } else {
        unsigned short* aware = (unsigned short*)d_ws;
        unsigned short* x2    = aware + (size_t)NM * NH;

        hipLaunchKernelGGL(kA1, dim3(NM / 128), dim3(512), 0, stream, h, bio, attn);
        hipLaunchKernelGGL(kA2, dim3(NH / 128, NM / 128), dim3(256), 0, stream, attn, bio, aware);
        hipLaunchKernelGGL(kB, dim3((NH / 128) * (NM / 128)), dim3(256), 0, stream,
                           h, aware, Wcat, bcat, x2);
        hipLaunchKernelGGL(kC, dim3(NM / 128), dim3(256), 0, stream, x2, Wcrf, bcrf, out);
        hipLaunchKernelGGL(kDold, dim3(NB), dim3(256), 0, stream, out, labels, token_nums,
                           trans, out + (size_t)NM * NLP);
    }
}